// Round 1
// baseline (878.994 us; speedup 1.0000x reference)
//
#include <hip/hip_runtime.h>
#include <hip/hip_bf16.h>

#define B_ 2
#define N_ 2048
#define H_ 8
#define DH_ 128
#define D_ 1024
#define NO_ 3072
#define SCALE_ 0.08838834764831845f

typedef __bf16 bf16;
typedef __bf16 bf16x4 __attribute__((ext_vector_type(4)));
typedef __bf16 bf16x8 __attribute__((ext_vector_type(8)));
typedef float f32x4 __attribute__((ext_vector_type(4)));

__device__ inline f32x4 mfma16(bf16x8 a, bf16x8 b, f32x4 c) {
  return __builtin_amdgcn_mfma_f32_16x16x32_bf16(a, b, c, 0, 0, 0);
}

// ---------------- RMSNorm: x[4096][1024] -> xn bf16 ----------------
__global__ __launch_bounds__(256) void k_rmsnorm(const float* __restrict__ x,
                                                 const float* __restrict__ gamma,
                                                 bf16* __restrict__ xn) {
  int row = blockIdx.x;
  int t = threadIdx.x;
  const float4* xr = (const float4*)(x + (size_t)row * D_);
  float4 xv = xr[t];
  float ss = xv.x*xv.x + xv.y*xv.y + xv.z*xv.z + xv.w*xv.w;
#pragma unroll
  for (int m = 1; m < 64; m <<= 1) ss += __shfl_xor(ss, m);
  __shared__ float sred[4];
  if ((t & 63) == 0) sred[t >> 6] = ss;
  __syncthreads();
  float tot = sred[0] + sred[1] + sred[2] + sred[3];
  float scale = 32.0f / fmaxf(sqrtf(tot), 1e-12f);
  float4 gv = ((const float4*)gamma)[t];
  bf16x4 ov;
  ov[0] = (bf16)(xv.x * scale * gv.x);
  ov[1] = (bf16)(xv.y * scale * gv.y);
  ov[2] = (bf16)(xv.z * scale * gv.z);
  ov[3] = (bf16)(xv.w * scale * gv.w);
  *(bf16x4*)(xn + (size_t)row * D_ + t * 4) = ov;
}

// ---------------- fp32 -> bf16 convert ----------------
__global__ void k_cvt4(const float4* __restrict__ in, bf16x4* __restrict__ out, int n4) {
  int i = blockIdx.x * blockDim.x + threadIdx.x;
  if (i < n4) {
    float4 v = in[i];
    bf16x4 o;
    o[0] = (bf16)v.x; o[1] = (bf16)v.y; o[2] = (bf16)v.z; o[3] = (bf16)v.w;
    out[i] = o;
  }
}

// ---------------- C[M][N] = A[M][K] @ B[N][K]^T  (bf16 in, fp32 out) -------
// 128x128 block tile, BK=32, 4 waves each 64x64 (4x4 of 16x16 MFMA)
__global__ __launch_bounds__(256) void k_gemm_bt(const bf16* __restrict__ A,
                                                 const bf16* __restrict__ B,
                                                 float* __restrict__ C,
                                                 int M, int Nn, int K) {
  __shared__ __align__(16) bf16 sA[128 * 32];
  __shared__ __align__(16) bf16 sB[128 * 32];
  int t = threadIdx.x;
  int w = t >> 6, lane = t & 63, quad = lane >> 4, l16 = lane & 15;
  int m0 = blockIdx.y * 128, n0 = blockIdx.x * 128;
  int wr = (w & 1) * 64, wc = (w >> 1) * 64;
  f32x4 zf = {0.f, 0.f, 0.f, 0.f};
  f32x4 acc[4][4];
#pragma unroll
  for (int a = 0; a < 4; a++)
#pragma unroll
    for (int c = 0; c < 4; c++) acc[a][c] = zf;
  int trow = t >> 2, tc = t & 3;
  for (int k0 = 0; k0 < K; k0 += 32) {
    __syncthreads();
    ((uint4*)sA)[trow * 4 + tc]        = *((const uint4*)(A + (size_t)(m0 + trow) * K + k0) + tc);
    ((uint4*)sA)[(trow + 64) * 4 + tc] = *((const uint4*)(A + (size_t)(m0 + trow + 64) * K + k0) + tc);
    ((uint4*)sB)[trow * 4 + tc]        = *((const uint4*)(B + (size_t)(n0 + trow) * K + k0) + tc);
    ((uint4*)sB)[(trow + 64) * 4 + tc] = *((const uint4*)(B + (size_t)(n0 + trow + 64) * K + k0) + tc);
    __syncthreads();
    bf16x8 af[4], bfr[4];
#pragma unroll
    for (int mt = 0; mt < 4; mt++)
      af[mt] = *(const bf16x8*)(sA + (wr + mt * 16 + l16) * 32 + quad * 8);
#pragma unroll
    for (int nt = 0; nt < 4; nt++)
      bfr[nt] = *(const bf16x8*)(sB + (wc + nt * 16 + l16) * 32 + quad * 8);
#pragma unroll
    for (int mt = 0; mt < 4; mt++)
#pragma unroll
      for (int nt = 0; nt < 4; nt++)
        acc[mt][nt] = mfma16(af[mt], bfr[nt], acc[mt][nt]);
  }
#pragma unroll
  for (int mt = 0; mt < 4; mt++)
#pragma unroll
    for (int nt = 0; nt < 4; nt++) {
      int row = m0 + wr + mt * 16 + quad * 4;
      int col = n0 + wc + nt * 16 + l16;
      float* cp = C + (size_t)row * Nn + col;
#pragma unroll
      for (int r = 0; r < 4; r++) cp[(size_t)r * Nn] = acc[mt][nt][r];
    }
}

// ---------------- prep: RoPE(q,k), kf, v^T, retrieval denominators --------
__global__ void k_prep(const float* __restrict__ qkv,
                       const float* __restrict__ mem_norm,
                       bf16* __restrict__ qr, bf16* __restrict__ kr,
                       bf16* __restrict__ vT, bf16* __restrict__ kf,
                       float* __restrict__ qden, float* __restrict__ kden) {
  int n = blockIdx.x;
  int h = blockIdx.y;
  int b = blockIdx.z;
  int d = threadIdx.x;  // 128
  size_t m = (size_t)b * N_ + n;
  const float* base = qkv + m * NO_ + h * DH_;
  float q = base[d];
  float k = base[D_ + d];
  float v = base[2 * D_ + d];
  int j = d >> 1;
  float inv_freq = __powf(10000.0f, -(float)(2 * j) * (1.0f / 128.0f));
  float ang = (float)n * inv_freq;
  float sn, cs;
  __sincosf(ang, &sn, &cs);
  float qs = q * SCALE_;
  float qp = __shfl_xor(qs, 1);
  float qrot = (d & 1) ? qp : -qp;  // even: -x[d+1], odd: x[d-1]
  float kp = __shfl_xor(k, 1);
  float krot = (d & 1) ? kp : -kp;
  size_t bh = (size_t)b * H_ + h;
  size_t ro = (bh * N_ + n) * DH_ + d;
  qr[ro] = (bf16)(qs * cs + qrot * sn);
  kr[ro] = (bf16)(k * cs + krot * sn);
  float kfv = k > 0.f ? k + 1.f : __expf(k);
  kf[ro] = (bf16)kfv;
  vT[(bh * DH_ + d) * N_ + n] = (bf16)v;
  float qfv = q > 0.f ? q + 1.f : __expf(q);
  float mn = mem_norm[bh * DH_ + d];
  float pq = qfv * mn;
  float pk = kfv * mn;
#pragma unroll
  for (int msk = 1; msk < 64; msk <<= 1) {
    pq += __shfl_xor(pq, msk);
    pk += __shfl_xor(pk, msk);
  }
  __shared__ float rq[2], rk[2];
  if ((d & 63) == 0) { rq[d >> 6] = pq; rk[d >> 6] = pk; }
  __syncthreads();
  if (d == 0) {
    qden[bh * N_ + n] = rq[0] + rq[1];
    kden[bh * N_ + n] = rk[0] + rk[1];
  }
}

// ---------------- flash attention (causal), bf16 MFMA ----------------
// block: 256 thr = 4 waves; wave w owns 16 q-rows; q-tile = 64, key-tile = 32
__global__ __launch_bounds__(256) void k_attn(const bf16* __restrict__ qr,
                                              const bf16* __restrict__ kr,
                                              const bf16* __restrict__ vT,
                                              float* __restrict__ attn_out) {
  __shared__ __align__(16) bf16 sK[32 * 128];   // [key][d]
  __shared__ __align__(16) bf16 sV[128 * 32];   // [d][key]
  __shared__ __align__(16) bf16 sP[4][16 * 32]; // per-wave [qrow][key]
  int qt = blockIdx.x;
  size_t bh = (size_t)blockIdx.z * H_ + blockIdx.y;
  int t = threadIdx.x;
  int w = t >> 6, lane = t & 63, quad = lane >> 4, l16 = lane & 15;
  int qlo = qt * 64 + w * 16;

  bf16x8 qfrag[4];
  const bf16* qrow = qr + (bh * N_ + qlo + l16) * DH_;
#pragma unroll
  for (int s = 0; s < 4; s++) qfrag[s] = *(const bf16x8*)(qrow + s * 32 + quad * 8);

  f32x4 zf = {0.f, 0.f, 0.f, 0.f};
  f32x4 o[8];
#pragma unroll
  for (int i = 0; i < 8; i++) o[i] = zf;
  float mrow[4] = {-1e30f, -1e30f, -1e30f, -1e30f};
  float lrow[4] = {0.f, 0.f, 0.f, 0.f};

  int ntiles = 2 * qt + 2;
  int krow = t >> 4, kc8 = t & 15;
  int vrow = t >> 2, vc = t & 3;
  for (int jt = 0; jt < ntiles; jt++) {
    __syncthreads();
    {  // stage K [32][128] and V^T [128][32]
      ((uint4*)sK)[krow * 16 + kc8] =
          *((const uint4*)(kr + (bh * N_ + (size_t)jt * 32 + krow) * DH_) + kc8);
      ((uint4*)sK)[(16 + krow) * 16 + kc8] =
          *((const uint4*)(kr + (bh * N_ + (size_t)jt * 32 + 16 + krow) * DH_) + kc8);
      ((uint4*)sV)[vrow * 4 + vc] =
          *((const uint4*)(vT + (bh * DH_ + vrow) * N_ + (size_t)jt * 32) + vc);
      ((uint4*)sV)[(64 + vrow) * 4 + vc] =
          *((const uint4*)(vT + (bh * DH_ + 64 + vrow) * N_ + (size_t)jt * 32) + vc);
    }
    __syncthreads();
    if (jt * 32 > qlo + 15) continue;  // wave fully above diagonal

    f32x4 s0 = zf, s1 = zf;
#pragma unroll
    for (int s = 0; s < 4; s++) {
      bf16x8 b0 = *(const bf16x8*)(sK + l16 * 128 + s * 32 + quad * 8);
      bf16x8 b1 = *(const bf16x8*)(sK + (16 + l16) * 128 + s * 32 + quad * 8);
      s0 = mfma16(qfrag[s], b0, s0);
      s1 = mfma16(qfrag[s], b1, s1);
    }
    if (jt * 32 + 31 > qlo) {  // diagonal tile: mask key > q
#pragma unroll
      for (int r = 0; r < 4; r++) {
        int qg = qlo + quad * 4 + r;
        int kg = jt * 32 + l16;
        if (kg > qg)      s0[r] = -1e30f;
        if (kg + 16 > qg) s1[r] = -1e30f;
      }
    }
    float alpha[4];
#pragma unroll
    for (int r = 0; r < 4; r++) {
      float tm = fmaxf(s0[r], s1[r]);
      tm = fmaxf(tm, __shfl_xor(tm, 1));
      tm = fmaxf(tm, __shfl_xor(tm, 2));
      tm = fmaxf(tm, __shfl_xor(tm, 4));
      tm = fmaxf(tm, __shfl_xor(tm, 8));
      float mn = fmaxf(mrow[r], tm);
      alpha[r] = __expf(mrow[r] - mn);
      float p0 = __expf(s0[r] - mn);
      float p1 = __expf(s1[r] - mn);
      s0[r] = p0; s1[r] = p1;
      float rs = p0 + p1;
      rs += __shfl_xor(rs, 1);
      rs += __shfl_xor(rs, 2);
      rs += __shfl_xor(rs, 4);
      rs += __shfl_xor(rs, 8);
      lrow[r] = lrow[r] * alpha[r] + rs;
      mrow[r] = mn;
    }
#pragma unroll
    for (int i = 0; i < 8; i++) {
      o[i][0] *= alpha[0]; o[i][1] *= alpha[1];
      o[i][2] *= alpha[2]; o[i][3] *= alpha[3];
    }
    // P: C-layout -> LDS -> A-operand layout (per-wave region, in-order DS)
    bf16* pw = sP[w];
#pragma unroll
    for (int r = 0; r < 4; r++) {
      int prow = quad * 4 + r;
      pw[prow * 32 + l16]      = (bf16)s0[r];
      pw[prow * 32 + 16 + l16] = (bf16)s1[r];
    }
    bf16x8 pa = *(const bf16x8*)(pw + l16 * 32 + quad * 8);
#pragma unroll
    for (int nt = 0; nt < 8; nt++) {
      bf16x8 bv = *(const bf16x8*)(sV + (nt * 16 + l16) * 32 + quad * 8);
      o[nt] = mfma16(pa, bv, o[nt]);
    }
  }
#pragma unroll
  for (int nt = 0; nt < 8; nt++)
#pragma unroll
    for (int r = 0; r < 4; r++) {
      int qg = qlo + quad * 4 + r;
      attn_out[(bh * N_ + qg) * DH_ + nt * 16 + l16] = o[nt][r] / lrow[r];
    }
}

// -------- retrieval (qf and kf paths) + gate-combine + vnew --------
__global__ __launch_bounds__(256) void k_retrieve(const float* __restrict__ qkv,
                                                  const float* __restrict__ mem_kv,
                                                  const float* __restrict__ qden,
                                                  const float* __restrict__ kden,
                                                  const float* __restrict__ attn,
                                                  const float* __restrict__ hg,
                                                  bf16* __restrict__ comb,
                                                  bf16* __restrict__ vnew) {
  __shared__ __align__(16) bf16 smkv[DH_ * DH_];
  __shared__ float sq[DH_], sk[DH_];
  int chunk = blockIdx.x;
  int h = blockIdx.y, b = blockIdx.z;
  size_t bh = (size_t)b * H_ + h;
  int t = threadIdx.x;
  {
    const float4* src = (const float4*)(mem_kv + bh * DH_ * DH_);
    bf16x4* dst = (bf16x4*)smkv;
    for (int i = t; i < DH_ * DH_ / 4; i += 256) {
      float4 v4 = src[i];
      bf16x4 o;
      o[0] = (bf16)v4.x; o[1] = (bf16)v4.y; o[2] = (bf16)v4.z; o[3] = (bf16)v4.w;
      dst[i] = o;
    }
  }
  float g = 1.f / (1.f + __expf(-hg[h]));
  int v = t & 127, which = t >> 7;
  for (int i = 0; i < 128; i++) {
    int n = chunk * 128 + i;
    size_t m = (size_t)b * N_ + n;
    const float* base = qkv + m * NO_ + h * DH_;
    __syncthreads();
    if (t < 128) { float qv = base[t];          sq[t]       = qv > 0.f ? qv + 1.f : __expf(qv); }
    else         { float kv = base[D_ + t-128]; sk[t - 128] = kv > 0.f ? kv + 1.f : __expf(kv); }
    __syncthreads();
    float acc = 0.f;
    const float* frow = which ? sk : sq;
#pragma unroll 8
    for (int kk = 0; kk < DH_; kk++) acc += frow[kk] * (float)smkv[kk * DH_ + v];
    if (which == 0) {
      float den = fmaxf(qden[bh * N_ + n], 1e-10f);
      float mo = acc / den;
      float ov = attn[(bh * N_ + n) * DH_ + v];
      comb[m * D_ + h * DH_ + v] = (bf16)(ov * g + mo * (1.f - g));
    } else {
      float den = fmaxf(kden[bh * N_ + n], 1e-10f);
      float vv = base[2 * D_ + v];
      vnew[(bh * N_ + n) * DH_ + v] = (bf16)(vv - acc / den);
    }
  }
}

// ---------------- init outputs new_kv/new_norm with memories ----------------
__global__ void k_init_out(const float* __restrict__ mem_kv, const float* __restrict__ mem_norm,
                           float* __restrict__ out_kv, float* __restrict__ out_norm) {
  int i = blockIdx.x * 256 + threadIdx.x;
  if (i < B_ * H_ * DH_ * DH_) out_kv[i] = mem_kv[i];
  if (i < B_ * H_ * DH_) out_norm[i] = mem_norm[i];
}

// ---------------- new_kv partial: kf^T @ vnew over an n-chunk --------------
__global__ __launch_bounds__(256) void k_newkv(const bf16* __restrict__ kf,
                                               const bf16* __restrict__ vnew,
                                               float* __restrict__ out_kv) {
  __shared__ __align__(16) bf16 skf[64 * DH_];
  __shared__ __align__(16) bf16 svn[64 * DH_];
  int chunk = blockIdx.x;
  int h = blockIdx.y, b = blockIdx.z;
  size_t bh = (size_t)b * H_ + h;
  int t = threadIdx.x;
  int k = t & 127, vh = t >> 7;
  float acc[64];
#pragma unroll
  for (int i = 0; i < 64; i++) acc[i] = 0.f;
  for (int sub = 0; sub < 4; sub++) {
    size_t nbase = (size_t)chunk * 256 + sub * 64;
    __syncthreads();
    const uint4* s1 = (const uint4*)(kf + (bh * N_ + nbase) * DH_);
    const uint4* s2 = (const uint4*)(vnew + (bh * N_ + nbase) * DH_);
    uint4* d1 = (uint4*)skf;
    uint4* d2 = (uint4*)svn;
    for (int i = t; i < 64 * DH_ / 8; i += 256) { d1[i] = s1[i]; d2[i] = s2[i]; }
    __syncthreads();
    for (int n = 0; n < 64; n++) {
      float kv = (float)skf[n * DH_ + k];
      const bf16x8* vrow8 = (const bf16x8*)(svn + n * DH_ + vh * 64);
#pragma unroll
      for (int i8 = 0; i8 < 8; i8++) {
        bf16x8 vv = vrow8[i8];
#pragma unroll
        for (int e = 0; e < 8; e++) acc[i8 * 8 + e] += kv * (float)vv[e];
      }
    }
  }
  float* orow = out_kv + (bh * DH_ + k) * DH_ + vh * 64;
#pragma unroll
  for (int i = 0; i < 64; i++) atomicAdd(orow + i, acc[i]);
}

// ---------------- new_norm partial: sum_n elu(k)+1 (fp32 from qkv) ---------
__global__ void k_newnorm(const float* __restrict__ qkv, float* __restrict__ out_norm) {
  int chunk = blockIdx.x;
  int h = blockIdx.y, b = blockIdx.z;
  int k = threadIdx.x;  // 128
  size_t bh = (size_t)b * H_ + h;
  float acc = 0.f;
  for (int i = 0; i < 256; i++) {
    size_t n = (size_t)chunk * 256 + i;
    float kv = qkv[((size_t)b * N_ + n) * NO_ + D_ + h * DH_ + k];
    acc += kv > 0.f ? kv + 1.f : __expf(kv);
  }
  atomicAdd(out_norm + bh * DH_ + k, acc);
}

extern "C" void kernel_launch(void* const* d_in, const int* in_sizes, int n_in,
                              void* d_out, int out_size, void* d_ws, size_t ws_size,
                              hipStream_t stream) {
  const float* x        = (const float*)d_in[0];
  const float* gamma    = (const float*)d_in[1];
  const float* w_qkv    = (const float*)d_in[2];
  const float* w_out    = (const float*)d_in[3];
  const float* hg       = (const float*)d_in[4];
  const float* mem_kv   = (const float*)d_in[5];
  const float* mem_norm = (const float*)d_in[6];
  float* out      = (float*)d_out;
  float* out_kv   = out + (size_t)B_ * N_ * D_;
  float* out_norm = out_kv + (size_t)B_ * H_ * DH_ * DH_;

  char* ws = (char*)d_ws;
  size_t off = 0;
  auto alloc = [&](size_t bytes) -> void* {
    void* p = ws + off;
    off += (bytes + 255) & ~(size_t)255;
    return p;
  };
  bf16*  xn   = (bf16*)alloc((size_t)B_ * N_ * D_ * 2);
  bf16*  wqb  = (bf16*)alloc((size_t)NO_ * D_ * 2);
  bf16*  wob  = (bf16*)alloc((size_t)D_ * D_ * 2);
  float* qkv  = (float*)alloc((size_t)B_ * N_ * NO_ * 4);
  bf16*  qr   = (bf16*)alloc((size_t)B_ * H_ * N_ * DH_ * 2);
  bf16*  kr   = (bf16*)alloc((size_t)B_ * H_ * N_ * DH_ * 2);
  bf16*  vT   = (bf16*)alloc((size_t)B_ * H_ * DH_ * N_ * 2);
  bf16*  kf   = (bf16*)alloc((size_t)B_ * H_ * N_ * DH_ * 2);
  bf16*  vnew = (bf16*)alloc((size_t)B_ * H_ * N_ * DH_ * 2);
  float* qden = (float*)alloc((size_t)B_ * H_ * N_ * 4);
  float* kden = (float*)alloc((size_t)B_ * H_ * N_ * 4);
  float* attn = (float*)alloc((size_t)B_ * H_ * N_ * DH_ * 4);
  bf16*  comb = (bf16*)alloc((size_t)B_ * N_ * D_ * 2);
  (void)in_sizes; (void)n_in; (void)out_size; (void)ws_size;

  k_rmsnorm<<<dim3(B_ * N_), 256, 0, stream>>>(x, gamma, xn);
  k_cvt4<<<(NO_ * D_ / 4 + 255) / 256, 256, 0, stream>>>((const float4*)w_qkv, (bf16x4*)wqb, NO_ * D_ / 4);
  k_cvt4<<<(D_ * D_ / 4 + 255) / 256, 256, 0, stream>>>((const float4*)w_out, (bf16x4*)wob, D_ * D_ / 4);
  k_gemm_bt<<<dim3(NO_ / 128, B_ * N_ / 128), 256, 0, stream>>>(xn, wqb, qkv, B_ * N_, NO_, D_);
  k_prep<<<dim3(N_, H_, B_), 128, 0, stream>>>(qkv, mem_norm, qr, kr, vT, kf, qden, kden);
  k_attn<<<dim3(N_ / 64, H_, B_), 256, 0, stream>>>(qr, kr, vT, attn);
  k_retrieve<<<dim3(N_ / 128, H_, B_), 256, 0, stream>>>(qkv, mem_kv, qden, kden, attn, hg, comb, vnew);
  k_gemm_bt<<<dim3(D_ / 128, B_ * N_ / 128), 256, 0, stream>>>(comb, wob, out, B_ * N_, D_, D_);
  k_init_out<<<(B_ * H_ * DH_ * DH_ + 255) / 256, 256, 0, stream>>>(mem_kv, mem_norm, out_kv, out_norm);
  k_newkv<<<dim3(N_ / 256, H_, B_), 256, 0, stream>>>(kf, vnew, out_kv);
  k_newnorm<<<dim3(N_ / 256, H_, B_), 128, 0, stream>>>(qkv, out_norm);
}

// Round 2
// 628.172 us; speedup vs baseline: 1.3993x; 1.3993x over previous
//
#include <hip/hip_runtime.h>
#include <hip/hip_bf16.h>

#define B_ 2
#define N_ 2048
#define H_ 8
#define DH_ 128
#define D_ 1024
#define NO_ 3072
#define SCALE_ 0.08838834764831845f

typedef __bf16 bf16;
typedef __bf16 bf16x4 __attribute__((ext_vector_type(4)));
typedef __bf16 bf16x8 __attribute__((ext_vector_type(8)));
typedef float f32x4 __attribute__((ext_vector_type(4)));

__device__ inline f32x4 mfma16(bf16x8 a, bf16x8 b, f32x4 c) {
  return __builtin_amdgcn_mfma_f32_16x16x32_bf16(a, b, c, 0, 0, 0);
}

__device__ inline float elu1(float x) { return x > 0.f ? x + 1.f : __expf(x); }

// ---------------- RMSNorm: x[4096][1024] -> xn bf16 ----------------
__global__ __launch_bounds__(256) void k_rmsnorm(const float* __restrict__ x,
                                                 const float* __restrict__ gamma,
                                                 bf16* __restrict__ xn) {
  int row = blockIdx.x;
  int t = threadIdx.x;
  const float4* xr = (const float4*)(x + (size_t)row * D_);
  float4 xv = xr[t];
  float ss = xv.x*xv.x + xv.y*xv.y + xv.z*xv.z + xv.w*xv.w;
#pragma unroll
  for (int m = 1; m < 64; m <<= 1) ss += __shfl_xor(ss, m);
  __shared__ float sred[4];
  if ((t & 63) == 0) sred[t >> 6] = ss;
  __syncthreads();
  float tot = sred[0] + sred[1] + sred[2] + sred[3];
  float scale = 32.0f / fmaxf(sqrtf(tot), 1e-12f);
  float4 gv = ((const float4*)gamma)[t];
  bf16x4 ov;
  ov[0] = (bf16)(xv.x * scale * gv.x);
  ov[1] = (bf16)(xv.y * scale * gv.y);
  ov[2] = (bf16)(xv.z * scale * gv.z);
  ov[3] = (bf16)(xv.w * scale * gv.w);
  *(bf16x4*)(xn + (size_t)row * D_ + t * 4) = ov;
}

// ---------------- fp32 -> bf16 convert ----------------
__global__ void k_cvt4(const float4* __restrict__ in, bf16x4* __restrict__ out, int n4) {
  int i = blockIdx.x * blockDim.x + threadIdx.x;
  if (i < n4) {
    float4 v = in[i];
    bf16x4 o;
    o[0] = (bf16)v.x; o[1] = (bf16)v.y; o[2] = (bf16)v.z; o[3] = (bf16)v.w;
    out[i] = o;
  }
}

// ---- mem_kv [bh][k][v] fp32 -> mkvT [bh][v][k] bf16 (global transpose) ----
__global__ __launch_bounds__(256) void k_mkvT(const float* __restrict__ mem_kv,
                                              bf16* __restrict__ mkvT) {
  int bh = blockIdx.x;
  int t = threadIdx.x;
  int v = t & 127, khalf = t >> 7;
  const float* src = mem_kv + (size_t)bh * DH_ * DH_;
  bf16* dst = mkvT + (size_t)bh * DH_ * DH_ + (size_t)v * DH_ + khalf * 64;
#pragma unroll
  for (int kk8 = 0; kk8 < 8; kk8++) {
    int k0 = khalf * 64 + kk8 * 8;
    bf16x8 o;
#pragma unroll
    for (int e = 0; e < 8; e++) o[e] = (bf16)src[(size_t)(k0 + e) * DH_ + v];
    *(bf16x8*)(dst + kk8 * 8) = o;
  }
}

// ---------------- C[M][N] = A[M][K] @ B[N][K]^T  (bf16 in, fp32 out) -------
__global__ __launch_bounds__(256) void k_gemm_bt(const bf16* __restrict__ A,
                                                 const bf16* __restrict__ B,
                                                 float* __restrict__ C,
                                                 int M, int Nn, int K) {
  __shared__ __align__(16) bf16 sA[128 * 32];
  __shared__ __align__(16) bf16 sB[128 * 32];
  int t = threadIdx.x;
  int w = t >> 6, lane = t & 63, quad = lane >> 4, l16 = lane & 15;
  int m0 = blockIdx.y * 128, n0 = blockIdx.x * 128;
  int wr = (w & 1) * 64, wc = (w >> 1) * 64;
  f32x4 zf = {0.f, 0.f, 0.f, 0.f};
  f32x4 acc[4][4];
#pragma unroll
  for (int a = 0; a < 4; a++)
#pragma unroll
    for (int c = 0; c < 4; c++) acc[a][c] = zf;
  int trow = t >> 2, tc = t & 3;
  for (int k0 = 0; k0 < K; k0 += 32) {
    __syncthreads();
    ((uint4*)sA)[trow * 4 + tc]        = *((const uint4*)(A + (size_t)(m0 + trow) * K + k0) + tc);
    ((uint4*)sA)[(trow + 64) * 4 + tc] = *((const uint4*)(A + (size_t)(m0 + trow + 64) * K + k0) + tc);
    ((uint4*)sB)[trow * 4 + tc]        = *((const uint4*)(B + (size_t)(n0 + trow) * K + k0) + tc);
    ((uint4*)sB)[(trow + 64) * 4 + tc] = *((const uint4*)(B + (size_t)(n0 + trow + 64) * K + k0) + tc);
    __syncthreads();
    bf16x8 af[4], bfr[4];
#pragma unroll
    for (int mt = 0; mt < 4; mt++)
      af[mt] = *(const bf16x8*)(sA + (wr + mt * 16 + l16) * 32 + quad * 8);
#pragma unroll
    for (int nt = 0; nt < 4; nt++)
      bfr[nt] = *(const bf16x8*)(sB + (wc + nt * 16 + l16) * 32 + quad * 8);
#pragma unroll
    for (int mt = 0; mt < 4; mt++)
#pragma unroll
      for (int nt = 0; nt < 4; nt++)
        acc[mt][nt] = mfma16(af[mt], bfr[nt], acc[mt][nt]);
  }
#pragma unroll
  for (int mt = 0; mt < 4; mt++)
#pragma unroll
    for (int nt = 0; nt < 4; nt++) {
      int row = m0 + wr + mt * 16 + quad * 4;
      int col = n0 + wc + nt * 16 + l16;
      float* cp = C + (size_t)row * Nn + col;
#pragma unroll
      for (int r = 0; r < 4; r++) cp[(size_t)r * Nn] = acc[mt][nt][r];
    }
}

// ---------------- prep: RoPE(q,k), kf, v^T, retrieval denominators --------
__global__ void k_prep(const float* __restrict__ qkv,
                       const float* __restrict__ mem_norm,
                       bf16* __restrict__ qr, bf16* __restrict__ kr,
                       bf16* __restrict__ vT, bf16* __restrict__ kf,
                       float* __restrict__ qden, float* __restrict__ kden) {
  int n = blockIdx.x;
  int h = blockIdx.y;
  int b = blockIdx.z;
  int d = threadIdx.x;  // 128
  size_t m = (size_t)b * N_ + n;
  const float* base = qkv + m * NO_ + h * DH_;
  float q = base[d];
  float k = base[D_ + d];
  float v = base[2 * D_ + d];
  int j = d >> 1;
  float inv_freq = __powf(10000.0f, -(float)(2 * j) * (1.0f / 128.0f));
  float ang = (float)n * inv_freq;
  float sn, cs;
  __sincosf(ang, &sn, &cs);
  float qs = q * SCALE_;
  float qp = __shfl_xor(qs, 1);
  float qrot = (d & 1) ? qp : -qp;
  float kp = __shfl_xor(k, 1);
  float krot = (d & 1) ? kp : -kp;
  size_t bh = (size_t)b * H_ + h;
  size_t ro = (bh * N_ + n) * DH_ + d;
  qr[ro] = (bf16)(qs * cs + qrot * sn);
  kr[ro] = (bf16)(k * cs + krot * sn);
  float kfv = elu1(k);
  kf[ro] = (bf16)kfv;
  vT[(bh * DH_ + d) * N_ + n] = (bf16)v;
  float qfv = elu1(q);
  float mn = mem_norm[bh * DH_ + d];
  float pq = qfv * mn;
  float pk = kfv * mn;
#pragma unroll
  for (int msk = 1; msk < 64; msk <<= 1) {
    pq += __shfl_xor(pq, msk);
    pk += __shfl_xor(pk, msk);
  }
  __shared__ float rq[2], rk[2];
  if ((d & 63) == 0) { rq[d >> 6] = pq; rk[d >> 6] = pk; }
  __syncthreads();
  if (d == 0) {
    qden[bh * N_ + n] = rq[0] + rq[1];
    kden[bh * N_ + n] = rk[0] + rk[1];
  }
}

// ---------------- flash attention (causal), bf16 MFMA ----------------
__global__ __launch_bounds__(256) void k_attn(const bf16* __restrict__ qr,
                                              const bf16* __restrict__ kr,
                                              const bf16* __restrict__ vT,
                                              float* __restrict__ attn_out) {
  __shared__ __align__(16) bf16 sK[32 * 128];   // [key][d]
  __shared__ __align__(16) bf16 sV[128 * 32];   // [d][key]
  __shared__ __align__(16) bf16 sP[4][16 * 32]; // per-wave [qrow][key]
  int qt = blockIdx.x;
  size_t bh = (size_t)blockIdx.z * H_ + blockIdx.y;
  int t = threadIdx.x;
  int w = t >> 6, lane = t & 63, quad = lane >> 4, l16 = lane & 15;
  int qlo = qt * 64 + w * 16;

  bf16x8 qfrag[4];
  const bf16* qrow = qr + (bh * N_ + qlo + l16) * DH_;
#pragma unroll
  for (int s = 0; s < 4; s++) qfrag[s] = *(const bf16x8*)(qrow + s * 32 + quad * 8);

  f32x4 zf = {0.f, 0.f, 0.f, 0.f};
  f32x4 o[8];
#pragma unroll
  for (int i = 0; i < 8; i++) o[i] = zf;
  float mrow[4] = {-1e30f, -1e30f, -1e30f, -1e30f};
  float lrow[4] = {0.f, 0.f, 0.f, 0.f};

  int ntiles = 2 * qt + 2;
  int krow = t >> 4, kc8 = t & 15;
  int vrow = t >> 2, vc = t & 3;
  for (int jt = 0; jt < ntiles; jt++) {
    __syncthreads();
    {
      ((uint4*)sK)[krow * 16 + kc8] =
          *((const uint4*)(kr + (bh * N_ + (size_t)jt * 32 + krow) * DH_) + kc8);
      ((uint4*)sK)[(16 + krow) * 16 + kc8] =
          *((const uint4*)(kr + (bh * N_ + (size_t)jt * 32 + 16 + krow) * DH_) + kc8);
      ((uint4*)sV)[vrow * 4 + vc] =
          *((const uint4*)(vT + (bh * DH_ + vrow) * N_ + (size_t)jt * 32) + vc);
      ((uint4*)sV)[(64 + vrow) * 4 + vc] =
          *((const uint4*)(vT + (bh * DH_ + 64 + vrow) * N_ + (size_t)jt * 32) + vc);
    }
    __syncthreads();
    if (jt * 32 > qlo + 15) continue;

    f32x4 s0 = zf, s1 = zf;
#pragma unroll
    for (int s = 0; s < 4; s++) {
      bf16x8 b0 = *(const bf16x8*)(sK + l16 * 128 + s * 32 + quad * 8);
      bf16x8 b1 = *(const bf16x8*)(sK + (16 + l16) * 128 + s * 32 + quad * 8);
      s0 = mfma16(qfrag[s], b0, s0);
      s1 = mfma16(qfrag[s], b1, s1);
    }
    if (jt * 32 + 31 > qlo) {
#pragma unroll
      for (int r = 0; r < 4; r++) {
        int qg = qlo + quad * 4 + r;
        int kg = jt * 32 + l16;
        if (kg > qg)      s0[r] = -1e30f;
        if (kg + 16 > qg) s1[r] = -1e30f;
      }
    }
    float alpha[4];
#pragma unroll
    for (int r = 0; r < 4; r++) {
      float tm = fmaxf(s0[r], s1[r]);
      tm = fmaxf(tm, __shfl_xor(tm, 1));
      tm = fmaxf(tm, __shfl_xor(tm, 2));
      tm = fmaxf(tm, __shfl_xor(tm, 4));
      tm = fmaxf(tm, __shfl_xor(tm, 8));
      float mn = fmaxf(mrow[r], tm);
      alpha[r] = __expf(mrow[r] - mn);
      float p0 = __expf(s0[r] - mn);
      float p1 = __expf(s1[r] - mn);
      s0[r] = p0; s1[r] = p1;
      float rs = p0 + p1;
      rs += __shfl_xor(rs, 1);
      rs += __shfl_xor(rs, 2);
      rs += __shfl_xor(rs, 4);
      rs += __shfl_xor(rs, 8);
      lrow[r] = lrow[r] * alpha[r] + rs;
      mrow[r] = mn;
    }
#pragma unroll
    for (int i = 0; i < 8; i++) {
      o[i][0] *= alpha[0]; o[i][1] *= alpha[1];
      o[i][2] *= alpha[2]; o[i][3] *= alpha[3];
    }
    bf16* pw = sP[w];
#pragma unroll
    for (int r = 0; r < 4; r++) {
      int prow = quad * 4 + r;
      pw[prow * 32 + l16]      = (bf16)s0[r];
      pw[prow * 32 + 16 + l16] = (bf16)s1[r];
    }
    bf16x8 pa = *(const bf16x8*)(pw + l16 * 32 + quad * 8);
#pragma unroll
    for (int nt = 0; nt < 8; nt++) {
      bf16x8 bv = *(const bf16x8*)(sV + (nt * 16 + l16) * 32 + quad * 8);
      o[nt] = mfma16(pa, bv, o[nt]);
    }
  }
#pragma unroll
  for (int nt = 0; nt < 8; nt++)
#pragma unroll
    for (int r = 0; r < 4; r++) {
      int qg = qlo + quad * 4 + r;
      attn_out[(bh * N_ + qg) * DH_ + nt * 16 + l16] = o[nt][r] / lrow[r];
    }
}

// ------- MFMA retrieval (q & k paths) + gate-combine + vnew -------
// grid (N/64, H, B); 4 waves x 16 n-rows; B-operand = mkvT tile in LDS
#define SMT_STRIDE 136  // 128 + 8 pad: 16B-aligned rows, breaks bank conflicts
__global__ __launch_bounds__(256) void k_retrieve2(const float* __restrict__ qkv,
                                                   const bf16* __restrict__ mkvT,
                                                   const float* __restrict__ qden,
                                                   const float* __restrict__ kden,
                                                   const float* __restrict__ attn,
                                                   const float* __restrict__ hg,
                                                   bf16* __restrict__ comb,
                                                   bf16* __restrict__ vnew) {
  __shared__ __align__(16) bf16 smT[DH_ * SMT_STRIDE];
  int h = blockIdx.y, b = blockIdx.z;
  size_t bh = (size_t)b * H_ + h;
  int t = threadIdx.x;
  int w = t >> 6, lane = t & 63, quad = lane >> 4, l16 = lane & 15;
  int n0 = blockIdx.x * 64;

  {  // stage mkvT [128][128] bf16 -> smT rows of SMT_STRIDE (17 uint4/row)
    const uint4* src = (const uint4*)(mkvT + bh * DH_ * DH_);
    uint4* dst = (uint4*)smT;
#pragma unroll
    for (int it = 0; it < 8; it++) {
      int i = t + it * 256;          // 2048 uint4 total
      int row = i >> 4, col = i & 15;
      dst[row * 17 + col] = src[i];
    }
  }

  // A fragments: qf/kf features in-register (row n = n0 + w*16 + l16)
  int nrow = n0 + w * 16 + l16;
  const float* base = qkv + ((size_t)b * N_ + nrow) * NO_ + h * DH_;
  bf16x8 qa[4], ka[4];
#pragma unroll
  for (int s = 0; s < 4; s++) {
    int k0 = s * 32 + quad * 8;
    float4 q0 = *(const float4*)(base + k0);
    float4 q1 = *(const float4*)(base + k0 + 4);
    float4 k0v = *(const float4*)(base + D_ + k0);
    float4 k1v = *(const float4*)(base + D_ + k0 + 4);
    bf16x8 qo, ko;
    qo[0]=(bf16)elu1(q0.x); qo[1]=(bf16)elu1(q0.y); qo[2]=(bf16)elu1(q0.z); qo[3]=(bf16)elu1(q0.w);
    qo[4]=(bf16)elu1(q1.x); qo[5]=(bf16)elu1(q1.y); qo[6]=(bf16)elu1(q1.z); qo[7]=(bf16)elu1(q1.w);
    ko[0]=(bf16)elu1(k0v.x); ko[1]=(bf16)elu1(k0v.y); ko[2]=(bf16)elu1(k0v.z); ko[3]=(bf16)elu1(k0v.w);
    ko[4]=(bf16)elu1(k1v.x); ko[5]=(bf16)elu1(k1v.y); ko[6]=(bf16)elu1(k1v.z); ko[7]=(bf16)elu1(k1v.w);
    qa[s] = qo; ka[s] = ko;
  }

  __syncthreads();
  f32x4 zf = {0.f, 0.f, 0.f, 0.f};
  f32x4 accq[8], acck[8];
#pragma unroll
  for (int vt = 0; vt < 8; vt++) { accq[vt] = zf; acck[vt] = zf; }
#pragma unroll
  for (int vt = 0; vt < 8; vt++) {
#pragma unroll
    for (int s = 0; s < 4; s++) {
      bf16x8 bfr = *(const bf16x8*)(smT + (vt * 16 + l16) * SMT_STRIDE + s * 32 + quad * 8);
      accq[vt] = mfma16(qa[s], bfr, accq[vt]);
      acck[vt] = mfma16(ka[s], bfr, acck[vt]);
    }
  }

  float g = 1.f / (1.f + __expf(-hg[h]));
#pragma unroll
  for (int r = 0; r < 4; r++) {
    int n = n0 + w * 16 + quad * 4 + r;
    size_t m = (size_t)b * N_ + n;
    float qd = fmaxf(qden[bh * N_ + n], 1e-10f);
    float kd = fmaxf(kden[bh * N_ + n], 1e-10f);
#pragma unroll
    for (int vt = 0; vt < 8; vt++) {
      int v = vt * 16 + l16;
      float mo = accq[vt][r] / qd;
      float ov = attn[(bh * N_ + n) * DH_ + v];
      comb[m * D_ + h * DH_ + v] = (bf16)(ov * g + mo * (1.f - g));
      float vv = qkv[m * NO_ + 2 * D_ + h * DH_ + v];
      vnew[(bh * N_ + n) * DH_ + v] = (bf16)(vv - acck[vt][r] / kd);
    }
  }
}

// ---------------- init outputs new_kv/new_norm with memories ----------------
__global__ void k_init_out(const float* __restrict__ mem_kv, const float* __restrict__ mem_norm,
                           float* __restrict__ out_kv, float* __restrict__ out_norm) {
  int i = blockIdx.x * 256 + threadIdx.x;
  if (i < B_ * H_ * DH_ * DH_) out_kv[i] = mem_kv[i];
  if (i < B_ * H_ * DH_) out_norm[i] = mem_norm[i];
}

// ---------------- new_kv partial: kf^T @ vnew over an n-chunk --------------
__global__ __launch_bounds__(256) void k_newkv(const bf16* __restrict__ kf,
                                               const bf16* __restrict__ vnew,
                                               float* __restrict__ out_kv) {
  __shared__ __align__(16) bf16 skf[64 * DH_];
  __shared__ __align__(16) bf16 svn[64 * DH_];
  int chunk = blockIdx.x;
  int h = blockIdx.y, b = blockIdx.z;
  size_t bh = (size_t)b * H_ + h;
  int t = threadIdx.x;
  int k = t & 127, vh = t >> 7;
  float acc[64];
#pragma unroll
  for (int i = 0; i < 64; i++) acc[i] = 0.f;
  for (int sub = 0; sub < 4; sub++) {
    size_t nbase = (size_t)chunk * 256 + sub * 64;
    __syncthreads();
    const uint4* s1 = (const uint4*)(kf + (bh * N_ + nbase) * DH_);
    const uint4* s2 = (const uint4*)(vnew + (bh * N_ + nbase) * DH_);
    uint4* d1 = (uint4*)skf;
    uint4* d2 = (uint4*)svn;
    for (int i = t; i < 64 * DH_ / 8; i += 256) { d1[i] = s1[i]; d2[i] = s2[i]; }
    __syncthreads();
    for (int n = 0; n < 64; n++) {
      float kv = (float)skf[n * DH_ + k];
      const bf16x8* vrow8 = (const bf16x8*)(svn + n * DH_ + vh * 64);
#pragma unroll
      for (int i8 = 0; i8 < 8; i8++) {
        bf16x8 vv = vrow8[i8];
#pragma unroll
        for (int e = 0; e < 8; e++) acc[i8 * 8 + e] += kv * (float)vv[e];
      }
    }
  }
  float* orow = out_kv + (bh * DH_ + k) * DH_ + vh * 64;
#pragma unroll
  for (int i = 0; i < 64; i++) atomicAdd(orow + i, acc[i]);
}

// ---------------- new_norm partial: sum_n elu(k)+1 (fp32 from qkv) ---------
__global__ void k_newnorm(const float* __restrict__ qkv, float* __restrict__ out_norm) {
  int chunk = blockIdx.x;
  int h = blockIdx.y, b = blockIdx.z;
  int k = threadIdx.x;  // 128
  size_t bh = (size_t)b * H_ + h;
  float acc = 0.f;
  for (int i = 0; i < 256; i++) {
    size_t n = (size_t)chunk * 256 + i;
    float kv = qkv[((size_t)b * N_ + n) * NO_ + D_ + h * DH_ + k];
    acc += elu1(kv);
  }
  atomicAdd(out_norm + bh * DH_ + k, acc);
}

extern "C" void kernel_launch(void* const* d_in, const int* in_sizes, int n_in,
                              void* d_out, int out_size, void* d_ws, size_t ws_size,
                              hipStream_t stream) {
  const float* x        = (const float*)d_in[0];
  const float* gamma    = (const float*)d_in[1];
  const float* w_qkv    = (const float*)d_in[2];
  const float* w_out    = (const float*)d_in[3];
  const float* hg       = (const float*)d_in[4];
  const float* mem_kv   = (const float*)d_in[5];
  const float* mem_norm = (const float*)d_in[6];
  float* out      = (float*)d_out;
  float* out_kv   = out + (size_t)B_ * N_ * D_;
  float* out_norm = out_kv + (size_t)B_ * H_ * DH_ * DH_;

  char* ws = (char*)d_ws;
  size_t off = 0;
  auto alloc = [&](size_t bytes) -> void* {
    void* p = ws + off;
    off += (bytes + 255) & ~(size_t)255;
    return p;
  };
  bf16*  xn   = (bf16*)alloc((size_t)B_ * N_ * D_ * 2);
  bf16*  wqb  = (bf16*)alloc((size_t)NO_ * D_ * 2);
  bf16*  wob  = (bf16*)alloc((size_t)D_ * D_ * 2);
  float* qkv  = (float*)alloc((size_t)B_ * N_ * NO_ * 4);
  bf16*  qr   = (bf16*)alloc((size_t)B_ * H_ * N_ * DH_ * 2);
  bf16*  kr   = (bf16*)alloc((size_t)B_ * H_ * N_ * DH_ * 2);
  bf16*  vT   = (bf16*)alloc((size_t)B_ * H_ * DH_ * N_ * 2);
  bf16*  kf   = (bf16*)alloc((size_t)B_ * H_ * N_ * DH_ * 2);
  bf16*  vnew = (bf16*)alloc((size_t)B_ * H_ * N_ * DH_ * 2);
  float* qden = (float*)alloc((size_t)B_ * H_ * N_ * 4);
  float* kden = (float*)alloc((size_t)B_ * H_ * N_ * 4);
  float* attn = (float*)alloc((size_t)B_ * H_ * N_ * DH_ * 4);
  bf16*  comb = (bf16*)alloc((size_t)B_ * N_ * D_ * 2);
  bf16*  mkvT = (bf16*)alloc((size_t)B_ * H_ * DH_ * DH_ * 2);
  (void)in_sizes; (void)n_in; (void)out_size; (void)ws_size;

  k_rmsnorm<<<dim3(B_ * N_), 256, 0, stream>>>(x, gamma, xn);
  k_cvt4<<<(NO_ * D_ / 4 + 255) / 256, 256, 0, stream>>>((const float4*)w_qkv, (bf16x4*)wqb, NO_ * D_ / 4);
  k_cvt4<<<(D_ * D_ / 4 + 255) / 256, 256, 0, stream>>>((const float4*)w_out, (bf16x4*)wob, D_ * D_ / 4);
  k_mkvT<<<dim3(B_ * H_), 256, 0, stream>>>(mem_kv, mkvT);
  k_gemm_bt<<<dim3(NO_ / 128, B_ * N_ / 128), 256, 0, stream>>>(xn, wqb, qkv, B_ * N_, NO_, D_);
  k_prep<<<dim3(N_, H_, B_), 128, 0, stream>>>(qkv, mem_norm, qr, kr, vT, kf, qden, kden);
  k_attn<<<dim3(N_ / 64, H_, B_), 256, 0, stream>>>(qr, kr, vT, attn);
  k_retrieve2<<<dim3(N_ / 64, H_, B_), 256, 0, stream>>>(qkv, mkvT, qden, kden, attn, hg, comb, vnew);
  k_gemm_bt<<<dim3(D_ / 128, B_ * N_ / 128), 256, 0, stream>>>(comb, wob, out, B_ * N_, D_, D_);
  k_init_out<<<(B_ * H_ * DH_ * DH_ + 255) / 256, 256, 0, stream>>>(mem_kv, mem_norm, out_kv, out_norm);
  k_newkv<<<dim3(N_ / 256, H_, B_), 256, 0, stream>>>(kf, vnew, out_kv);
  k_newnorm<<<dim3(N_ / 256, H_, B_), 128, 0, stream>>>(qkv, out_norm);
}

// Round 3
// 467.861 us; speedup vs baseline: 1.8787x; 1.3426x over previous
//
#include <hip/hip_runtime.h>
#include <hip/hip_bf16.h>

#define B_ 2
#define N_ 2048
#define H_ 8
#define DH_ 128
#define D_ 1024
#define NO_ 3072
#define SCALE_ 0.08838834764831845f

typedef __bf16 bf16;
typedef __bf16 bf16x4 __attribute__((ext_vector_type(4)));
typedef __bf16 bf16x8 __attribute__((ext_vector_type(8)));
typedef float f32x4 __attribute__((ext_vector_type(4)));

__device__ inline f32x4 mfma16(bf16x8 a, bf16x8 b, f32x4 c) {
  return __builtin_amdgcn_mfma_f32_16x16x32_bf16(a, b, c, 0, 0, 0);
}

__device__ inline float elu1(float x) { return x > 0.f ? x + 1.f : __expf(x); }

// ---------------- RMSNorm: x[4096][1024] -> xn bf16 ----------------
__global__ __launch_bounds__(256) void k_rmsnorm(const float* __restrict__ x,
                                                 const float* __restrict__ gamma,
                                                 bf16* __restrict__ xn) {
  int row = blockIdx.x;
  int t = threadIdx.x;
  const float4* xr = (const float4*)(x + (size_t)row * D_);
  float4 xv = xr[t];
  float ss = xv.x*xv.x + xv.y*xv.y + xv.z*xv.z + xv.w*xv.w;
#pragma unroll
  for (int m = 1; m < 64; m <<= 1) ss += __shfl_xor(ss, m);
  __shared__ float sred[4];
  if ((t & 63) == 0) sred[t >> 6] = ss;
  __syncthreads();
  float tot = sred[0] + sred[1] + sred[2] + sred[3];
  float scale = 32.0f / fmaxf(sqrtf(tot), 1e-12f);
  float4 gv = ((const float4*)gamma)[t];
  bf16x4 ov;
  ov[0] = (bf16)(xv.x * scale * gv.x);
  ov[1] = (bf16)(xv.y * scale * gv.y);
  ov[2] = (bf16)(xv.z * scale * gv.z);
  ov[3] = (bf16)(xv.w * scale * gv.w);
  *(bf16x4*)(xn + (size_t)row * D_ + t * 4) = ov;
}

// ---------------- fp32 -> bf16 convert ----------------
__global__ void k_cvt4(const float4* __restrict__ in, bf16x4* __restrict__ out, int n4) {
  int i = blockIdx.x * blockDim.x + threadIdx.x;
  if (i < n4) {
    float4 v = in[i];
    bf16x4 o;
    o[0] = (bf16)v.x; o[1] = (bf16)v.y; o[2] = (bf16)v.z; o[3] = (bf16)v.w;
    out[i] = o;
  }
}

// ---- mem_kv [bh][k][v] fp32 -> mkvT [bh][v][k] bf16 (global transpose) ----
__global__ __launch_bounds__(256) void k_mkvT(const float* __restrict__ mem_kv,
                                              bf16* __restrict__ mkvT) {
  int bh = blockIdx.x;
  int t = threadIdx.x;
  int v = t & 127, khalf = t >> 7;
  const float* src = mem_kv + (size_t)bh * DH_ * DH_;
  bf16* dst = mkvT + (size_t)bh * DH_ * DH_ + (size_t)v * DH_ + khalf * 64;
#pragma unroll
  for (int kk8 = 0; kk8 < 8; kk8++) {
    int k0 = khalf * 64 + kk8 * 8;
    bf16x8 o;
#pragma unroll
    for (int e = 0; e < 8; e++) o[e] = (bf16)src[(size_t)(k0 + e) * DH_ + v];
    *(bf16x8*)(dst + kk8 * 8) = o;
  }
}

// ---- batched bf16 transpose: in [bh][R][C] -> out [bh][C][R], 64x64 tiles ----
__global__ __launch_bounds__(256) void k_transp(const bf16* __restrict__ in,
                                                bf16* __restrict__ out, int R, int C) {
  __shared__ bf16 tile[64][72];  // +8 pad
  int r0 = blockIdx.x * 64, c0 = blockIdx.y * 64;
  const bf16* src = in + (size_t)blockIdx.z * R * C;
  bf16* dst = out + (size_t)blockIdx.z * R * C;
  int t = threadIdx.x;
#pragma unroll
  for (int i = t; i < 512; i += 256) {
    int r = i >> 3, cu = i & 7;
    *(uint4*)&tile[r][cu * 8] = *(const uint4*)(src + (size_t)(r0 + r) * C + c0 + cu * 8);
  }
  __syncthreads();
#pragma unroll
  for (int i = t; i < 512; i += 256) {
    int c = i >> 3, ru = i & 7;
    bf16x8 o;
#pragma unroll
    for (int e = 0; e < 8; e++) o[e] = tile[ru * 8 + e][c];
    *(bf16x8*)(dst + (size_t)(c0 + c) * R + r0 + ru * 8) = o;
  }
}

// ---------------- C[M][N] = A[M][K] @ B[N][K]^T  (bf16 in, fp32 out) -------
__global__ __launch_bounds__(256) void k_gemm_bt(const bf16* __restrict__ A,
                                                 const bf16* __restrict__ B,
                                                 float* __restrict__ C,
                                                 int M, int Nn, int K) {
  __shared__ __align__(16) bf16 sA[128 * 32];
  __shared__ __align__(16) bf16 sB[128 * 32];
  int t = threadIdx.x;
  int w = t >> 6, lane = t & 63, quad = lane >> 4, l16 = lane & 15;
  int m0 = blockIdx.y * 128, n0 = blockIdx.x * 128;
  int wr = (w & 1) * 64, wc = (w >> 1) * 64;
  f32x4 zf = {0.f, 0.f, 0.f, 0.f};
  f32x4 acc[4][4];
#pragma unroll
  for (int a = 0; a < 4; a++)
#pragma unroll
    for (int c = 0; c < 4; c++) acc[a][c] = zf;
  int trow = t >> 2, tc = t & 3;
  for (int k0 = 0; k0 < K; k0 += 32) {
    __syncthreads();
    ((uint4*)sA)[trow * 4 + tc]        = *((const uint4*)(A + (size_t)(m0 + trow) * K + k0) + tc);
    ((uint4*)sA)[(trow + 64) * 4 + tc] = *((const uint4*)(A + (size_t)(m0 + trow + 64) * K + k0) + tc);
    ((uint4*)sB)[trow * 4 + tc]        = *((const uint4*)(B + (size_t)(n0 + trow) * K + k0) + tc);
    ((uint4*)sB)[(trow + 64) * 4 + tc] = *((const uint4*)(B + (size_t)(n0 + trow + 64) * K + k0) + tc);
    __syncthreads();
    bf16x8 af[4], bfr[4];
#pragma unroll
    for (int mt = 0; mt < 4; mt++)
      af[mt] = *(const bf16x8*)(sA + (wr + mt * 16 + l16) * 32 + quad * 8);
#pragma unroll
    for (int nt = 0; nt < 4; nt++)
      bfr[nt] = *(const bf16x8*)(sB + (wc + nt * 16 + l16) * 32 + quad * 8);
#pragma unroll
    for (int mt = 0; mt < 4; mt++)
#pragma unroll
      for (int nt = 0; nt < 4; nt++)
        acc[mt][nt] = mfma16(af[mt], bfr[nt], acc[mt][nt]);
  }
#pragma unroll
  for (int mt = 0; mt < 4; mt++)
#pragma unroll
    for (int nt = 0; nt < 4; nt++) {
      int row = m0 + wr + mt * 16 + quad * 4;
      int col = n0 + wc + nt * 16 + l16;
      float* cp = C + (size_t)row * Nn + col;
#pragma unroll
      for (int r = 0; r < 4; r++) cp[(size_t)r * Nn] = acc[mt][nt][r];
    }
}

// ---------------- prep: RoPE(q,k), kf, v^T, retrieval denominators --------
__global__ void k_prep(const float* __restrict__ qkv,
                       const float* __restrict__ mem_norm,
                       bf16* __restrict__ qr, bf16* __restrict__ kr,
                       bf16* __restrict__ vT, bf16* __restrict__ kf,
                       float* __restrict__ qden, float* __restrict__ kden) {
  int n = blockIdx.x;
  int h = blockIdx.y;
  int b = blockIdx.z;
  int d = threadIdx.x;  // 128
  size_t m = (size_t)b * N_ + n;
  const float* base = qkv + m * NO_ + h * DH_;
  float q = base[d];
  float k = base[D_ + d];
  float v = base[2 * D_ + d];
  int j = d >> 1;
  float inv_freq = __powf(10000.0f, -(float)(2 * j) * (1.0f / 128.0f));
  float ang = (float)n * inv_freq;
  float sn, cs;
  __sincosf(ang, &sn, &cs);
  float qs = q * SCALE_;
  float qp = __shfl_xor(qs, 1);
  float qrot = (d & 1) ? qp : -qp;
  float kp = __shfl_xor(k, 1);
  float krot = (d & 1) ? kp : -kp;
  size_t bh = (size_t)b * H_ + h;
  size_t ro = (bh * N_ + n) * DH_ + d;
  qr[ro] = (bf16)(qs * cs + qrot * sn);
  kr[ro] = (bf16)(k * cs + krot * sn);
  float kfv = elu1(k);
  kf[ro] = (bf16)kfv;
  vT[(bh * DH_ + d) * N_ + n] = (bf16)v;
  float qfv = elu1(q);
  float mn = mem_norm[bh * DH_ + d];
  float pq = qfv * mn;
  float pk = kfv * mn;
#pragma unroll
  for (int msk = 1; msk < 64; msk <<= 1) {
    pq += __shfl_xor(pq, msk);
    pk += __shfl_xor(pk, msk);
  }
  __shared__ float rq[2], rk[2];
  if ((d & 63) == 0) { rq[d >> 6] = pq; rk[d >> 6] = pk; }
  __syncthreads();
  if (d == 0) {
    qden[bh * N_ + n] = rq[0] + rq[1];
    kden[bh * N_ + n] = rk[0] + rk[1];
  }
}

// ---------------- flash attention (causal), bf16 MFMA ----------------
__global__ __launch_bounds__(256) void k_attn(const bf16* __restrict__ qr,
                                              const bf16* __restrict__ kr,
                                              const bf16* __restrict__ vT,
                                              float* __restrict__ attn_out) {
  __shared__ __align__(16) bf16 sK[32 * 128];   // [key][d]
  __shared__ __align__(16) bf16 sV[128 * 32];   // [d][key]
  __shared__ __align__(16) bf16 sP[4][16 * 32]; // per-wave [qrow][key]
  int qt = blockIdx.x;
  size_t bh = (size_t)blockIdx.z * H_ + blockIdx.y;
  int t = threadIdx.x;
  int w = t >> 6, lane = t & 63, quad = lane >> 4, l16 = lane & 15;
  int qlo = qt * 64 + w * 16;

  bf16x8 qfrag[4];
  const bf16* qrow = qr + (bh * N_ + qlo + l16) * DH_;
#pragma unroll
  for (int s = 0; s < 4; s++) qfrag[s] = *(const bf16x8*)(qrow + s * 32 + quad * 8);

  f32x4 zf = {0.f, 0.f, 0.f, 0.f};
  f32x4 o[8];
#pragma unroll
  for (int i = 0; i < 8; i++) o[i] = zf;
  float mrow[4] = {-1e30f, -1e30f, -1e30f, -1e30f};
  float lrow[4] = {0.f, 0.f, 0.f, 0.f};

  int ntiles = 2 * qt + 2;
  int krow = t >> 4, kc8 = t & 15;
  int vrow = t >> 2, vc = t & 3;
  for (int jt = 0; jt < ntiles; jt++) {
    __syncthreads();
    {
      ((uint4*)sK)[krow * 16 + kc8] =
          *((const uint4*)(kr + (bh * N_ + (size_t)jt * 32 + krow) * DH_) + kc8);
      ((uint4*)sK)[(16 + krow) * 16 + kc8] =
          *((const uint4*)(kr + (bh * N_ + (size_t)jt * 32 + 16 + krow) * DH_) + kc8);
      ((uint4*)sV)[vrow * 4 + vc] =
          *((const uint4*)(vT + (bh * DH_ + vrow) * N_ + (size_t)jt * 32) + vc);
      ((uint4*)sV)[(64 + vrow) * 4 + vc] =
          *((const uint4*)(vT + (bh * DH_ + 64 + vrow) * N_ + (size_t)jt * 32) + vc);
    }
    __syncthreads();
    if (jt * 32 > qlo + 15) continue;

    f32x4 s0 = zf, s1 = zf;
#pragma unroll
    for (int s = 0; s < 4; s++) {
      bf16x8 b0 = *(const bf16x8*)(sK + l16 * 128 + s * 32 + quad * 8);
      bf16x8 b1 = *(const bf16x8*)(sK + (16 + l16) * 128 + s * 32 + quad * 8);
      s0 = mfma16(qfrag[s], b0, s0);
      s1 = mfma16(qfrag[s], b1, s1);
    }
    if (jt * 32 + 31 > qlo) {
#pragma unroll
      for (int r = 0; r < 4; r++) {
        int qg = qlo + quad * 4 + r;
        int kg = jt * 32 + l16;
        if (kg > qg)      s0[r] = -1e30f;
        if (kg + 16 > qg) s1[r] = -1e30f;
      }
    }
    float alpha[4];
#pragma unroll
    for (int r = 0; r < 4; r++) {
      float tm = fmaxf(s0[r], s1[r]);
      tm = fmaxf(tm, __shfl_xor(tm, 1));
      tm = fmaxf(tm, __shfl_xor(tm, 2));
      tm = fmaxf(tm, __shfl_xor(tm, 4));
      tm = fmaxf(tm, __shfl_xor(tm, 8));
      float mn = fmaxf(mrow[r], tm);
      alpha[r] = __expf(mrow[r] - mn);
      float p0 = __expf(s0[r] - mn);
      float p1 = __expf(s1[r] - mn);
      s0[r] = p0; s1[r] = p1;
      float rs = p0 + p1;
      rs += __shfl_xor(rs, 1);
      rs += __shfl_xor(rs, 2);
      rs += __shfl_xor(rs, 4);
      rs += __shfl_xor(rs, 8);
      lrow[r] = lrow[r] * alpha[r] + rs;
      mrow[r] = mn;
    }
#pragma unroll
    for (int i = 0; i < 8; i++) {
      o[i][0] *= alpha[0]; o[i][1] *= alpha[1];
      o[i][2] *= alpha[2]; o[i][3] *= alpha[3];
    }
    bf16* pw = sP[w];
#pragma unroll
    for (int r = 0; r < 4; r++) {
      int prow = quad * 4 + r;
      pw[prow * 32 + l16]      = (bf16)s0[r];
      pw[prow * 32 + 16 + l16] = (bf16)s1[r];
    }
    bf16x8 pa = *(const bf16x8*)(pw + l16 * 32 + quad * 8);
#pragma unroll
    for (int nt = 0; nt < 8; nt++) {
      bf16x8 bv = *(const bf16x8*)(sV + (nt * 16 + l16) * 32 + quad * 8);
      o[nt] = mfma16(pa, bv, o[nt]);
    }
  }
#pragma unroll
  for (int nt = 0; nt < 8; nt++)
#pragma unroll
    for (int r = 0; r < 4; r++) {
      int qg = qlo + quad * 4 + r;
      attn_out[(bh * N_ + qg) * DH_ + nt * 16 + l16] = o[nt][r] / lrow[r];
    }
}

// ------- MFMA retrieval (q & k paths) + gate-combine + vnew -------
#define SMT_STRIDE 136
__global__ __launch_bounds__(256) void k_retrieve2(const float* __restrict__ qkv,
                                                   const bf16* __restrict__ mkvT,
                                                   const float* __restrict__ qden,
                                                   const float* __restrict__ kden,
                                                   const float* __restrict__ attn,
                                                   const float* __restrict__ hg,
                                                   bf16* __restrict__ comb,
                                                   bf16* __restrict__ vnew) {
  __shared__ __align__(16) bf16 smT[DH_ * SMT_STRIDE];
  int h = blockIdx.y, b = blockIdx.z;
  size_t bh = (size_t)b * H_ + h;
  int t = threadIdx.x;
  int w = t >> 6, lane = t & 63, quad = lane >> 4, l16 = lane & 15;
  int n0 = blockIdx.x * 64;

  {
    const uint4* src = (const uint4*)(mkvT + bh * DH_ * DH_);
    uint4* dst = (uint4*)smT;
#pragma unroll
    for (int it = 0; it < 8; it++) {
      int i = t + it * 256;
      int row = i >> 4, col = i & 15;
      dst[row * 17 + col] = src[i];
    }
  }

  int nrow = n0 + w * 16 + l16;
  const float* base = qkv + ((size_t)b * N_ + nrow) * NO_ + h * DH_;
  bf16x8 qa[4], ka[4];
#pragma unroll
  for (int s = 0; s < 4; s++) {
    int k0 = s * 32 + quad * 8;
    float4 q0 = *(const float4*)(base + k0);
    float4 q1 = *(const float4*)(base + k0 + 4);
    float4 k0v = *(const float4*)(base + D_ + k0);
    float4 k1v = *(const float4*)(base + D_ + k0 + 4);
    bf16x8 qo, ko;
    qo[0]=(bf16)elu1(q0.x); qo[1]=(bf16)elu1(q0.y); qo[2]=(bf16)elu1(q0.z); qo[3]=(bf16)elu1(q0.w);
    qo[4]=(bf16)elu1(q1.x); qo[5]=(bf16)elu1(q1.y); qo[6]=(bf16)elu1(q1.z); qo[7]=(bf16)elu1(q1.w);
    ko[0]=(bf16)elu1(k0v.x); ko[1]=(bf16)elu1(k0v.y); ko[2]=(bf16)elu1(k0v.z); ko[3]=(bf16)elu1(k0v.w);
    ko[4]=(bf16)elu1(k1v.x); ko[5]=(bf16)elu1(k1v.y); ko[6]=(bf16)elu1(k1v.z); ko[7]=(bf16)elu1(k1v.w);
    qa[s] = qo; ka[s] = ko;
  }

  __syncthreads();
  f32x4 zf = {0.f, 0.f, 0.f, 0.f};
  f32x4 accq[8], acck[8];
#pragma unroll
  for (int vt = 0; vt < 8; vt++) { accq[vt] = zf; acck[vt] = zf; }
#pragma unroll
  for (int vt = 0; vt < 8; vt++) {
#pragma unroll
    for (int s = 0; s < 4; s++) {
      bf16x8 bfr = *(const bf16x8*)(smT + (vt * 16 + l16) * SMT_STRIDE + s * 32 + quad * 8);
      accq[vt] = mfma16(qa[s], bfr, accq[vt]);
      acck[vt] = mfma16(ka[s], bfr, acck[vt]);
    }
  }

  float g = 1.f / (1.f + __expf(-hg[h]));
#pragma unroll
  for (int r = 0; r < 4; r++) {
    int n = n0 + w * 16 + quad * 4 + r;
    size_t m = (size_t)b * N_ + n;
    float qd = fmaxf(qden[bh * N_ + n], 1e-10f);
    float kd = fmaxf(kden[bh * N_ + n], 1e-10f);
#pragma unroll
    for (int vt = 0; vt < 8; vt++) {
      int v = vt * 16 + l16;
      float mo = accq[vt][r] / qd;
      float ov = attn[(bh * N_ + n) * DH_ + v];
      comb[m * D_ + h * DH_ + v] = (bf16)(ov * g + mo * (1.f - g));
      float vv = qkv[m * NO_ + 2 * D_ + h * DH_ + v];
      vnew[(bh * N_ + n) * DH_ + v] = (bf16)(vv - acck[vt][r] / kd);
    }
  }
}

// ---------------- init outputs new_kv/new_norm with memories ----------------
__global__ void k_init_out(const float* __restrict__ mem_kv, const float* __restrict__ mem_norm,
                           float* __restrict__ out_kv, float* __restrict__ out_norm) {
  int i = blockIdx.x * 256 + threadIdx.x;
  if (i < B_ * H_ * DH_ * DH_) out_kv[i] = mem_kv[i];
  if (i < B_ * H_ * DH_) out_norm[i] = mem_norm[i];
}

// ---- new_kv: out_kv[bh] += kfT[bh][128][2048] @ vnT[bh][128][2048]^T -----
// split-K over n: grid (16, H, B); per block K-chunk = 128
__global__ __launch_bounds__(256) void k_newkv2(const bf16* __restrict__ kfT,
                                                const bf16* __restrict__ vnT,
                                                float* __restrict__ out_kv) {
  __shared__ __align__(16) bf16 sA[128 * 32];
  __shared__ __align__(16) bf16 sB[128 * 32];
  int t = threadIdx.x;
  int w = t >> 6, lane = t & 63, quad = lane >> 4, l16 = lane & 15;
  size_t bh = (size_t)blockIdx.z * H_ + blockIdx.y;
  const bf16* A  = kfT + bh * DH_ * N_;
  const bf16* Bm = vnT + bh * DH_ * N_;
  int wr = (w & 1) * 64, wc = (w >> 1) * 64;
  f32x4 zf = {0.f, 0.f, 0.f, 0.f};
  f32x4 acc[4][4];
#pragma unroll
  for (int a = 0; a < 4; a++)
#pragma unroll
    for (int c = 0; c < 4; c++) acc[a][c] = zf;
  int trow = t >> 2, tc = t & 3;
  int kend = (blockIdx.x + 1) * 128;
  for (int k0 = blockIdx.x * 128; k0 < kend; k0 += 32) {
    __syncthreads();
    ((uint4*)sA)[trow * 4 + tc]        = *((const uint4*)(A + (size_t)trow * N_ + k0) + tc);
    ((uint4*)sA)[(trow + 64) * 4 + tc] = *((const uint4*)(A + (size_t)(trow + 64) * N_ + k0) + tc);
    ((uint4*)sB)[trow * 4 + tc]        = *((const uint4*)(Bm + (size_t)trow * N_ + k0) + tc);
    ((uint4*)sB)[(trow + 64) * 4 + tc] = *((const uint4*)(Bm + (size_t)(trow + 64) * N_ + k0) + tc);
    __syncthreads();
    bf16x8 af[4], bfr[4];
#pragma unroll
    for (int mt = 0; mt < 4; mt++)
      af[mt] = *(const bf16x8*)(sA + (wr + mt * 16 + l16) * 32 + quad * 8);
#pragma unroll
    for (int nt = 0; nt < 4; nt++)
      bfr[nt] = *(const bf16x8*)(sB + (wc + nt * 16 + l16) * 32 + quad * 8);
#pragma unroll
    for (int mt = 0; mt < 4; mt++)
#pragma unroll
      for (int nt = 0; nt < 4; nt++)
        acc[mt][nt] = mfma16(af[mt], bfr[nt], acc[mt][nt]);
  }
  float* obh = out_kv + bh * DH_ * DH_;
#pragma unroll
  for (int mt = 0; mt < 4; mt++)
#pragma unroll
    for (int nt = 0; nt < 4; nt++) {
      int row = wr + mt * 16 + quad * 4;
      int col = wc + nt * 16 + l16;
#pragma unroll
      for (int r = 0; r < 4; r++)
        atomicAdd(obh + (size_t)(row + r) * DH_ + col, acc[mt][nt][r]);
    }
}

// ---------------- new_norm partial: sum_n elu(k)+1 (fp32 from qkv) ---------
__global__ void k_newnorm(const float* __restrict__ qkv, float* __restrict__ out_norm) {
  int chunk = blockIdx.x;
  int h = blockIdx.y, b = blockIdx.z;
  int k = threadIdx.x;  // 128
  size_t bh = (size_t)b * H_ + h;
  float acc = 0.f;
  for (int i = 0; i < 256; i++) {
    size_t n = (size_t)chunk * 256 + i;
    float kv = qkv[((size_t)b * N_ + n) * NO_ + D_ + h * DH_ + k];
    acc += elu1(kv);
  }
  atomicAdd(out_norm + bh * DH_ + k, acc);
}

extern "C" void kernel_launch(void* const* d_in, const int* in_sizes, int n_in,
                              void* d_out, int out_size, void* d_ws, size_t ws_size,
                              hipStream_t stream) {
  const float* x        = (const float*)d_in[0];
  const float* gamma    = (const float*)d_in[1];
  const float* w_qkv    = (const float*)d_in[2];
  const float* w_out    = (const float*)d_in[3];
  const float* hg       = (const float*)d_in[4];
  const float* mem_kv   = (const float*)d_in[5];
  const float* mem_norm = (const float*)d_in[6];
  float* out      = (float*)d_out;
  float* out_kv   = out + (size_t)B_ * N_ * D_;
  float* out_norm = out_kv + (size_t)B_ * H_ * DH_ * DH_;

  char* ws = (char*)d_ws;
  size_t off = 0;
  auto alloc = [&](size_t bytes) -> void* {
    void* p = ws + off;
    off += (bytes + 255) & ~(size_t)255;
    return p;
  };
  bf16*  xn   = (bf16*)alloc((size_t)B_ * N_ * D_ * 2);
  bf16*  wqb  = (bf16*)alloc((size_t)NO_ * D_ * 2);
  bf16*  wob  = (bf16*)alloc((size_t)D_ * D_ * 2);
  float* qkv  = (float*)alloc((size_t)B_ * N_ * NO_ * 4);
  bf16*  qr   = (bf16*)alloc((size_t)B_ * H_ * N_ * DH_ * 2);
  bf16*  kr   = (bf16*)alloc((size_t)B_ * H_ * N_ * DH_ * 2);
  bf16*  vT   = (bf16*)alloc((size_t)B_ * H_ * DH_ * N_ * 2);
  bf16*  kf   = (bf16*)alloc((size_t)B_ * H_ * N_ * DH_ * 2);
  bf16*  vnew = (bf16*)alloc((size_t)B_ * H_ * N_ * DH_ * 2);
  float* qden = (float*)alloc((size_t)B_ * H_ * N_ * 4);
  float* kden = (float*)alloc((size_t)B_ * H_ * N_ * 4);
  float* attn = (float*)alloc((size_t)B_ * H_ * N_ * DH_ * 4);
  bf16*  comb = (bf16*)alloc((size_t)B_ * N_ * D_ * 2);
  bf16*  mkvT = (bf16*)alloc((size_t)B_ * H_ * DH_ * DH_ * 2);
  bf16*  kfT  = (bf16*)alloc((size_t)B_ * H_ * DH_ * N_ * 2);
  bf16*  vnT  = (bf16*)alloc((size_t)B_ * H_ * DH_ * N_ * 2);
  (void)in_sizes; (void)n_in; (void)out_size; (void)ws_size;

  k_rmsnorm<<<dim3(B_ * N_), 256, 0, stream>>>(x, gamma, xn);
  k_cvt4<<<(NO_ * D_ / 4 + 255) / 256, 256, 0, stream>>>((const float4*)w_qkv, (bf16x4*)wqb, NO_ * D_ / 4);
  k_cvt4<<<(D_ * D_ / 4 + 255) / 256, 256, 0, stream>>>((const float4*)w_out, (bf16x4*)wob, D_ * D_ / 4);
  k_mkvT<<<dim3(B_ * H_), 256, 0, stream>>>(mem_kv, mkvT);
  k_gemm_bt<<<dim3(NO_ / 128, B_ * N_ / 128), 256, 0, stream>>>(xn, wqb, qkv, B_ * N_, NO_, D_);
  k_prep<<<dim3(N_, H_, B_), 128, 0, stream>>>(qkv, mem_norm, qr, kr, vT, kf, qden, kden);
  k_attn<<<dim3(N_ / 64, H_, B_), 256, 0, stream>>>(qr, kr, vT, attn);
  k_retrieve2<<<dim3(N_ / 64, H_, B_), 256, 0, stream>>>(qkv, mkvT, qden, kden, attn, hg, comb, vnew);
  k_gemm_bt<<<dim3(D_ / 128, B_ * N_ / 128), 256, 0, stream>>>(comb, wob, out, B_ * N_, D_, D_);
  k_transp<<<dim3(N_ / 64, DH_ / 64, B_ * H_), 256, 0, stream>>>(kf, kfT, N_, DH_);
  k_transp<<<dim3(N_ / 64, DH_ / 64, B_ * H_), 256, 0, stream>>>(vnew, vnT, N_, DH_);
  k_init_out<<<(B_ * H_ * DH_ * DH_ + 255) / 256, 256, 0, stream>>>(mem_kv, mem_norm, out_kv, out_norm);
  k_newkv2<<<dim3(16, H_, B_), 256, 0, stream>>>(kfT, vnT, out_kv);
  k_newnorm<<<dim3(N_ / 256, H_, B_), 128, 0, stream>>>(qkv, out_norm);
}

// Round 4
// 376.170 us; speedup vs baseline: 2.3367x; 1.2438x over previous
//
#include <hip/hip_runtime.h>
#include <hip/hip_bf16.h>

#define B_ 2
#define N_ 2048
#define H_ 8
#define DH_ 128
#define D_ 1024
#define NO_ 3072
#define SCALE_ 0.08838834764831845f

typedef __bf16 bf16;
typedef __bf16 bf16x4 __attribute__((ext_vector_type(4)));
typedef __bf16 bf16x8 __attribute__((ext_vector_type(8)));
typedef float f32x4 __attribute__((ext_vector_type(4)));

__device__ inline f32x4 mfma16(bf16x8 a, bf16x8 b, f32x4 c) {
  return __builtin_amdgcn_mfma_f32_16x16x32_bf16(a, b, c, 0, 0, 0);
}

__device__ inline float elu1(float x) { return x > 0.f ? x + 1.f : __expf(x); }

// ---------------- RMSNorm: x[4096][1024] -> xn bf16 ----------------
__global__ __launch_bounds__(256) void k_rmsnorm(const float* __restrict__ x,
                                                 const float* __restrict__ gamma,
                                                 bf16* __restrict__ xn) {
  int row = blockIdx.x;
  int t = threadIdx.x;
  const float4* xr = (const float4*)(x + (size_t)row * D_);
  float4 xv = xr[t];
  float ss = xv.x*xv.x + xv.y*xv.y + xv.z*xv.z + xv.w*xv.w;
#pragma unroll
  for (int m = 1; m < 64; m <<= 1) ss += __shfl_xor(ss, m);
  __shared__ float sred[4];
  if ((t & 63) == 0) sred[t >> 6] = ss;
  __syncthreads();
  float tot = sred[0] + sred[1] + sred[2] + sred[3];
  float scale = 32.0f / fmaxf(sqrtf(tot), 1e-12f);
  float4 gv = ((const float4*)gamma)[t];
  bf16x4 ov;
  ov[0] = (bf16)(xv.x * scale * gv.x);
  ov[1] = (bf16)(xv.y * scale * gv.y);
  ov[2] = (bf16)(xv.z * scale * gv.z);
  ov[3] = (bf16)(xv.w * scale * gv.w);
  *(bf16x4*)(xn + (size_t)row * D_ + t * 4) = ov;
}

// ---------------- fp32 -> bf16 convert ----------------
__global__ void k_cvt4(const float4* __restrict__ in, bf16x4* __restrict__ out, int n4) {
  int i = blockIdx.x * blockDim.x + threadIdx.x;
  if (i < n4) {
    float4 v = in[i];
    bf16x4 o;
    o[0] = (bf16)v.x; o[1] = (bf16)v.y; o[2] = (bf16)v.z; o[3] = (bf16)v.w;
    out[i] = o;
  }
}

// ---- mem_kv [bh][k][v] fp32 -> mkvT [bh][v][k] bf16 (global transpose) ----
__global__ __launch_bounds__(256) void k_mkvT(const float* __restrict__ mem_kv,
                                              bf16* __restrict__ mkvT) {
  int bh = blockIdx.x;
  int t = threadIdx.x;
  int v = t & 127, khalf = t >> 7;
  const float* src = mem_kv + (size_t)bh * DH_ * DH_;
  bf16* dst = mkvT + (size_t)bh * DH_ * DH_ + (size_t)v * DH_ + khalf * 64;
#pragma unroll
  for (int kk8 = 0; kk8 < 8; kk8++) {
    int k0 = khalf * 64 + kk8 * 8;
    bf16x8 o;
#pragma unroll
    for (int e = 0; e < 8; e++) o[e] = (bf16)src[(size_t)(k0 + e) * DH_ + v];
    *(bf16x8*)(dst + kk8 * 8) = o;
  }
}

// ---- batched bf16 transpose: in [bh][R][C] -> out [bh][C][R], 64x64 tiles ----
__global__ __launch_bounds__(256) void k_transp(const bf16* __restrict__ in,
                                                bf16* __restrict__ out, int R, int C) {
  __shared__ bf16 tile[64][72];
  int r0 = blockIdx.x * 64, c0 = blockIdx.y * 64;
  const bf16* src = in + (size_t)blockIdx.z * R * C;
  bf16* dst = out + (size_t)blockIdx.z * R * C;
  int t = threadIdx.x;
#pragma unroll
  for (int i = t; i < 512; i += 256) {
    int r = i >> 3, cu = i & 7;
    *(uint4*)&tile[r][cu * 8] = *(const uint4*)(src + (size_t)(r0 + r) * C + c0 + cu * 8);
  }
  __syncthreads();
#pragma unroll
  for (int i = t; i < 512; i += 256) {
    int c = i >> 3, ru = i & 7;
    bf16x8 o;
#pragma unroll
    for (int e = 0; e < 8; e++) o[e] = tile[ru * 8 + e][c];
    *(bf16x8*)(dst + (size_t)(c0 + c) * R + r0 + ru * 8) = o;
  }
}

// ---------------- C[M][N] = A[M][K] @ B[N][K]^T  (bf16 in, fp32 out) -------
// LDS rows padded 32->40 bf16 (80B: banks step 20/row -> 2-way, free)
#define GSTR 40
__global__ __launch_bounds__(256) void k_gemm_bt(const bf16* __restrict__ A,
                                                 const bf16* __restrict__ B,
                                                 float* __restrict__ C,
                                                 int M, int Nn, int K) {
  __shared__ __align__(16) bf16 sA[128 * GSTR];
  __shared__ __align__(16) bf16 sB[128 * GSTR];
  int t = threadIdx.x;
  int w = t >> 6, lane = t & 63, quad = lane >> 4, l16 = lane & 15;
  int m0 = blockIdx.y * 128, n0 = blockIdx.x * 128;
  int wr = (w & 1) * 64, wc = (w >> 1) * 64;
  f32x4 zf = {0.f, 0.f, 0.f, 0.f};
  f32x4 acc[4][4];
#pragma unroll
  for (int a = 0; a < 4; a++)
#pragma unroll
    for (int c = 0; c < 4; c++) acc[a][c] = zf;
  int trow = t >> 2, tc = t & 3;
  for (int k0 = 0; k0 < K; k0 += 32) {
    __syncthreads();
    ((uint4*)sA)[trow * 5 + tc]        = *((const uint4*)(A + (size_t)(m0 + trow) * K + k0) + tc);
    ((uint4*)sA)[(trow + 64) * 5 + tc] = *((const uint4*)(A + (size_t)(m0 + trow + 64) * K + k0) + tc);
    ((uint4*)sB)[trow * 5 + tc]        = *((const uint4*)(B + (size_t)(n0 + trow) * K + k0) + tc);
    ((uint4*)sB)[(trow + 64) * 5 + tc] = *((const uint4*)(B + (size_t)(n0 + trow + 64) * K + k0) + tc);
    __syncthreads();
    bf16x8 af[4], bfr[4];
#pragma unroll
    for (int mt = 0; mt < 4; mt++)
      af[mt] = *(const bf16x8*)(sA + (wr + mt * 16 + l16) * GSTR + quad * 8);
#pragma unroll
    for (int nt = 0; nt < 4; nt++)
      bfr[nt] = *(const bf16x8*)(sB + (wc + nt * 16 + l16) * GSTR + quad * 8);
#pragma unroll
    for (int mt = 0; mt < 4; mt++)
#pragma unroll
      for (int nt = 0; nt < 4; nt++)
        acc[mt][nt] = mfma16(af[mt], bfr[nt], acc[mt][nt]);
  }
#pragma unroll
  for (int mt = 0; mt < 4; mt++)
#pragma unroll
    for (int nt = 0; nt < 4; nt++) {
      int row = m0 + wr + mt * 16 + quad * 4;
      int col = n0 + wc + nt * 16 + l16;
      float* cp = C + (size_t)row * Nn + col;
#pragma unroll
      for (int r = 0; r < 4; r++) cp[(size_t)r * Nn] = acc[mt][nt][r];
    }
}

// ---------------- prep: RoPE(q,k), kf, v^T, retrieval denominators --------
__global__ void k_prep(const float* __restrict__ qkv,
                       const float* __restrict__ mem_norm,
                       bf16* __restrict__ qr, bf16* __restrict__ kr,
                       bf16* __restrict__ vT, bf16* __restrict__ kf,
                       float* __restrict__ qden, float* __restrict__ kden) {
  int n = blockIdx.x;
  int h = blockIdx.y;
  int b = blockIdx.z;
  int d = threadIdx.x;  // 128
  size_t m = (size_t)b * N_ + n;
  const float* base = qkv + m * NO_ + h * DH_;
  float q = base[d];
  float k = base[D_ + d];
  float v = base[2 * D_ + d];
  int j = d >> 1;
  float inv_freq = __powf(10000.0f, -(float)(2 * j) * (1.0f / 128.0f));
  float ang = (float)n * inv_freq;
  float sn, cs;
  __sincosf(ang, &sn, &cs);
  float qs = q * SCALE_;
  float qp = __shfl_xor(qs, 1);
  float qrot = (d & 1) ? qp : -qp;
  float kp = __shfl_xor(k, 1);
  float krot = (d & 1) ? kp : -kp;
  size_t bh = (size_t)b * H_ + h;
  size_t ro = (bh * N_ + n) * DH_ + d;
  qr[ro] = (bf16)(qs * cs + qrot * sn);
  kr[ro] = (bf16)(k * cs + krot * sn);
  float kfv = elu1(k);
  kf[ro] = (bf16)kfv;
  vT[(bh * DH_ + d) * N_ + n] = (bf16)v;
  float qfv = elu1(q);
  float mn = mem_norm[bh * DH_ + d];
  float pq = qfv * mn;
  float pk = kfv * mn;
#pragma unroll
  for (int msk = 1; msk < 64; msk <<= 1) {
    pq += __shfl_xor(pq, msk);
    pk += __shfl_xor(pk, msk);
  }
  __shared__ float rq[2], rk[2];
  if ((d & 63) == 0) { rq[d >> 6] = pq; rk[d >> 6] = pk; }
  __syncthreads();
  if (d == 0) {
    qden[bh * N_ + n] = rq[0] + rq[1];
    kden[bh * N_ + n] = rk[0] + rk[1];
  }
}

// ---------------- flash attention (causal), bf16 MFMA, K-tile 64 ----------
// 4 waves x 16 q-rows (q-tile 64). Padded LDS: conflict-free (2-way max).
#define KSTR 136  // 128+8, 272B rows
#define VSTR 72   // 64+8, 144B rows
__global__ __launch_bounds__(256) void k_attn(const bf16* __restrict__ qr,
                                              const bf16* __restrict__ kr,
                                              const bf16* __restrict__ vT,
                                              float* __restrict__ attn_out) {
  __shared__ __align__(16) bf16 sK[64 * KSTR];    // [key][d]
  __shared__ __align__(16) bf16 sV[128 * VSTR];   // [d][key]
  __shared__ __align__(16) bf16 sP[4][16 * VSTR]; // per-wave [qrow][key]
  int qt = (int)gridDim.x - 1 - (int)blockIdx.x;  // heavy blocks first
  size_t bh = (size_t)blockIdx.z * H_ + blockIdx.y;
  int t = threadIdx.x;
  int w = t >> 6, lane = t & 63, quad = lane >> 4, l16 = lane & 15;
  int qlo = qt * 64 + w * 16;

  bf16x8 qfrag[4];
  const bf16* qrow = qr + (bh * N_ + qlo + l16) * DH_;
#pragma unroll
  for (int s = 0; s < 4; s++) qfrag[s] = *(const bf16x8*)(qrow + s * 32 + quad * 8);

  f32x4 zf = {0.f, 0.f, 0.f, 0.f};
  f32x4 o[8];
#pragma unroll
  for (int i = 0; i < 8; i++) o[i] = zf;
  float mrow[4] = {-1e30f, -1e30f, -1e30f, -1e30f};
  float lrow[4] = {0.f, 0.f, 0.f, 0.f};

  int ntiles = qt + 1;
  for (int jt = 0; jt < ntiles; jt++) {
    __syncthreads();
    {  // stage K [64][128] and V^T [128][64]
      const uint4* ksrc = (const uint4*)(kr + (bh * N_ + (size_t)jt * 64) * DH_);
#pragma unroll
      for (int p = 0; p < 4; p++) {
        int i = p * 256 + t;
        int row = i >> 4, c16 = i & 15;
        ((uint4*)sK)[row * 17 + c16] = ksrc[row * 16 + c16];
      }
#pragma unroll
      for (int p = 0; p < 4; p++) {
        int i = p * 256 + t;
        int row = i >> 3, c8 = i & 7;
        ((uint4*)sV)[row * 9 + c8] =
            *((const uint4*)(vT + (bh * DH_ + row) * N_ + (size_t)jt * 64) + c8);
      }
    }
    __syncthreads();

    f32x4 sf[4];
#pragma unroll
    for (int nt = 0; nt < 4; nt++) sf[nt] = zf;
#pragma unroll
    for (int s = 0; s < 4; s++) {
#pragma unroll
      for (int nt = 0; nt < 4; nt++) {
        bf16x8 b = *(const bf16x8*)(sK + (nt * 16 + l16) * KSTR + s * 32 + quad * 8);
        sf[nt] = mfma16(qfrag[s], b, sf[nt]);
      }
    }
    if (jt == ntiles - 1) {  // diagonal tile: mask key > q
#pragma unroll
      for (int nt = 0; nt < 4; nt++) {
        int kg = jt * 64 + nt * 16 + l16;
#pragma unroll
        for (int r = 0; r < 4; r++) {
          int qg = qlo + quad * 4 + r;
          if (kg > qg) sf[nt][r] = -1e30f;
        }
      }
    }
    float alpha[4];
#pragma unroll
    for (int r = 0; r < 4; r++) {
      float tm = fmaxf(fmaxf(sf[0][r], sf[1][r]), fmaxf(sf[2][r], sf[3][r]));
      tm = fmaxf(tm, __shfl_xor(tm, 1));
      tm = fmaxf(tm, __shfl_xor(tm, 2));
      tm = fmaxf(tm, __shfl_xor(tm, 4));
      tm = fmaxf(tm, __shfl_xor(tm, 8));
      float mn = fmaxf(mrow[r], tm);
      alpha[r] = __expf(mrow[r] - mn);
      float rs = 0.f;
#pragma unroll
      for (int nt = 0; nt < 4; nt++) {
        float p = __expf(sf[nt][r] - mn);
        sf[nt][r] = p;
        rs += p;
      }
      rs += __shfl_xor(rs, 1);
      rs += __shfl_xor(rs, 2);
      rs += __shfl_xor(rs, 4);
      rs += __shfl_xor(rs, 8);
      lrow[r] = lrow[r] * alpha[r] + rs;
      mrow[r] = mn;
    }
#pragma unroll
    for (int i = 0; i < 8; i++) {
      o[i][0] *= alpha[0]; o[i][1] *= alpha[1];
      o[i][2] *= alpha[2]; o[i][3] *= alpha[3];
    }
    // P: C-layout -> per-wave LDS -> A-operand layout
    bf16* pw = sP[w];
#pragma unroll
    for (int nt = 0; nt < 4; nt++)
#pragma unroll
      for (int r = 0; r < 4; r++)
        pw[(quad * 4 + r) * VSTR + nt * 16 + l16] = (bf16)sf[nt][r];
    bf16x8 pa0 = *(const bf16x8*)(pw + l16 * VSTR + quad * 8);
    bf16x8 pa1 = *(const bf16x8*)(pw + l16 * VSTR + 32 + quad * 8);
#pragma unroll
    for (int vt = 0; vt < 8; vt++) {
      bf16x8 b0 = *(const bf16x8*)(sV + (vt * 16 + l16) * VSTR + quad * 8);
      bf16x8 b1 = *(const bf16x8*)(sV + (vt * 16 + l16) * VSTR + 32 + quad * 8);
      o[vt] = mfma16(pa0, b0, o[vt]);
      o[vt] = mfma16(pa1, b1, o[vt]);
    }
  }
#pragma unroll
  for (int vt = 0; vt < 8; vt++)
#pragma unroll
    for (int r = 0; r < 4; r++) {
      int qg = qlo + quad * 4 + r;
      attn_out[(bh * N_ + qg) * DH_ + vt * 16 + l16] = o[vt][r] / lrow[r];
    }
}

// ------- MFMA retrieval (q & k paths) + gate-combine + vnew -------
#define SMT_STRIDE 136
__global__ __launch_bounds__(256) void k_retrieve2(const float* __restrict__ qkv,
                                                   const bf16* __restrict__ mkvT,
                                                   const float* __restrict__ qden,
                                                   const float* __restrict__ kden,
                                                   const float* __restrict__ attn,
                                                   const float* __restrict__ hg,
                                                   bf16* __restrict__ comb,
                                                   bf16* __restrict__ vnew) {
  __shared__ __align__(16) bf16 smT[DH_ * SMT_STRIDE];
  int h = blockIdx.y, b = blockIdx.z;
  size_t bh = (size_t)b * H_ + h;
  int t = threadIdx.x;
  int w = t >> 6, lane = t & 63, quad = lane >> 4, l16 = lane & 15;
  int n0 = blockIdx.x * 64;

  {
    const uint4* src = (const uint4*)(mkvT + bh * DH_ * DH_);
    uint4* dst = (uint4*)smT;
#pragma unroll
    for (int it = 0; it < 8; it++) {
      int i = t + it * 256;
      int row = i >> 4, col = i & 15;
      dst[row * 17 + col] = src[i];
    }
  }

  int nrow = n0 + w * 16 + l16;
  const float* base = qkv + ((size_t)b * N_ + nrow) * NO_ + h * DH_;
  bf16x8 qa[4], ka[4];
#pragma unroll
  for (int s = 0; s < 4; s++) {
    int k0 = s * 32 + quad * 8;
    float4 q0 = *(const float4*)(base + k0);
    float4 q1 = *(const float4*)(base + k0 + 4);
    float4 k0v = *(const float4*)(base + D_ + k0);
    float4 k1v = *(const float4*)(base + D_ + k0 + 4);
    bf16x8 qo, ko;
    qo[0]=(bf16)elu1(q0.x); qo[1]=(bf16)elu1(q0.y); qo[2]=(bf16)elu1(q0.z); qo[3]=(bf16)elu1(q0.w);
    qo[4]=(bf16)elu1(q1.x); qo[5]=(bf16)elu1(q1.y); qo[6]=(bf16)elu1(q1.z); qo[7]=(bf16)elu1(q1.w);
    ko[0]=(bf16)elu1(k0v.x); ko[1]=(bf16)elu1(k0v.y); ko[2]=(bf16)elu1(k0v.z); ko[3]=(bf16)elu1(k0v.w);
    ko[4]=(bf16)elu1(k1v.x); ko[5]=(bf16)elu1(k1v.y); ko[6]=(bf16)elu1(k1v.z); ko[7]=(bf16)elu1(k1v.w);
    qa[s] = qo; ka[s] = ko;
  }

  __syncthreads();
  f32x4 zf = {0.f, 0.f, 0.f, 0.f};
  f32x4 accq[8], acck[8];
#pragma unroll
  for (int vt = 0; vt < 8; vt++) { accq[vt] = zf; acck[vt] = zf; }
#pragma unroll
  for (int vt = 0; vt < 8; vt++) {
#pragma unroll
    for (int s = 0; s < 4; s++) {
      bf16x8 bfr = *(const bf16x8*)(smT + (vt * 16 + l16) * SMT_STRIDE + s * 32 + quad * 8);
      accq[vt] = mfma16(qa[s], bfr, accq[vt]);
      acck[vt] = mfma16(ka[s], bfr, acck[vt]);
    }
  }

  float g = 1.f / (1.f + __expf(-hg[h]));
#pragma unroll
  for (int r = 0; r < 4; r++) {
    int n = n0 + w * 16 + quad * 4 + r;
    size_t m = (size_t)b * N_ + n;
    float qd = fmaxf(qden[bh * N_ + n], 1e-10f);
    float kd = fmaxf(kden[bh * N_ + n], 1e-10f);
#pragma unroll
    for (int vt = 0; vt < 8; vt++) {
      int v = vt * 16 + l16;
      float mo = accq[vt][r] / qd;
      float ov = attn[(bh * N_ + n) * DH_ + v];
      comb[m * D_ + h * DH_ + v] = (bf16)(ov * g + mo * (1.f - g));
      float vv = qkv[m * NO_ + 2 * D_ + h * DH_ + v];
      vnew[(bh * N_ + n) * DH_ + v] = (bf16)(vv - acck[vt][r] / kd);
    }
  }
}

// ---------------- init outputs new_kv/new_norm with memories ----------------
__global__ void k_init_out(const float* __restrict__ mem_kv, const float* __restrict__ mem_norm,
                           float* __restrict__ out_kv, float* __restrict__ out_norm) {
  int i = blockIdx.x * 256 + threadIdx.x;
  if (i < B_ * H_ * DH_ * DH_) out_kv[i] = mem_kv[i];
  if (i < B_ * H_ * DH_) out_norm[i] = mem_norm[i];
}

// ---- new_kv: out_kv[bh] += kfT[bh] @ vnT[bh]^T, split-K over n ----
__global__ __launch_bounds__(256) void k_newkv2(const bf16* __restrict__ kfT,
                                                const bf16* __restrict__ vnT,
                                                float* __restrict__ out_kv) {
  __shared__ __align__(16) bf16 sA[128 * GSTR];
  __shared__ __align__(16) bf16 sB[128 * GSTR];
  int t = threadIdx.x;
  int w = t >> 6, lane = t & 63, quad = lane >> 4, l16 = lane & 15;
  size_t bh = (size_t)blockIdx.z * H_ + blockIdx.y;
  const bf16* A  = kfT + bh * DH_ * N_;
  const bf16* Bm = vnT + bh * DH_ * N_;
  int wr = (w & 1) * 64, wc = (w >> 1) * 64;
  f32x4 zf = {0.f, 0.f, 0.f, 0.f};
  f32x4 acc[4][4];
#pragma unroll
  for (int a = 0; a < 4; a++)
#pragma unroll
    for (int c = 0; c < 4; c++) acc[a][c] = zf;
  int trow = t >> 2, tc = t & 3;
  int kend = (blockIdx.x + 1) * 128;
  for (int k0 = blockIdx.x * 128; k0 < kend; k0 += 32) {
    __syncthreads();
    ((uint4*)sA)[trow * 5 + tc]        = *((const uint4*)(A + (size_t)trow * N_ + k0) + tc);
    ((uint4*)sA)[(trow + 64) * 5 + tc] = *((const uint4*)(A + (size_t)(trow + 64) * N_ + k0) + tc);
    ((uint4*)sB)[trow * 5 + tc]        = *((const uint4*)(Bm + (size_t)trow * N_ + k0) + tc);
    ((uint4*)sB)[(trow + 64) * 5 + tc] = *((const uint4*)(Bm + (size_t)(trow + 64) * N_ + k0) + tc);
    __syncthreads();
    bf16x8 af[4], bfr[4];
#pragma unroll
    for (int mt = 0; mt < 4; mt++)
      af[mt] = *(const bf16x8*)(sA + (wr + mt * 16 + l16) * GSTR + quad * 8);
#pragma unroll
    for (int nt = 0; nt < 4; nt++)
      bfr[nt] = *(const bf16x8*)(sB + (wc + nt * 16 + l16) * GSTR + quad * 8);
#pragma unroll
    for (int mt = 0; mt < 4; mt++)
#pragma unroll
      for (int nt = 0; nt < 4; nt++)
        acc[mt][nt] = mfma16(af[mt], bfr[nt], acc[mt][nt]);
  }
  float* obh = out_kv + bh * DH_ * DH_;
#pragma unroll
  for (int mt = 0; mt < 4; mt++)
#pragma unroll
    for (int nt = 0; nt < 4; nt++) {
      int row = wr + mt * 16 + quad * 4;
      int col = wc + nt * 16 + l16;
#pragma unroll
      for (int r = 0; r < 4; r++)
        atomicAdd(obh + (size_t)(row + r) * DH_ + col, acc[mt][nt][r]);
    }
}

// ---------------- new_norm partial: sum_n elu(k)+1 (fp32 from qkv) ---------
__global__ void k_newnorm(const float* __restrict__ qkv, float* __restrict__ out_norm) {
  int chunk = blockIdx.x;
  int h = blockIdx.y, b = blockIdx.z;
  int k = threadIdx.x;  // 128
  size_t bh = (size_t)b * H_ + h;
  float acc = 0.f;
  for (int i = 0; i < 256; i++) {
    size_t n = (size_t)chunk * 256 + i;
    float kv = qkv[((size_t)b * N_ + n) * NO_ + D_ + h * DH_ + k];
    acc += elu1(kv);
  }
  atomicAdd(out_norm + bh * DH_ + k, acc);
}

extern "C" void kernel_launch(void* const* d_in, const int* in_sizes, int n_in,
                              void* d_out, int out_size, void* d_ws, size_t ws_size,
                              hipStream_t stream) {
  const float* x        = (const float*)d_in[0];
  const float* gamma    = (const float*)d_in[1];
  const float* w_qkv    = (const float*)d_in[2];
  const float* w_out    = (const float*)d_in[3];
  const float* hg       = (const float*)d_in[4];
  const float* mem_kv   = (const float*)d_in[5];
  const float* mem_norm = (const float*)d_in[6];
  float* out      = (float*)d_out;
  float* out_kv   = out + (size_t)B_ * N_ * D_;
  float* out_norm = out_kv + (size_t)B_ * H_ * DH_ * DH_;

  char* ws = (char*)d_ws;
  size_t off = 0;
  auto alloc = [&](size_t bytes) -> void* {
    void* p = ws + off;
    off += (bytes + 255) & ~(size_t)255;
    return p;
  };
  bf16*  xn   = (bf16*)alloc((size_t)B_ * N_ * D_ * 2);
  bf16*  wqb  = (bf16*)alloc((size_t)NO_ * D_ * 2);
  bf16*  wob  = (bf16*)alloc((size_t)D_ * D_ * 2);
  float* qkv  = (float*)alloc((size_t)B_ * N_ * NO_ * 4);
  bf16*  qr   = (bf16*)alloc((size_t)B_ * H_ * N_ * DH_ * 2);
  bf16*  kr   = (bf16*)alloc((size_t)B_ * H_ * N_ * DH_ * 2);
  bf16*  vT   = (bf16*)alloc((size_t)B_ * H_ * DH_ * N_ * 2);
  bf16*  kf   = (bf16*)alloc((size_t)B_ * H_ * N_ * DH_ * 2);
  bf16*  vnew = (bf16*)alloc((size_t)B_ * H_ * N_ * DH_ * 2);
  float* qden = (float*)alloc((size_t)B_ * H_ * N_ * 4);
  float* kden = (float*)alloc((size_t)B_ * H_ * N_ * 4);
  float* attn = (float*)alloc((size_t)B_ * H_ * N_ * DH_ * 4);
  bf16*  comb = (bf16*)alloc((size_t)B_ * N_ * D_ * 2);
  bf16*  mkvT = (bf16*)alloc((size_t)B_ * H_ * DH_ * DH_ * 2);
  bf16*  kfT  = (bf16*)alloc((size_t)B_ * H_ * DH_ * N_ * 2);
  bf16*  vnT  = (bf16*)alloc((size_t)B_ * H_ * DH_ * N_ * 2);
  (void)in_sizes; (void)n_in; (void)out_size; (void)ws_size;

  k_rmsnorm<<<dim3(B_ * N_), 256, 0, stream>>>(x, gamma, xn);
  k_cvt4<<<(NO_ * D_ / 4 + 255) / 256, 256, 0, stream>>>((const float4*)w_qkv, (bf16x4*)wqb, NO_ * D_ / 4);
  k_cvt4<<<(D_ * D_ / 4 + 255) / 256, 256, 0, stream>>>((const float4*)w_out, (bf16x4*)wob, D_ * D_ / 4);
  k_mkvT<<<dim3(B_ * H_), 256, 0, stream>>>(mem_kv, mkvT);
  k_gemm_bt<<<dim3(NO_ / 128, B_ * N_ / 128), 256, 0, stream>>>(xn, wqb, qkv, B_ * N_, NO_, D_);
  k_prep<<<dim3(N_, H_, B_), 128, 0, stream>>>(qkv, mem_norm, qr, kr, vT, kf, qden, kden);
  k_attn<<<dim3(N_ / 64, H_, B_), 256, 0, stream>>>(qr, kr, vT, attn);
  k_retrieve2<<<dim3(N_ / 64, H_, B_), 256, 0, stream>>>(qkv, mkvT, qden, kden, attn, hg, comb, vnew);
  k_gemm_bt<<<dim3(D_ / 128, B_ * N_ / 128), 256, 0, stream>>>(comb, wob, out, B_ * N_, D_, D_);
  k_transp<<<dim3(N_ / 64, DH_ / 64, B_ * H_), 256, 0, stream>>>(kf, kfT, N_, DH_);
  k_transp<<<dim3(N_ / 64, DH_ / 64, B_ * H_), 256, 0, stream>>>(vnew, vnT, N_, DH_);
  k_init_out<<<(B_ * H_ * DH_ * DH_ + 255) / 256, 256, 0, stream>>>(mem_kv, mem_norm, out_kv, out_norm);
  k_newkv2<<<dim3(16, H_, B_), 256, 0, stream>>>(kfT, vnT, out_kv);
  k_newnorm<<<dim3(N_ / 256, H_, B_), 128, 0, stream>>>(qkv, out_norm);
}

// Round 5
// 369.934 us; speedup vs baseline: 2.3761x; 1.0169x over previous
//
#include <hip/hip_runtime.h>
#include <hip/hip_bf16.h>

#define B_ 2
#define N_ 2048
#define H_ 8
#define DH_ 128
#define D_ 1024
#define NO_ 3072
#define SCALE_ 0.08838834764831845f

typedef __bf16 bf16;
typedef __bf16 bf16x4 __attribute__((ext_vector_type(4)));
typedef __bf16 bf16x8 __attribute__((ext_vector_type(8)));
typedef float f32x4 __attribute__((ext_vector_type(4)));

__device__ inline f32x4 mfma16(bf16x8 a, bf16x8 b, f32x4 c) {
  return __builtin_amdgcn_mfma_f32_16x16x32_bf16(a, b, c, 0, 0, 0);
}

__device__ inline float elu1(float x) { return x > 0.f ? x + 1.f : __expf(x); }

// ---------------- RMSNorm: x[4096][1024] -> xn bf16 ----------------
__global__ __launch_bounds__(256) void k_rmsnorm(const float* __restrict__ x,
                                                 const float* __restrict__ gamma,
                                                 bf16* __restrict__ xn) {
  int row = blockIdx.x;
  int t = threadIdx.x;
  const float4* xr = (const float4*)(x + (size_t)row * D_);
  float4 xv = xr[t];
  float ss = xv.x*xv.x + xv.y*xv.y + xv.z*xv.z + xv.w*xv.w;
#pragma unroll
  for (int m = 1; m < 64; m <<= 1) ss += __shfl_xor(ss, m);
  __shared__ float sred[4];
  if ((t & 63) == 0) sred[t >> 6] = ss;
  __syncthreads();
  float tot = sred[0] + sred[1] + sred[2] + sred[3];
  float scale = 32.0f / fmaxf(sqrtf(tot), 1e-12f);
  float4 gv = ((const float4*)gamma)[t];
  bf16x4 ov;
  ov[0] = (bf16)(xv.x * scale * gv.x);
  ov[1] = (bf16)(xv.y * scale * gv.y);
  ov[2] = (bf16)(xv.z * scale * gv.z);
  ov[3] = (bf16)(xv.w * scale * gv.w);
  *(bf16x4*)(xn + (size_t)row * D_ + t * 4) = ov;
}

// ---------------- fp32 -> bf16 convert ----------------
__global__ void k_cvt4(const float4* __restrict__ in, bf16x4* __restrict__ out, int n4) {
  int i = blockIdx.x * blockDim.x + threadIdx.x;
  if (i < n4) {
    float4 v = in[i];
    bf16x4 o;
    o[0] = (bf16)v.x; o[1] = (bf16)v.y; o[2] = (bf16)v.z; o[3] = (bf16)v.w;
    out[i] = o;
  }
}

// ---- mem_kv [bh][k][v] fp32 -> mkvT [bh][v][k] bf16 (global transpose) ----
__global__ __launch_bounds__(256) void k_mkvT(const float* __restrict__ mem_kv,
                                              bf16* __restrict__ mkvT) {
  int bh = blockIdx.x;
  int t = threadIdx.x;
  int v = t & 127, khalf = t >> 7;
  const float* src = mem_kv + (size_t)bh * DH_ * DH_;
  bf16* dst = mkvT + (size_t)bh * DH_ * DH_ + (size_t)v * DH_ + khalf * 64;
#pragma unroll
  for (int kk8 = 0; kk8 < 8; kk8++) {
    int k0 = khalf * 64 + kk8 * 8;
    bf16x8 o;
#pragma unroll
    for (int e = 0; e < 8; e++) o[e] = (bf16)src[(size_t)(k0 + e) * DH_ + v];
    *(bf16x8*)(dst + kk8 * 8) = o;
  }
}

// ---- batched bf16 transpose: in [bh][R][C] -> out [bh][C][R], 64x64 tiles ----
__global__ __launch_bounds__(256) void k_transp(const bf16* __restrict__ in,
                                                bf16* __restrict__ out, int R, int C) {
  __shared__ bf16 tile[64][72];
  int r0 = blockIdx.x * 64, c0 = blockIdx.y * 64;
  const bf16* src = in + (size_t)blockIdx.z * R * C;
  bf16* dst = out + (size_t)blockIdx.z * R * C;
  int t = threadIdx.x;
#pragma unroll
  for (int i = t; i < 512; i += 256) {
    int r = i >> 3, cu = i & 7;
    *(uint4*)&tile[r][cu * 8] = *(const uint4*)(src + (size_t)(r0 + r) * C + c0 + cu * 8);
  }
  __syncthreads();
#pragma unroll
  for (int i = t; i < 512; i += 256) {
    int c = i >> 3, ru = i & 7;
    bf16x8 o;
#pragma unroll
    for (int e = 0; e < 8; e++) o[e] = tile[ru * 8 + e][c];
    *(bf16x8*)(dst + (size_t)(c0 + c) * R + r0 + ru * 8) = o;
  }
}

// ---------------- C[M][N] = A[M][K] @ B[N][K]^T  (bf16 in, fp32 out) -------
#define GSTR 40
__global__ __launch_bounds__(256) void k_gemm_bt(const bf16* __restrict__ A,
                                                 const bf16* __restrict__ B,
                                                 float* __restrict__ C,
                                                 int M, int Nn, int K) {
  __shared__ __align__(16) bf16 sA[128 * GSTR];
  __shared__ __align__(16) bf16 sB[128 * GSTR];
  int t = threadIdx.x;
  int w = t >> 6, lane = t & 63, quad = lane >> 4, l16 = lane & 15;
  int m0 = blockIdx.y * 128, n0 = blockIdx.x * 128;
  int wr = (w & 1) * 64, wc = (w >> 1) * 64;
  f32x4 zf = {0.f, 0.f, 0.f, 0.f};
  f32x4 acc[4][4];
#pragma unroll
  for (int a = 0; a < 4; a++)
#pragma unroll
    for (int c = 0; c < 4; c++) acc[a][c] = zf;
  int trow = t >> 2, tc = t & 3;
  for (int k0 = 0; k0 < K; k0 += 32) {
    __syncthreads();
    ((uint4*)sA)[trow * 5 + tc]        = *((const uint4*)(A + (size_t)(m0 + trow) * K + k0) + tc);
    ((uint4*)sA)[(trow + 64) * 5 + tc] = *((const uint4*)(A + (size_t)(m0 + trow + 64) * K + k0) + tc);
    ((uint4*)sB)[trow * 5 + tc]        = *((const uint4*)(B + (size_t)(n0 + trow) * K + k0) + tc);
    ((uint4*)sB)[(trow + 64) * 5 + tc] = *((const uint4*)(B + (size_t)(n0 + trow + 64) * K + k0) + tc);
    __syncthreads();
    bf16x8 af[4], bfr[4];
#pragma unroll
    for (int mt = 0; mt < 4; mt++)
      af[mt] = *(const bf16x8*)(sA + (wr + mt * 16 + l16) * GSTR + quad * 8);
#pragma unroll
    for (int nt = 0; nt < 4; nt++)
      bfr[nt] = *(const bf16x8*)(sB + (wc + nt * 16 + l16) * GSTR + quad * 8);
#pragma unroll
    for (int mt = 0; mt < 4; mt++)
#pragma unroll
      for (int nt = 0; nt < 4; nt++)
        acc[mt][nt] = mfma16(af[mt], bfr[nt], acc[mt][nt]);
  }
#pragma unroll
  for (int mt = 0; mt < 4; mt++)
#pragma unroll
    for (int nt = 0; nt < 4; nt++) {
      int row = m0 + wr + mt * 16 + quad * 4;
      int col = n0 + wc + nt * 16 + l16;
      float* cp = C + (size_t)row * Nn + col;
#pragma unroll
      for (int r = 0; r < 4; r++) cp[(size_t)r * Nn] = acc[mt][nt][r];
    }
}

// ---------------- prep: RoPE(q,k), kf, v^T, retrieval denominators --------
__global__ void k_prep(const float* __restrict__ qkv,
                       const float* __restrict__ mem_norm,
                       bf16* __restrict__ qr, bf16* __restrict__ kr,
                       bf16* __restrict__ vT, bf16* __restrict__ kf,
                       float* __restrict__ qden, float* __restrict__ kden) {
  int n = blockIdx.x;
  int h = blockIdx.y;
  int b = blockIdx.z;
  int d = threadIdx.x;  // 128
  size_t m = (size_t)b * N_ + n;
  const float* base = qkv + m * NO_ + h * DH_;
  float q = base[d];
  float k = base[D_ + d];
  float v = base[2 * D_ + d];
  int j = d >> 1;
  float inv_freq = __powf(10000.0f, -(float)(2 * j) * (1.0f / 128.0f));
  float ang = (float)n * inv_freq;
  float sn, cs;
  __sincosf(ang, &sn, &cs);
  float qs = q * SCALE_;
  float qp = __shfl_xor(qs, 1);
  float qrot = (d & 1) ? qp : -qp;
  float kp = __shfl_xor(k, 1);
  float krot = (d & 1) ? kp : -kp;
  size_t bh = (size_t)b * H_ + h;
  size_t ro = (bh * N_ + n) * DH_ + d;
  qr[ro] = (bf16)(qs * cs + qrot * sn);
  kr[ro] = (bf16)(k * cs + krot * sn);
  float kfv = elu1(k);
  kf[ro] = (bf16)kfv;
  vT[(bh * DH_ + d) * N_ + n] = (bf16)v;
  float qfv = elu1(q);
  float mn = mem_norm[bh * DH_ + d];
  float pq = qfv * mn;
  float pk = kfv * mn;
#pragma unroll
  for (int msk = 1; msk < 64; msk <<= 1) {
    pq += __shfl_xor(pq, msk);
    pk += __shfl_xor(pk, msk);
  }
  __shared__ float rq[2], rk[2];
  if ((d & 63) == 0) { rq[d >> 6] = pq; rk[d >> 6] = pk; }
  __syncthreads();
  if (d == 0) {
    qden[bh * N_ + n] = rq[0] + rq[1];
    kden[bh * N_ + n] = rk[0] + rk[1];
  }
}

// ---------------- flash attention (causal), bf16 MFMA, K-tile 64 ----------
// Flat 512-block grid with complementary qt map: co-resident blocks (i, i+256)
// get qt summing to 31 -> every CU carries ~33 tile-units (load balance).
#define KSTR 136  // 128+8, 272B rows
#define VSTR 72   // 64+8, 144B rows
__global__ __launch_bounds__(256) void k_attn(const bf16* __restrict__ qr,
                                              const bf16* __restrict__ kr,
                                              const bf16* __restrict__ vT,
                                              float* __restrict__ attn_out) {
  __shared__ __align__(16) bf16 sK[64 * KSTR];    // [key][d]
  __shared__ __align__(16) bf16 sV[128 * VSTR];   // [d][key]
  __shared__ __align__(16) bf16 sP[4][16 * VSTR]; // per-wave [qrow][key]
  int id = blockIdx.x;
  int j = id & 255;
  size_t bh = j >> 4;                       // 0..15
  int half = id >> 8;                       // 0: heavy, 1: light
  int qt = half ? (j & 15) : (31 - (j & 15));
  int t = threadIdx.x;
  int w = t >> 6, lane = t & 63, quad = lane >> 4, l16 = lane & 15;
  int qlo = qt * 64 + w * 16;

  bf16x8 qfrag[4];
  const bf16* qrow = qr + (bh * N_ + qlo + l16) * DH_;
#pragma unroll
  for (int s = 0; s < 4; s++) qfrag[s] = *(const bf16x8*)(qrow + s * 32 + quad * 8);

  f32x4 zf = {0.f, 0.f, 0.f, 0.f};
  f32x4 o[8];
#pragma unroll
  for (int i = 0; i < 8; i++) o[i] = zf;
  float mrow[4] = {-1e30f, -1e30f, -1e30f, -1e30f};
  float lrow[4] = {0.f, 0.f, 0.f, 0.f};

  int ntiles = qt + 1;
  for (int jt = 0; jt < ntiles; jt++) {
    __syncthreads();
    {  // stage K [64][128] and V^T [128][64]
      const uint4* ksrc = (const uint4*)(kr + (bh * N_ + (size_t)jt * 64) * DH_);
#pragma unroll
      for (int p = 0; p < 4; p++) {
        int i = p * 256 + t;
        int row = i >> 4, c16 = i & 15;
        ((uint4*)sK)[row * 17 + c16] = ksrc[row * 16 + c16];
      }
#pragma unroll
      for (int p = 0; p < 4; p++) {
        int i = p * 256 + t;
        int row = i >> 3, c8 = i & 7;
        ((uint4*)sV)[row * 9 + c8] =
            *((const uint4*)(vT + (bh * DH_ + row) * N_ + (size_t)jt * 64) + c8);
      }
    }
    __syncthreads();

    f32x4 sf[4];
#pragma unroll
    for (int nt = 0; nt < 4; nt++) sf[nt] = zf;
#pragma unroll
    for (int s = 0; s < 4; s++) {
#pragma unroll
      for (int nt = 0; nt < 4; nt++) {
        bf16x8 b = *(const bf16x8*)(sK + (nt * 16 + l16) * KSTR + s * 32 + quad * 8);
        sf[nt] = mfma16(qfrag[s], b, sf[nt]);
      }
    }
    if (jt == ntiles - 1) {  // diagonal tile: mask key > q
#pragma unroll
      for (int nt = 0; nt < 4; nt++) {
        int kg = jt * 64 + nt * 16 + l16;
#pragma unroll
        for (int r = 0; r < 4; r++) {
          int qg = qlo + quad * 4 + r;
          if (kg > qg) sf[nt][r] = -1e30f;
        }
      }
    }
    float alpha[4];
#pragma unroll
    for (int r = 0; r < 4; r++) {
      float tm = fmaxf(fmaxf(sf[0][r], sf[1][r]), fmaxf(sf[2][r], sf[3][r]));
      tm = fmaxf(tm, __shfl_xor(tm, 1));
      tm = fmaxf(tm, __shfl_xor(tm, 2));
      tm = fmaxf(tm, __shfl_xor(tm, 4));
      tm = fmaxf(tm, __shfl_xor(tm, 8));
      float mn = fmaxf(mrow[r], tm);
      alpha[r] = __expf(mrow[r] - mn);
      float rs = 0.f;
#pragma unroll
      for (int nt = 0; nt < 4; nt++) {
        float p = __expf(sf[nt][r] - mn);
        sf[nt][r] = p;
        rs += p;
      }
      rs += __shfl_xor(rs, 1);
      rs += __shfl_xor(rs, 2);
      rs += __shfl_xor(rs, 4);
      rs += __shfl_xor(rs, 8);
      lrow[r] = lrow[r] * alpha[r] + rs;
      mrow[r] = mn;
    }
#pragma unroll
    for (int i = 0; i < 8; i++) {
      o[i][0] *= alpha[0]; o[i][1] *= alpha[1];
      o[i][2] *= alpha[2]; o[i][3] *= alpha[3];
    }
    // P: C-layout -> per-wave LDS -> A-operand layout
    bf16* pw = sP[w];
#pragma unroll
    for (int nt = 0; nt < 4; nt++)
#pragma unroll
      for (int r = 0; r < 4; r++)
        pw[(quad * 4 + r) * VSTR + nt * 16 + l16] = (bf16)sf[nt][r];
    bf16x8 pa0 = *(const bf16x8*)(pw + l16 * VSTR + quad * 8);
    bf16x8 pa1 = *(const bf16x8*)(pw + l16 * VSTR + 32 + quad * 8);
#pragma unroll
    for (int vt = 0; vt < 8; vt++) {
      bf16x8 b0 = *(const bf16x8*)(sV + (vt * 16 + l16) * VSTR + quad * 8);
      bf16x8 b1 = *(const bf16x8*)(sV + (vt * 16 + l16) * VSTR + 32 + quad * 8);
      o[vt] = mfma16(pa0, b0, o[vt]);
      o[vt] = mfma16(pa1, b1, o[vt]);
    }
  }
#pragma unroll
  for (int vt = 0; vt < 8; vt++)
#pragma unroll
    for (int r = 0; r < 4; r++) {
      int qg = qlo + quad * 4 + r;
      attn_out[(bh * N_ + qg) * DH_ + vt * 16 + l16] = o[vt][r] / lrow[r];
    }
}

// ------- MFMA retrieval (q & k paths) + gate-combine + vnew -------
#define SMT_STRIDE 136
__global__ __launch_bounds__(256) void k_retrieve2(const float* __restrict__ qkv,
                                                   const bf16* __restrict__ mkvT,
                                                   const float* __restrict__ qden,
                                                   const float* __restrict__ kden,
                                                   const float* __restrict__ attn,
                                                   const float* __restrict__ hg,
                                                   bf16* __restrict__ comb,
                                                   bf16* __restrict__ vnew) {
  __shared__ __align__(16) bf16 smT[DH_ * SMT_STRIDE];
  int h = blockIdx.y, b = blockIdx.z;
  size_t bh = (size_t)b * H_ + h;
  int t = threadIdx.x;
  int w = t >> 6, lane = t & 63, quad = lane >> 4, l16 = lane & 15;
  int n0 = blockIdx.x * 64;

  {
    const uint4* src = (const uint4*)(mkvT + bh * DH_ * DH_);
    uint4* dst = (uint4*)smT;
#pragma unroll
    for (int it = 0; it < 8; it++) {
      int i = t + it * 256;
      int row = i >> 4, col = i & 15;
      dst[row * 17 + col] = src[i];
    }
  }

  int nrow = n0 + w * 16 + l16;
  const float* base = qkv + ((size_t)b * N_ + nrow) * NO_ + h * DH_;
  bf16x8 qa[4], ka[4];
#pragma unroll
  for (int s = 0; s < 4; s++) {
    int k0 = s * 32 + quad * 8;
    float4 q0 = *(const float4*)(base + k0);
    float4 q1 = *(const float4*)(base + k0 + 4);
    float4 k0v = *(const float4*)(base + D_ + k0);
    float4 k1v = *(const float4*)(base + D_ + k0 + 4);
    bf16x8 qo, ko;
    qo[0]=(bf16)elu1(q0.x); qo[1]=(bf16)elu1(q0.y); qo[2]=(bf16)elu1(q0.z); qo[3]=(bf16)elu1(q0.w);
    qo[4]=(bf16)elu1(q1.x); qo[5]=(bf16)elu1(q1.y); qo[6]=(bf16)elu1(q1.z); qo[7]=(bf16)elu1(q1.w);
    ko[0]=(bf16)elu1(k0v.x); ko[1]=(bf16)elu1(k0v.y); ko[2]=(bf16)elu1(k0v.z); ko[3]=(bf16)elu1(k0v.w);
    ko[4]=(bf16)elu1(k1v.x); ko[5]=(bf16)elu1(k1v.y); ko[6]=(bf16)elu1(k1v.z); ko[7]=(bf16)elu1(k1v.w);
    qa[s] = qo; ka[s] = ko;
  }

  __syncthreads();
  f32x4 zf = {0.f, 0.f, 0.f, 0.f};
  f32x4 accq[8], acck[8];
#pragma unroll
  for (int vt = 0; vt < 8; vt++) { accq[vt] = zf; acck[vt] = zf; }
#pragma unroll
  for (int vt = 0; vt < 8; vt++) {
#pragma unroll
    for (int s = 0; s < 4; s++) {
      bf16x8 bfr = *(const bf16x8*)(smT + (vt * 16 + l16) * SMT_STRIDE + s * 32 + quad * 8);
      accq[vt] = mfma16(qa[s], bfr, accq[vt]);
      acck[vt] = mfma16(ka[s], bfr, acck[vt]);
    }
  }

  float g = 1.f / (1.f + __expf(-hg[h]));
#pragma unroll
  for (int r = 0; r < 4; r++) {
    int n = n0 + w * 16 + quad * 4 + r;
    size_t m = (size_t)b * N_ + n;
    float qd = fmaxf(qden[bh * N_ + n], 1e-10f);
    float kd = fmaxf(kden[bh * N_ + n], 1e-10f);
#pragma unroll
    for (int vt = 0; vt < 8; vt++) {
      int v = vt * 16 + l16;
      float mo = accq[vt][r] / qd;
      float ov = attn[(bh * N_ + n) * DH_ + v];
      comb[m * D_ + h * DH_ + v] = (bf16)(ov * g + mo * (1.f - g));
      float vv = qkv[m * NO_ + 2 * D_ + h * DH_ + v];
      vnew[(bh * N_ + n) * DH_ + v] = (bf16)(vv - acck[vt][r] / kd);
    }
  }
}

// ---------------- init outputs new_kv/new_norm with memories ----------------
__global__ void k_init_out(const float* __restrict__ mem_kv, const float* __restrict__ mem_norm,
                           float* __restrict__ out_kv, float* __restrict__ out_norm) {
  int i = blockIdx.x * 256 + threadIdx.x;
  if (i < B_ * H_ * DH_ * DH_) out_kv[i] = mem_kv[i];
  if (i < B_ * H_ * DH_) out_norm[i] = mem_norm[i];
}

// ---- new_kv: out_kv[bh] += kfT[bh] @ vnT[bh]^T, split-K over n ----
__global__ __launch_bounds__(256) void k_newkv2(const bf16* __restrict__ kfT,
                                                const bf16* __restrict__ vnT,
                                                float* __restrict__ out_kv) {
  __shared__ __align__(16) bf16 sA[128 * GSTR];
  __shared__ __align__(16) bf16 sB[128 * GSTR];
  int t = threadIdx.x;
  int w = t >> 6, lane = t & 63, quad = lane >> 4, l16 = lane & 15;
  size_t bh = (size_t)blockIdx.z * H_ + blockIdx.y;
  const bf16* A  = kfT + bh * DH_ * N_;
  const bf16* Bm = vnT + bh * DH_ * N_;
  int wr = (w & 1) * 64, wc = (w >> 1) * 64;
  f32x4 zf = {0.f, 0.f, 0.f, 0.f};
  f32x4 acc[4][4];
#pragma unroll
  for (int a = 0; a < 4; a++)
#pragma unroll
    for (int c = 0; c < 4; c++) acc[a][c] = zf;
  int trow = t >> 2, tc = t & 3;
  int kend = (blockIdx.x + 1) * 128;
  for (int k0 = blockIdx.x * 128; k0 < kend; k0 += 32) {
    __syncthreads();
    ((uint4*)sA)[trow * 5 + tc]        = *((const uint4*)(A + (size_t)trow * N_ + k0) + tc);
    ((uint4*)sA)[(trow + 64) * 5 + tc] = *((const uint4*)(A + (size_t)(trow + 64) * N_ + k0) + tc);
    ((uint4*)sB)[trow * 5 + tc]        = *((const uint4*)(Bm + (size_t)trow * N_ + k0) + tc);
    ((uint4*)sB)[(trow + 64) * 5 + tc] = *((const uint4*)(Bm + (size_t)(trow + 64) * N_ + k0) + tc);
    __syncthreads();
    bf16x8 af[4], bfr[4];
#pragma unroll
    for (int mt = 0; mt < 4; mt++)
      af[mt] = *(const bf16x8*)(sA + (wr + mt * 16 + l16) * GSTR + quad * 8);
#pragma unroll
    for (int nt = 0; nt < 4; nt++)
      bfr[nt] = *(const bf16x8*)(sB + (wc + nt * 16 + l16) * GSTR + quad * 8);
#pragma unroll
    for (int mt = 0; mt < 4; mt++)
#pragma unroll
      for (int nt = 0; nt < 4; nt++)
        acc[mt][nt] = mfma16(af[mt], bfr[nt], acc[mt][nt]);
  }
  float* obh = out_kv + bh * DH_ * DH_;
#pragma unroll
  for (int mt = 0; mt < 4; mt++)
#pragma unroll
    for (int nt = 0; nt < 4; nt++) {
      int row = wr + mt * 16 + quad * 4;
      int col = wc + nt * 16 + l16;
#pragma unroll
      for (int r = 0; r < 4; r++)
        atomicAdd(obh + (size_t)(row + r) * DH_ + col, acc[mt][nt][r]);
    }
}

// ---------------- new_norm partial: sum_n elu(k)+1 (fp32 from qkv) ---------
__global__ void k_newnorm(const float* __restrict__ qkv, float* __restrict__ out_norm) {
  int chunk = blockIdx.x;
  int h = blockIdx.y, b = blockIdx.z;
  int k = threadIdx.x;  // 128
  size_t bh = (size_t)b * H_ + h;
  float acc = 0.f;
  for (int i = 0; i < 256; i++) {
    size_t n = (size_t)chunk * 256 + i;
    float kv = qkv[((size_t)b * N_ + n) * NO_ + D_ + h * DH_ + k];
    acc += elu1(kv);
  }
  atomicAdd(out_norm + bh * DH_ + k, acc);
}

extern "C" void kernel_launch(void* const* d_in, const int* in_sizes, int n_in,
                              void* d_out, int out_size, void* d_ws, size_t ws_size,
                              hipStream_t stream) {
  const float* x        = (const float*)d_in[0];
  const float* gamma    = (const float*)d_in[1];
  const float* w_qkv    = (const float*)d_in[2];
  const float* w_out    = (const float*)d_in[3];
  const float* hg       = (const float*)d_in[4];
  const float* mem_kv   = (const float*)d_in[5];
  const float* mem_norm = (const float*)d_in[6];
  float* out      = (float*)d_out;
  float* out_kv   = out + (size_t)B_ * N_ * D_;
  float* out_norm = out_kv + (size_t)B_ * H_ * DH_ * DH_;

  char* ws = (char*)d_ws;
  size_t off = 0;
  auto alloc = [&](size_t bytes) -> void* {
    void* p = ws + off;
    off += (bytes + 255) & ~(size_t)255;
    return p;
  };
  bf16*  xn   = (bf16*)alloc((size_t)B_ * N_ * D_ * 2);
  bf16*  wqb  = (bf16*)alloc((size_t)NO_ * D_ * 2);
  bf16*  wob  = (bf16*)alloc((size_t)D_ * D_ * 2);
  float* qkv  = (float*)alloc((size_t)B_ * N_ * NO_ * 4);
  bf16*  qr   = (bf16*)alloc((size_t)B_ * H_ * N_ * DH_ * 2);
  bf16*  kr   = (bf16*)alloc((size_t)B_ * H_ * N_ * DH_ * 2);
  bf16*  vT   = (bf16*)alloc((size_t)B_ * H_ * DH_ * N_ * 2);
  bf16*  kf   = (bf16*)alloc((size_t)B_ * H_ * N_ * DH_ * 2);
  bf16*  vnew = (bf16*)alloc((size_t)B_ * H_ * N_ * DH_ * 2);
  float* qden = (float*)alloc((size_t)B_ * H_ * N_ * 4);
  float* kden = (float*)alloc((size_t)B_ * H_ * N_ * 4);
  float* attn = (float*)alloc((size_t)B_ * H_ * N_ * DH_ * 4);
  bf16*  comb = (bf16*)alloc((size_t)B_ * N_ * D_ * 2);
  bf16*  mkvT = (bf16*)alloc((size_t)B_ * H_ * DH_ * DH_ * 2);
  bf16*  kfT  = (bf16*)alloc((size_t)B_ * H_ * DH_ * N_ * 2);
  bf16*  vnT  = (bf16*)alloc((size_t)B_ * H_ * DH_ * N_ * 2);
  (void)in_sizes; (void)n_in; (void)out_size; (void)ws_size;

  k_rmsnorm<<<dim3(B_ * N_), 256, 0, stream>>>(x, gamma, xn);
  k_cvt4<<<(NO_ * D_ / 4 + 255) / 256, 256, 0, stream>>>((const float4*)w_qkv, (bf16x4*)wqb, NO_ * D_ / 4);
  k_cvt4<<<(D_ * D_ / 4 + 255) / 256, 256, 0, stream>>>((const float4*)w_out, (bf16x4*)wob, D_ * D_ / 4);
  k_mkvT<<<dim3(B_ * H_), 256, 0, stream>>>(mem_kv, mkvT);
  k_gemm_bt<<<dim3(NO_ / 128, B_ * N_ / 128), 256, 0, stream>>>(xn, wqb, qkv, B_ * N_, NO_, D_);
  k_prep<<<dim3(N_, H_, B_), 128, 0, stream>>>(qkv, mem_norm, qr, kr, vT, kf, qden, kden);
  k_attn<<<dim3(512), 256, 0, stream>>>(qr, kr, vT, attn);
  k_retrieve2<<<dim3(N_ / 64, H_, B_), 256, 0, stream>>>(qkv, mkvT, qden, kden, attn, hg, comb, vnew);
  k_gemm_bt<<<dim3(D_ / 128, B_ * N_ / 128), 256, 0, stream>>>(comb, wob, out, B_ * N_, D_, D_);
  k_transp<<<dim3(N_ / 64, DH_ / 64, B_ * H_), 256, 0, stream>>>(kf, kfT, N_, DH_);
  k_transp<<<dim3(N_ / 64, DH_ / 64, B_ * H_), 256, 0, stream>>>(vnew, vnT, N_, DH_);
  k_init_out<<<(B_ * H_ * DH_ * DH_ + 255) / 256, 256, 0, stream>>>(mem_kv, mem_norm, out_kv, out_norm);
  k_newkv2<<<dim3(16, H_, B_), 256, 0, stream>>>(kfT, vnT, out_kv);
  k_newnorm<<<dim3(N_ / 256, H_, B_), 128, 0, stream>>>(qkv, out_norm);
}

// Round 6
// 349.811 us; speedup vs baseline: 2.5128x; 1.0575x over previous
//
#include <hip/hip_runtime.h>
#include <hip/hip_bf16.h>

#define B_ 2
#define N_ 2048
#define H_ 8
#define DH_ 128
#define D_ 1024
#define NO_ 3072
#define SCALE_ 0.08838834764831845f

typedef __bf16 bf16;
typedef __bf16 bf16x4 __attribute__((ext_vector_type(4)));
typedef __bf16 bf16x8 __attribute__((ext_vector_type(8)));
typedef float f32x4 __attribute__((ext_vector_type(4)));

__device__ inline f32x4 mfma16(bf16x8 a, bf16x8 b, f32x4 c) {
  return __builtin_amdgcn_mfma_f32_16x16x32_bf16(a, b, c, 0, 0, 0);
}

__device__ inline float elu1(float x) { return x > 0.f ? x + 1.f : __expf(x); }

// ---------------- RMSNorm: x[4096][1024] -> xn bf16 ----------------
__global__ __launch_bounds__(256) void k_rmsnorm(const float* __restrict__ x,
                                                 const float* __restrict__ gamma,
                                                 bf16* __restrict__ xn) {
  int row = blockIdx.x;
  int t = threadIdx.x;
  const float4* xr = (const float4*)(x + (size_t)row * D_);
  float4 xv = xr[t];
  float ss = xv.x*xv.x + xv.y*xv.y + xv.z*xv.z + xv.w*xv.w;
#pragma unroll
  for (int m = 1; m < 64; m <<= 1) ss += __shfl_xor(ss, m);
  __shared__ float sred[4];
  if ((t & 63) == 0) sred[t >> 6] = ss;
  __syncthreads();
  float tot = sred[0] + sred[1] + sred[2] + sred[3];
  float scale = 32.0f / fmaxf(sqrtf(tot), 1e-12f);
  float4 gv = ((const float4*)gamma)[t];
  bf16x4 ov;
  ov[0] = (bf16)(xv.x * scale * gv.x);
  ov[1] = (bf16)(xv.y * scale * gv.y);
  ov[2] = (bf16)(xv.z * scale * gv.z);
  ov[3] = (bf16)(xv.w * scale * gv.w);
  *(bf16x4*)(xn + (size_t)row * D_ + t * 4) = ov;
}

// ---------------- fp32 -> bf16 convert ----------------
__global__ void k_cvt4(const float4* __restrict__ in, bf16x4* __restrict__ out, int n4) {
  int i = blockIdx.x * blockDim.x + threadIdx.x;
  if (i < n4) {
    float4 v = in[i];
    bf16x4 o;
    o[0] = (bf16)v.x; o[1] = (bf16)v.y; o[2] = (bf16)v.z; o[3] = (bf16)v.w;
    out[i] = o;
  }
}

// ---- mem_kv [bh][k][v] fp32 -> mkvT [bh][v][k] bf16 (global transpose) ----
__global__ __launch_bounds__(256) void k_mkvT(const float* __restrict__ mem_kv,
                                              bf16* __restrict__ mkvT) {
  int bh = blockIdx.x;
  int t = threadIdx.x;
  int v = t & 127, khalf = t >> 7;
  const float* src = mem_kv + (size_t)bh * DH_ * DH_;
  bf16* dst = mkvT + (size_t)bh * DH_ * DH_ + (size_t)v * DH_ + khalf * 64;
#pragma unroll
  for (int kk8 = 0; kk8 < 8; kk8++) {
    int k0 = khalf * 64 + kk8 * 8;
    bf16x8 o;
#pragma unroll
    for (int e = 0; e < 8; e++) o[e] = (bf16)src[(size_t)(k0 + e) * DH_ + v];
    *(bf16x8*)(dst + kk8 * 8) = o;
  }
}

// ---- batched bf16 transpose: in [bh][R][C] -> out [bh][C][R], 64x64 tiles ----
__global__ __launch_bounds__(256) void k_transp(const bf16* __restrict__ in,
                                                bf16* __restrict__ out, int R, int C) {
  __shared__ bf16 tile[64][72];
  int r0 = blockIdx.x * 64, c0 = blockIdx.y * 64;
  const bf16* src = in + (size_t)blockIdx.z * R * C;
  bf16* dst = out + (size_t)blockIdx.z * R * C;
  int t = threadIdx.x;
#pragma unroll
  for (int i = t; i < 512; i += 256) {
    int r = i >> 3, cu = i & 7;
    *(uint4*)&tile[r][cu * 8] = *(const uint4*)(src + (size_t)(r0 + r) * C + c0 + cu * 8);
  }
  __syncthreads();
#pragma unroll
  for (int i = t; i < 512; i += 256) {
    int c = i >> 3, ru = i & 7;
    bf16x8 o;
#pragma unroll
    for (int e = 0; e < 8; e++) o[e] = tile[ru * 8 + e][c];
    *(bf16x8*)(dst + (size_t)(c0 + c) * R + r0 + ru * 8) = o;
  }
}

// ---------------- C[M][N] = A[M][K] @ B[N][K]^T  (bf16 in, fp32 out) -------
#define GSTR 40
__global__ __launch_bounds__(256) void k_gemm_bt(const bf16* __restrict__ A,
                                                 const bf16* __restrict__ B,
                                                 float* __restrict__ C,
                                                 int M, int Nn, int K) {
  __shared__ __align__(16) bf16 sA[128 * GSTR];
  __shared__ __align__(16) bf16 sB[128 * GSTR];
  int t = threadIdx.x;
  int w = t >> 6, lane = t & 63, quad = lane >> 4, l16 = lane & 15;
  int m0 = blockIdx.y * 128, n0 = blockIdx.x * 128;
  int wr = (w & 1) * 64, wc = (w >> 1) * 64;
  f32x4 zf = {0.f, 0.f, 0.f, 0.f};
  f32x4 acc[4][4];
#pragma unroll
  for (int a = 0; a < 4; a++)
#pragma unroll
    for (int c = 0; c < 4; c++) acc[a][c] = zf;
  int trow = t >> 2, tc = t & 3;
  for (int k0 = 0; k0 < K; k0 += 32) {
    __syncthreads();
    ((uint4*)sA)[trow * 5 + tc]        = *((const uint4*)(A + (size_t)(m0 + trow) * K + k0) + tc);
    ((uint4*)sA)[(trow + 64) * 5 + tc] = *((const uint4*)(A + (size_t)(m0 + trow + 64) * K + k0) + tc);
    ((uint4*)sB)[trow * 5 + tc]        = *((const uint4*)(B + (size_t)(n0 + trow) * K + k0) + tc);
    ((uint4*)sB)[(trow + 64) * 5 + tc] = *((const uint4*)(B + (size_t)(n0 + trow + 64) * K + k0) + tc);
    __syncthreads();
    bf16x8 af[4], bfr[4];
#pragma unroll
    for (int mt = 0; mt < 4; mt++)
      af[mt] = *(const bf16x8*)(sA + (wr + mt * 16 + l16) * GSTR + quad * 8);
#pragma unroll
    for (int nt = 0; nt < 4; nt++)
      bfr[nt] = *(const bf16x8*)(sB + (wc + nt * 16 + l16) * GSTR + quad * 8);
#pragma unroll
    for (int mt = 0; mt < 4; mt++)
#pragma unroll
      for (int nt = 0; nt < 4; nt++)
        acc[mt][nt] = mfma16(af[mt], bfr[nt], acc[mt][nt]);
  }
#pragma unroll
  for (int mt = 0; mt < 4; mt++)
#pragma unroll
    for (int nt = 0; nt < 4; nt++) {
      int row = m0 + wr + mt * 16 + quad * 4;
      int col = n0 + wc + nt * 16 + l16;
      float* cp = C + (size_t)row * Nn + col;
#pragma unroll
      for (int r = 0; r < 4; r++) cp[(size_t)r * Nn] = acc[mt][nt][r];
    }
}

// ---------------- prep: RoPE(q,k), kf, v^T, retrieval denominators --------
__global__ void k_prep(const float* __restrict__ qkv,
                       const float* __restrict__ mem_norm,
                       bf16* __restrict__ qr, bf16* __restrict__ kr,
                       bf16* __restrict__ vT, bf16* __restrict__ kf,
                       float* __restrict__ qden, float* __restrict__ kden) {
  int n = blockIdx.x;
  int h = blockIdx.y;
  int b = blockIdx.z;
  int d = threadIdx.x;  // 128
  size_t m = (size_t)b * N_ + n;
  const float* base = qkv + m * NO_ + h * DH_;
  float q = base[d];
  float k = base[D_ + d];
  float v = base[2 * D_ + d];
  int j = d >> 1;
  float inv_freq = __powf(10000.0f, -(float)(2 * j) * (1.0f / 128.0f));
  float ang = (float)n * inv_freq;
  float sn, cs;
  __sincosf(ang, &sn, &cs);
  float qs = q * SCALE_;
  float qp = __shfl_xor(qs, 1);
  float qrot = (d & 1) ? qp : -qp;
  float kp = __shfl_xor(k, 1);
  float krot = (d & 1) ? kp : -kp;
  size_t bh = (size_t)b * H_ + h;
  size_t ro = (bh * N_ + n) * DH_ + d;
  qr[ro] = (bf16)(qs * cs + qrot * sn);
  kr[ro] = (bf16)(k * cs + krot * sn);
  float kfv = elu1(k);
  kf[ro] = (bf16)kfv;
  vT[(bh * DH_ + d) * N_ + n] = (bf16)v;
  float qfv = elu1(q);
  float mn = mem_norm[bh * DH_ + d];
  float pq = qfv * mn;
  float pk = kfv * mn;
#pragma unroll
  for (int msk = 1; msk < 64; msk <<= 1) {
    pq += __shfl_xor(pq, msk);
    pk += __shfl_xor(pk, msk);
  }
  __shared__ float rq[2], rk[2];
  if ((d & 63) == 0) { rq[d >> 6] = pq; rk[d >> 6] = pk; }
  __syncthreads();
  if (d == 0) {
    qden[bh * N_ + n] = rq[0] + rq[1];
    kden[bh * N_ + n] = rk[0] + rk[1];
  }
}

// ------- flash attention, K-chunked (flash-decoding style) -------
// grid 1280 = 16 bh x 80 chunks (chunk = up to 8 K-tiles of 64 keys).
// qt<=7: single chunk, writes attn directly. qt>=8: bf16 partial O + (m,l).
#define KSTR 136
#define VSTR 72
__global__ __launch_bounds__(256) void k_attn2(const bf16* __restrict__ qr,
                                               const bf16* __restrict__ kr,
                                               const bf16* __restrict__ vT,
                                               float* __restrict__ attn_out,
                                               bf16* __restrict__ pO,
                                               float* __restrict__ pstat) {
  __shared__ __align__(16) bf16 sK[64 * KSTR];
  __shared__ __align__(16) bf16 sV[128 * VSTR];
  __shared__ __align__(16) bf16 sP[4][16 * VSTR];
  int x = blockIdx.x;
  size_t bh = x / 80;
  int e = x % 80;
  int qt, c;
  if (e < 32)      { qt = 31 - (e >> 2); c = e & 3; }
  else if (e < 56) { int u = e - 32; qt = 23 - u / 3; c = u % 3; }
  else if (e < 72) { int u = e - 56; qt = 15 - (u >> 1); c = u & 1; }
  else             { qt = 7 - (e - 72); c = 0; }
  int jt0 = c * 8;
  int jt1 = min(jt0 + 8, qt + 1);

  int t = threadIdx.x;
  int w = t >> 6, lane = t & 63, quad = lane >> 4, l16 = lane & 15;
  int qlo = qt * 64 + w * 16;

  bf16x8 qfrag[4];
  const bf16* qrow = qr + (bh * N_ + qlo + l16) * DH_;
#pragma unroll
  for (int s = 0; s < 4; s++) qfrag[s] = *(const bf16x8*)(qrow + s * 32 + quad * 8);

  f32x4 zf = {0.f, 0.f, 0.f, 0.f};
  f32x4 o[8];
#pragma unroll
  for (int i = 0; i < 8; i++) o[i] = zf;
  float mrow[4] = {-1e30f, -1e30f, -1e30f, -1e30f};
  float lrow[4] = {0.f, 0.f, 0.f, 0.f};

  for (int jt = jt0; jt < jt1; jt++) {
    __syncthreads();
    {  // stage K [64][128] and V^T [128][64]
      const uint4* ksrc = (const uint4*)(kr + (bh * N_ + (size_t)jt * 64) * DH_);
#pragma unroll
      for (int p = 0; p < 4; p++) {
        int i = p * 256 + t;
        int row = i >> 4, c16 = i & 15;
        ((uint4*)sK)[row * 17 + c16] = ksrc[row * 16 + c16];
      }
#pragma unroll
      for (int p = 0; p < 4; p++) {
        int i = p * 256 + t;
        int row = i >> 3, c8 = i & 7;
        ((uint4*)sV)[row * 9 + c8] =
            *((const uint4*)(vT + (bh * DH_ + row) * N_ + (size_t)jt * 64) + c8);
      }
    }
    __syncthreads();

    f32x4 sf[4];
#pragma unroll
    for (int nt = 0; nt < 4; nt++) sf[nt] = zf;
#pragma unroll
    for (int s = 0; s < 4; s++) {
#pragma unroll
      for (int nt = 0; nt < 4; nt++) {
        bf16x8 b = *(const bf16x8*)(sK + (nt * 16 + l16) * KSTR + s * 32 + quad * 8);
        sf[nt] = mfma16(qfrag[s], b, sf[nt]);
      }
    }
    if (jt == qt) {  // diagonal tile: mask key > q
#pragma unroll
      for (int nt = 0; nt < 4; nt++) {
        int kg = jt * 64 + nt * 16 + l16;
#pragma unroll
        for (int r = 0; r < 4; r++) {
          int qg = qlo + quad * 4 + r;
          if (kg > qg) sf[nt][r] = -1e30f;
        }
      }
    }
    float alpha[4];
#pragma unroll
    for (int r = 0; r < 4; r++) {
      float tm = fmaxf(fmaxf(sf[0][r], sf[1][r]), fmaxf(sf[2][r], sf[3][r]));
      tm = fmaxf(tm, __shfl_xor(tm, 1));
      tm = fmaxf(tm, __shfl_xor(tm, 2));
      tm = fmaxf(tm, __shfl_xor(tm, 4));
      tm = fmaxf(tm, __shfl_xor(tm, 8));
      float mn = fmaxf(mrow[r], tm);
      alpha[r] = __expf(mrow[r] - mn);
      float rs = 0.f;
#pragma unroll
      for (int nt = 0; nt < 4; nt++) {
        float p = __expf(sf[nt][r] - mn);
        sf[nt][r] = p;
        rs += p;
      }
      rs += __shfl_xor(rs, 1);
      rs += __shfl_xor(rs, 2);
      rs += __shfl_xor(rs, 4);
      rs += __shfl_xor(rs, 8);
      lrow[r] = lrow[r] * alpha[r] + rs;
      mrow[r] = mn;
    }
#pragma unroll
    for (int i = 0; i < 8; i++) {
      o[i][0] *= alpha[0]; o[i][1] *= alpha[1];
      o[i][2] *= alpha[2]; o[i][3] *= alpha[3];
    }
    bf16* pw = sP[w];
#pragma unroll
    for (int nt = 0; nt < 4; nt++)
#pragma unroll
      for (int r = 0; r < 4; r++)
        pw[(quad * 4 + r) * VSTR + nt * 16 + l16] = (bf16)sf[nt][r];
    bf16x8 pa0 = *(const bf16x8*)(pw + l16 * VSTR + quad * 8);
    bf16x8 pa1 = *(const bf16x8*)(pw + l16 * VSTR + 32 + quad * 8);
#pragma unroll
    for (int vt = 0; vt < 8; vt++) {
      bf16x8 b0 = *(const bf16x8*)(sV + (vt * 16 + l16) * VSTR + quad * 8);
      bf16x8 b1 = *(const bf16x8*)(sV + (vt * 16 + l16) * VSTR + 32 + quad * 8);
      o[vt] = mfma16(pa0, b0, o[vt]);
      o[vt] = mfma16(pa1, b1, o[vt]);
    }
  }

  if (qt < 8) {  // single chunk: final output
#pragma unroll
    for (int vt = 0; vt < 8; vt++)
#pragma unroll
      for (int r = 0; r < 4; r++) {
        int qg = qlo + quad * 4 + r;
        attn_out[(bh * N_ + qg) * DH_ + vt * 16 + l16] = o[vt][r] / lrow[r];
      }
  } else {       // partial: bf16 numerator + per-row (m,l)
    int cid = ((int)bh * 24 + qt - 8) * 4 + c;
    if (l16 == 0) {
#pragma unroll
      for (int r = 0; r < 4; r++) {
        size_t si = ((size_t)cid * 64 + w * 16 + quad * 4 + r) * 2;
        pstat[si] = mrow[r];
        pstat[si + 1] = lrow[r];
      }
    }
#pragma unroll
    for (int vt = 0; vt < 8; vt++)
#pragma unroll
      for (int r = 0; r < 4; r++) {
        int lr = w * 16 + quad * 4 + r;
        pO[((size_t)cid * 64 + lr) * DH_ + vt * 16 + l16] = (bf16)o[vt][r];
      }
  }
}

// ------- combine partial chunks (qt>=8): up to 4 per q-row -------
__global__ __launch_bounds__(256) void k_combine(const bf16* __restrict__ pO,
                                                 const float* __restrict__ pstat,
                                                 float* __restrict__ attn_out) {
  int x = blockIdx.x;          // 384 = 16 bh * 24 qt
  int bh = x / 24, qi = x % 24;
  int qt = 8 + qi;
  int nch = (qt + 8) / 8;      // ceil((qt+1)/8), 2..4
  int t = threadIdx.x;
  int row = t >> 2, dseg = (t & 3) * 32;
  int cidb = (bh * 24 + qi) * 4;
  float ms[4], ls[4];
  float mg = -1e30f;
#pragma unroll 4
  for (int c = 0; c < nch; c++) {
    float2 st = *(const float2*)(pstat + ((size_t)(cidb + c) * 64 + row) * 2);
    ms[c] = st.x; ls[c] = st.y;
    mg = fmaxf(mg, st.x);
  }
  float L = 0.f, wc[4];
#pragma unroll 4
  for (int c = 0; c < nch; c++) { wc[c] = __expf(ms[c] - mg); L += ls[c] * wc[c]; }
  float inv = 1.f / L;
  float acc[32];
#pragma unroll
  for (int i = 0; i < 32; i++) acc[i] = 0.f;
#pragma unroll 4
  for (int c = 0; c < nch; c++) {
    const bf16x8* p = (const bf16x8*)(pO + ((size_t)(cidb + c) * 64 + row) * DH_ + dseg);
#pragma unroll
    for (int j = 0; j < 4; j++) {
      bf16x8 v = p[j];
#pragma unroll
      for (int e2 = 0; e2 < 8; e2++) acc[j * 8 + e2] += wc[c] * (float)v[e2];
    }
  }
  float* dst = attn_out + ((size_t)bh * N_ + qt * 64 + row) * DH_ + dseg;
#pragma unroll
  for (int i = 0; i < 32; i++) dst[i] = acc[i] * inv;
}

// ------- MFMA retrieval (q & k paths) + gate-combine + vnew -------
#define SMT_STRIDE 136
__global__ __launch_bounds__(256) void k_retrieve2(const float* __restrict__ qkv,
                                                   const bf16* __restrict__ mkvT,
                                                   const float* __restrict__ qden,
                                                   const float* __restrict__ kden,
                                                   const float* __restrict__ attn,
                                                   const float* __restrict__ hg,
                                                   bf16* __restrict__ comb,
                                                   bf16* __restrict__ vnew) {
  __shared__ __align__(16) bf16 smT[DH_ * SMT_STRIDE];
  int h = blockIdx.y, b = blockIdx.z;
  size_t bh = (size_t)b * H_ + h;
  int t = threadIdx.x;
  int w = t >> 6, lane = t & 63, quad = lane >> 4, l16 = lane & 15;
  int n0 = blockIdx.x * 64;

  {
    const uint4* src = (const uint4*)(mkvT + bh * DH_ * DH_);
    uint4* dst = (uint4*)smT;
#pragma unroll
    for (int it = 0; it < 8; it++) {
      int i = t + it * 256;
      int row = i >> 4, col = i & 15;
      dst[row * 17 + col] = src[i];
    }
  }

  int nrow = n0 + w * 16 + l16;
  const float* base = qkv + ((size_t)b * N_ + nrow) * NO_ + h * DH_;
  bf16x8 qa[4], ka[4];
#pragma unroll
  for (int s = 0; s < 4; s++) {
    int k0 = s * 32 + quad * 8;
    float4 q0 = *(const float4*)(base + k0);
    float4 q1 = *(const float4*)(base + k0 + 4);
    float4 k0v = *(const float4*)(base + D_ + k0);
    float4 k1v = *(const float4*)(base + D_ + k0 + 4);
    bf16x8 qo, ko;
    qo[0]=(bf16)elu1(q0.x); qo[1]=(bf16)elu1(q0.y); qo[2]=(bf16)elu1(q0.z); qo[3]=(bf16)elu1(q0.w);
    qo[4]=(bf16)elu1(q1.x); qo[5]=(bf16)elu1(q1.y); qo[6]=(bf16)elu1(q1.z); qo[7]=(bf16)elu1(q1.w);
    ko[0]=(bf16)elu1(k0v.x); ko[1]=(bf16)elu1(k0v.y); ko[2]=(bf16)elu1(k0v.z); ko[3]=(bf16)elu1(k0v.w);
    ko[4]=(bf16)elu1(k1v.x); ko[5]=(bf16)elu1(k1v.y); ko[6]=(bf16)elu1(k1v.z); ko[7]=(bf16)elu1(k1v.w);
    qa[s] = qo; ka[s] = ko;
  }

  __syncthreads();
  f32x4 zf = {0.f, 0.f, 0.f, 0.f};
  f32x4 accq[8], acck[8];
#pragma unroll
  for (int vt = 0; vt < 8; vt++) { accq[vt] = zf; acck[vt] = zf; }
#pragma unroll
  for (int vt = 0; vt < 8; vt++) {
#pragma unroll
    for (int s = 0; s < 4; s++) {
      bf16x8 bfr = *(const bf16x8*)(smT + (vt * 16 + l16) * SMT_STRIDE + s * 32 + quad * 8);
      accq[vt] = mfma16(qa[s], bfr, accq[vt]);
      acck[vt] = mfma16(ka[s], bfr, acck[vt]);
    }
  }

  float g = 1.f / (1.f + __expf(-hg[h]));
#pragma unroll
  for (int r = 0; r < 4; r++) {
    int n = n0 + w * 16 + quad * 4 + r;
    size_t m = (size_t)b * N_ + n;
    float qd = fmaxf(qden[bh * N_ + n], 1e-10f);
    float kd = fmaxf(kden[bh * N_ + n], 1e-10f);
#pragma unroll
    for (int vt = 0; vt < 8; vt++) {
      int v = vt * 16 + l16;
      float mo = accq[vt][r] / qd;
      float ov = attn[(bh * N_ + n) * DH_ + v];
      comb[m * D_ + h * DH_ + v] = (bf16)(ov * g + mo * (1.f - g));
      float vv = qkv[m * NO_ + 2 * D_ + h * DH_ + v];
      vnew[(bh * N_ + n) * DH_ + v] = (bf16)(vv - acck[vt][r] / kd);
    }
  }
}

// ---------------- init outputs new_kv/new_norm with memories ----------------
__global__ void k_init_out(const float* __restrict__ mem_kv, const float* __restrict__ mem_norm,
                           float* __restrict__ out_kv, float* __restrict__ out_norm) {
  int i = blockIdx.x * 256 + threadIdx.x;
  if (i < B_ * H_ * DH_ * DH_) out_kv[i] = mem_kv[i];
  if (i < B_ * H_ * DH_) out_norm[i] = mem_norm[i];
}

// ---- new_kv: out_kv[bh] += kfT[bh] @ vnT[bh]^T, split-K over n ----
__global__ __launch_bounds__(256) void k_newkv2(const bf16* __restrict__ kfT,
                                                const bf16* __restrict__ vnT,
                                                float* __restrict__ out_kv) {
  __shared__ __align__(16) bf16 sA[128 * GSTR];
  __shared__ __align__(16) bf16 sB[128 * GSTR];
  int t = threadIdx.x;
  int w = t >> 6, lane = t & 63, quad = lane >> 4, l16 = lane & 15;
  size_t bh = (size_t)blockIdx.z * H_ + blockIdx.y;
  const bf16* A  = kfT + bh * DH_ * N_;
  const bf16* Bm = vnT + bh * DH_ * N_;
  int wr = (w & 1) * 64, wc = (w >> 1) * 64;
  f32x4 zf = {0.f, 0.f, 0.f, 0.f};
  f32x4 acc[4][4];
#pragma unroll
  for (int a = 0; a < 4; a++)
#pragma unroll
    for (int c = 0; c < 4; c++) acc[a][c] = zf;
  int trow = t >> 2, tc = t & 3;
  int kend = (blockIdx.x + 1) * 128;
  for (int k0 = blockIdx.x * 128; k0 < kend; k0 += 32) {
    __syncthreads();
    ((uint4*)sA)[trow * 5 + tc]        = *((const uint4*)(A + (size_t)trow * N_ + k0) + tc);
    ((uint4*)sA)[(trow + 64) * 5 + tc] = *((const uint4*)(A + (size_t)(trow + 64) * N_ + k0) + tc);
    ((uint4*)sB)[trow * 5 + tc]        = *((const uint4*)(Bm + (size_t)trow * N_ + k0) + tc);
    ((uint4*)sB)[(trow + 64) * 5 + tc] = *((const uint4*)(Bm + (size_t)(trow + 64) * N_ + k0) + tc);
    __syncthreads();
    bf16x8 af[4], bfr[4];
#pragma unroll
    for (int mt = 0; mt < 4; mt++)
      af[mt] = *(const bf16x8*)(sA + (wr + mt * 16 + l16) * GSTR + quad * 8);
#pragma unroll
    for (int nt = 0; nt < 4; nt++)
      bfr[nt] = *(const bf16x8*)(sB + (wc + nt * 16 + l16) * GSTR + quad * 8);
#pragma unroll
    for (int mt = 0; mt < 4; mt++)
#pragma unroll
      for (int nt = 0; nt < 4; nt++)
        acc[mt][nt] = mfma16(af[mt], bfr[nt], acc[mt][nt]);
  }
  float* obh = out_kv + bh * DH_ * DH_;
#pragma unroll
  for (int mt = 0; mt < 4; mt++)
#pragma unroll
    for (int nt = 0; nt < 4; nt++) {
      int row = wr + mt * 16 + quad * 4;
      int col = wc + nt * 16 + l16;
#pragma unroll
      for (int r = 0; r < 4; r++)
        atomicAdd(obh + (size_t)(row + r) * DH_ + col, acc[mt][nt][r]);
    }
}

// ---------------- new_norm partial: sum_n elu(k)+1 (fp32 from qkv) ---------
__global__ void k_newnorm(const float* __restrict__ qkv, float* __restrict__ out_norm) {
  int chunk = blockIdx.x;
  int h = blockIdx.y, b = blockIdx.z;
  int k = threadIdx.x;  // 128
  size_t bh = (size_t)b * H_ + h;
  float acc = 0.f;
  for (int i = 0; i < 256; i++) {
    size_t n = (size_t)chunk * 256 + i;
    float kv = qkv[((size_t)b * N_ + n) * NO_ + D_ + h * DH_ + k];
    acc += elu1(kv);
  }
  atomicAdd(out_norm + bh * DH_ + k, acc);
}

extern "C" void kernel_launch(void* const* d_in, const int* in_sizes, int n_in,
                              void* d_out, int out_size, void* d_ws, size_t ws_size,
                              hipStream_t stream) {
  const float* x        = (const float*)d_in[0];
  const float* gamma    = (const float*)d_in[1];
  const float* w_qkv    = (const float*)d_in[2];
  const float* w_out    = (const float*)d_in[3];
  const float* hg       = (const float*)d_in[4];
  const float* mem_kv   = (const float*)d_in[5];
  const float* mem_norm = (const float*)d_in[6];
  float* out      = (float*)d_out;
  float* out_kv   = out + (size_t)B_ * N_ * D_;
  float* out_norm = out_kv + (size_t)B_ * H_ * DH_ * DH_;

  char* ws = (char*)d_ws;
  size_t off = 0;
  auto alloc = [&](size_t bytes) -> void* {
    void* p = ws + off;
    off += (bytes + 255) & ~(size_t)255;
    return p;
  };
  bf16*  xn   = (bf16*)alloc((size_t)B_ * N_ * D_ * 2);
  bf16*  wqb  = (bf16*)alloc((size_t)NO_ * D_ * 2);
  bf16*  wob  = (bf16*)alloc((size_t)D_ * D_ * 2);
  float* qkv  = (float*)alloc((size_t)B_ * N_ * NO_ * 4);
  bf16*  qr   = (bf16*)alloc((size_t)B_ * H_ * N_ * DH_ * 2);
  bf16*  kr   = (bf16*)alloc((size_t)B_ * H_ * N_ * DH_ * 2);
  bf16*  vT   = (bf16*)alloc((size_t)B_ * H_ * DH_ * N_ * 2);
  bf16*  kf   = (bf16*)alloc((size_t)B_ * H_ * N_ * DH_ * 2);
  bf16*  vnew = (bf16*)alloc((size_t)B_ * H_ * N_ * DH_ * 2);
  float* qden = (float*)alloc((size_t)B_ * H_ * N_ * 4);
  float* kden = (float*)alloc((size_t)B_ * H_ * N_ * 4);
  float* attn = (float*)alloc((size_t)B_ * H_ * N_ * DH_ * 4);
  bf16*  mkvT = (bf16*)alloc((size_t)B_ * H_ * DH_ * DH_ * 2);
  // Union region: attention partials (pO 1536x64x128 bf16 + pstat) alias
  // comb/kfT/vnT, whose lifetimes start only after k_combine completes.
  size_t pO_bytes    = (size_t)1536 * 64 * DH_ * 2;           // 25.2 MB
  size_t pstat_bytes = (size_t)1536 * 64 * 2 * 4;             // 0.8 MB
  size_t comb_bytes  = (size_t)B_ * N_ * D_ * 2;              // 8 MB
  size_t kfT_bytes   = (size_t)B_ * H_ * DH_ * N_ * 2;        // 8 MB
  size_t union_bytes = pO_bytes + pstat_bytes;
  if (comb_bytes + 2 * kfT_bytes > union_bytes) union_bytes = comb_bytes + 2 * kfT_bytes;
  char* uni = (char*)alloc(union_bytes);
  bf16*  pO    = (bf16*)uni;
  float* pstat = (float*)(uni + pO_bytes);
  bf16*  comb  = (bf16*)uni;
  bf16*  kfT   = (bf16*)(uni + comb_bytes);
  bf16*  vnT   = (bf16*)(uni + comb_bytes + kfT_bytes);
  (void)in_sizes; (void)n_in; (void)out_size; (void)ws_size;

  k_rmsnorm<<<dim3(B_ * N_), 256, 0, stream>>>(x, gamma, xn);
  k_cvt4<<<(NO_ * D_ / 4 + 255) / 256, 256, 0, stream>>>((const float4*)w_qkv, (bf16x4*)wqb, NO_ * D_ / 4);
  k_cvt4<<<(D_ * D_ / 4 + 255) / 256, 256, 0, stream>>>((const float4*)w_out, (bf16x4*)wob, D_ * D_ / 4);
  k_mkvT<<<dim3(B_ * H_), 256, 0, stream>>>(mem_kv, mkvT);
  k_gemm_bt<<<dim3(NO_ / 128, B_ * N_ / 128), 256, 0, stream>>>(xn, wqb, qkv, B_ * N_, NO_, D_);
  k_prep<<<dim3(N_, H_, B_), 128, 0, stream>>>(qkv, mem_norm, qr, kr, vT, kf, qden, kden);
  k_attn2<<<dim3(1280), 256, 0, stream>>>(qr, kr, vT, attn, pO, pstat);
  k_combine<<<dim3(384), 256, 0, stream>>>(pO, pstat, attn);
  k_retrieve2<<<dim3(N_ / 64, H_, B_), 256, 0, stream>>>(qkv, mkvT, qden, kden, attn, hg, comb, vnew);
  k_gemm_bt<<<dim3(D_ / 128, B_ * N_ / 128), 256, 0, stream>>>(comb, wob, out, B_ * N_, D_, D_);
  k_transp<<<dim3(N_ / 64, DH_ / 64, B_ * H_), 256, 0, stream>>>(kf, kfT, N_, DH_);
  k_transp<<<dim3(N_ / 64, DH_ / 64, B_ * H_), 256, 0, stream>>>(vnew, vnT, N_, DH_);
  k_init_out<<<(B_ * H_ * DH_ * DH_ + 255) / 256, 256, 0, stream>>>(mem_kv, mem_norm, out_kv, out_norm);
  k_newkv2<<<dim3(16, H_, B_), 256, 0, stream>>>(kfT, vnT, out_kv);
  k_newnorm<<<dim3(N_ / 256, H_, B_), 128, 0, stream>>>(qkv, out_norm);
}

// Round 7
// 330.523 us; speedup vs baseline: 2.6594x; 1.0584x over previous
//
#include <hip/hip_runtime.h>
#include <hip/hip_bf16.h>

#define B_ 2
#define N_ 2048
#define H_ 8
#define DH_ 128
#define D_ 1024
#define NO_ 3072
#define SCALE_ 0.08838834764831845f

typedef __bf16 bf16;
typedef __bf16 bf16x4 __attribute__((ext_vector_type(4)));
typedef __bf16 bf16x8 __attribute__((ext_vector_type(8)));
typedef float f32x4 __attribute__((ext_vector_type(4)));

__device__ inline f32x4 mfma16(bf16x8 a, bf16x8 b, f32x4 c) {
  return __builtin_amdgcn_mfma_f32_16x16x32_bf16(a, b, c, 0, 0, 0);
}

__device__ inline float elu1(float x) { return x > 0.f ? x + 1.f : __expf(x); }

// async global->LDS 16B: lds dest = wave-uniform base + lane*16
__device__ inline void gl_lds16(const bf16* g, bf16* l) {
  __builtin_amdgcn_global_load_lds(
      (const __attribute__((address_space(1))) unsigned int*)g,
      (__attribute__((address_space(3))) unsigned int*)l, 16, 0, 0);
}

// ---------------- RMSNorm: x[4096][1024] -> xn bf16 ----------------
__global__ __launch_bounds__(256) void k_rmsnorm(const float* __restrict__ x,
                                                 const float* __restrict__ gamma,
                                                 bf16* __restrict__ xn) {
  int row = blockIdx.x;
  int t = threadIdx.x;
  const float4* xr = (const float4*)(x + (size_t)row * D_);
  float4 xv = xr[t];
  float ss = xv.x*xv.x + xv.y*xv.y + xv.z*xv.z + xv.w*xv.w;
#pragma unroll
  for (int m = 1; m < 64; m <<= 1) ss += __shfl_xor(ss, m);
  __shared__ float sred[4];
  if ((t & 63) == 0) sred[t >> 6] = ss;
  __syncthreads();
  float tot = sred[0] + sred[1] + sred[2] + sred[3];
  float scale = 32.0f / fmaxf(sqrtf(tot), 1e-12f);
  float4 gv = ((const float4*)gamma)[t];
  bf16x4 ov;
  ov[0] = (bf16)(xv.x * scale * gv.x);
  ov[1] = (bf16)(xv.y * scale * gv.y);
  ov[2] = (bf16)(xv.z * scale * gv.z);
  ov[3] = (bf16)(xv.w * scale * gv.w);
  *(bf16x4*)(xn + (size_t)row * D_ + t * 4) = ov;
}

// ---------------- fp32 -> bf16 convert ----------------
__global__ void k_cvt4(const float4* __restrict__ in, bf16x4* __restrict__ out, int n4) {
  int i = blockIdx.x * blockDim.x + threadIdx.x;
  if (i < n4) {
    float4 v = in[i];
    bf16x4 o;
    o[0] = (bf16)v.x; o[1] = (bf16)v.y; o[2] = (bf16)v.z; o[3] = (bf16)v.w;
    out[i] = o;
  }
}

// ---- mem_kv [bh][k][v] fp32 -> mkvT [bh][v][k] bf16 (global transpose) ----
__global__ __launch_bounds__(256) void k_mkvT(const float* __restrict__ mem_kv,
                                              bf16* __restrict__ mkvT) {
  int bh = blockIdx.x;
  int t = threadIdx.x;
  int v = t & 127, khalf = t >> 7;
  const float* src = mem_kv + (size_t)bh * DH_ * DH_;
  bf16* dst = mkvT + (size_t)bh * DH_ * DH_ + (size_t)v * DH_ + khalf * 64;
#pragma unroll
  for (int kk8 = 0; kk8 < 8; kk8++) {
    int k0 = khalf * 64 + kk8 * 8;
    bf16x8 o;
#pragma unroll
    for (int e = 0; e < 8; e++) o[e] = (bf16)src[(size_t)(k0 + e) * DH_ + v];
    *(bf16x8*)(dst + kk8 * 8) = o;
  }
}

// ---- batched bf16 transpose: in [bh][R][C] -> out [bh][C][R], 64x64 tiles ----
__global__ __launch_bounds__(256) void k_transp(const bf16* __restrict__ in,
                                                bf16* __restrict__ out, int R, int C) {
  __shared__ bf16 tile[64][72];
  int r0 = blockIdx.x * 64, c0 = blockIdx.y * 64;
  const bf16* src = in + (size_t)blockIdx.z * R * C;
  bf16* dst = out + (size_t)blockIdx.z * R * C;
  int t = threadIdx.x;
#pragma unroll
  for (int i = t; i < 512; i += 256) {
    int r = i >> 3, cu = i & 7;
    *(uint4*)&tile[r][cu * 8] = *(const uint4*)(src + (size_t)(r0 + r) * C + c0 + cu * 8);
  }
  __syncthreads();
#pragma unroll
  for (int i = t; i < 512; i += 256) {
    int c = i >> 3, ru = i & 7;
    bf16x8 o;
#pragma unroll
    for (int e = 0; e < 8; e++) o[e] = tile[ru * 8 + e][c];
    *(bf16x8*)(dst + (size_t)(c0 + c) * R + r0 + ru * 8) = o;
  }
}

// --- C[M][N] = A[M][K] @ B[N][K]^T, m97-style global_load_lds staging ---
// unpadded stride-32 LDS (required by lane-contiguous async dest); OT = bf16|f32
template <typename OT>
__global__ __launch_bounds__(256) void k_gemm_lds(const bf16* __restrict__ A,
                                                  const bf16* __restrict__ B,
                                                  OT* __restrict__ C,
                                                  int M, int Nn, int K) {
  __shared__ __align__(16) bf16 sA[128 * 32];
  __shared__ __align__(16) bf16 sB[128 * 32];
  int t = threadIdx.x;
  int w = t >> 6, lane = t & 63, quad = lane >> 4, l16 = lane & 15;
  int m0 = blockIdx.y * 128, n0 = blockIdx.x * 128;
  int wr = (w & 1) * 64, wc = (w >> 1) * 64;
  f32x4 zf = {0.f, 0.f, 0.f, 0.f};
  f32x4 acc[4][4];
#pragma unroll
  for (int a = 0; a < 4; a++)
#pragma unroll
    for (int c = 0; c < 4; c++) acc[a][c] = zf;
  int srow = w * 16 + (lane >> 2);   // 0..63
  int scol = (lane & 3) * 8;
  const bf16* gA = A + (size_t)(m0 + srow) * K + scol;
  const bf16* gB = B + (size_t)(n0 + srow) * K + scol;
  bf16* lA0 = sA + (size_t)w * 16 * 32;       // wave-uniform bases
  bf16* lA1 = sA + (size_t)(64 + w * 16) * 32;
  bf16* lB0 = sB + (size_t)w * 16 * 32;
  bf16* lB1 = sB + (size_t)(64 + w * 16) * 32;
  for (int k0 = 0; k0 < K; k0 += 32) {
    __syncthreads();
    gl_lds16(gA + k0, lA0);
    gl_lds16(gA + (size_t)64 * K + k0, lA1);
    gl_lds16(gB + k0, lB0);
    gl_lds16(gB + (size_t)64 * K + k0, lB1);
    __syncthreads();   // drains vmcnt for global_load_lds
    bf16x8 af[4], bfr[4];
#pragma unroll
    for (int mt = 0; mt < 4; mt++)
      af[mt] = *(const bf16x8*)(sA + (wr + mt * 16 + l16) * 32 + quad * 8);
#pragma unroll
    for (int nt = 0; nt < 4; nt++)
      bfr[nt] = *(const bf16x8*)(sB + (wc + nt * 16 + l16) * 32 + quad * 8);
#pragma unroll
    for (int mt = 0; mt < 4; mt++)
#pragma unroll
      for (int nt = 0; nt < 4; nt++)
        acc[mt][nt] = mfma16(af[mt], bfr[nt], acc[mt][nt]);
  }
#pragma unroll
  for (int mt = 0; mt < 4; mt++)
#pragma unroll
    for (int nt = 0; nt < 4; nt++) {
      int row = m0 + wr + mt * 16 + quad * 4;
      int col = n0 + wc + nt * 16 + l16;
      OT* cp = C + (size_t)row * Nn + col;
#pragma unroll
      for (int r = 0; r < 4; r++) cp[(size_t)r * Nn] = (OT)acc[mt][nt][r];
    }
}

// ---------------- prep: RoPE(q,k), kf, v^T, retrieval denominators --------
__global__ void k_prep(const bf16* __restrict__ qkv,
                       const float* __restrict__ mem_norm,
                       bf16* __restrict__ qr, bf16* __restrict__ kr,
                       bf16* __restrict__ vT, bf16* __restrict__ kf,
                       float* __restrict__ qden, float* __restrict__ kden) {
  int n = blockIdx.x;
  int h = blockIdx.y;
  int b = blockIdx.z;
  int d = threadIdx.x;  // 128
  size_t m = (size_t)b * N_ + n;
  const bf16* base = qkv + m * NO_ + h * DH_;
  float q = (float)base[d];
  float k = (float)base[D_ + d];
  bf16 v = base[2 * D_ + d];
  int j = d >> 1;
  float inv_freq = __powf(10000.0f, -(float)(2 * j) * (1.0f / 128.0f));
  float ang = (float)n * inv_freq;
  float sn, cs;
  __sincosf(ang, &sn, &cs);
  float qs = q * SCALE_;
  float qp = __shfl_xor(qs, 1);
  float qrot = (d & 1) ? qp : -qp;
  float kp = __shfl_xor(k, 1);
  float krot = (d & 1) ? kp : -kp;
  size_t bh = (size_t)b * H_ + h;
  size_t ro = (bh * N_ + n) * DH_ + d;
  qr[ro] = (bf16)(qs * cs + qrot * sn);
  kr[ro] = (bf16)(k * cs + krot * sn);
  float kfv = elu1(k);
  kf[ro] = (bf16)kfv;
  vT[(bh * DH_ + d) * N_ + n] = v;
  float qfv = elu1(q);
  float mn = mem_norm[bh * DH_ + d];
  float pq = qfv * mn;
  float pk = kfv * mn;
#pragma unroll
  for (int msk = 1; msk < 64; msk <<= 1) {
    pq += __shfl_xor(pq, msk);
    pk += __shfl_xor(pk, msk);
  }
  __shared__ float rq[2], rk[2];
  if ((d & 63) == 0) { rq[d >> 6] = pq; rk[d >> 6] = pk; }
  __syncthreads();
  if (d == 0) {
    qden[bh * N_ + n] = rq[0] + rq[1];
    kden[bh * N_ + n] = rk[0] + rk[1];
  }
}

// ------- flash attention, K-chunked (flash-decoding style) -------
#define KSTR 136
#define VSTR 72
__global__ __launch_bounds__(256) void k_attn2(const bf16* __restrict__ qr,
                                               const bf16* __restrict__ kr,
                                               const bf16* __restrict__ vT,
                                               float* __restrict__ attn_out,
                                               bf16* __restrict__ pO,
                                               float* __restrict__ pstat) {
  __shared__ __align__(16) bf16 sK[64 * KSTR];
  __shared__ __align__(16) bf16 sV[128 * VSTR];
  __shared__ __align__(16) bf16 sP[4][16 * VSTR];
  int x = blockIdx.x;
  size_t bh = x / 80;
  int e = x % 80;
  int qt, c;
  if (e < 32)      { qt = 31 - (e >> 2); c = e & 3; }
  else if (e < 56) { int u = e - 32; qt = 23 - u / 3; c = u % 3; }
  else if (e < 72) { int u = e - 56; qt = 15 - (u >> 1); c = u & 1; }
  else             { qt = 7 - (e - 72); c = 0; }
  int jt0 = c * 8;
  int jt1 = min(jt0 + 8, qt + 1);

  int t = threadIdx.x;
  int w = t >> 6, lane = t & 63, quad = lane >> 4, l16 = lane & 15;
  int qlo = qt * 64 + w * 16;

  bf16x8 qfrag[4];
  const bf16* qrow = qr + (bh * N_ + qlo + l16) * DH_;
#pragma unroll
  for (int s = 0; s < 4; s++) qfrag[s] = *(const bf16x8*)(qrow + s * 32 + quad * 8);

  f32x4 zf = {0.f, 0.f, 0.f, 0.f};
  f32x4 o[8];
#pragma unroll
  for (int i = 0; i < 8; i++) o[i] = zf;
  float mrow[4] = {-1e30f, -1e30f, -1e30f, -1e30f};
  float lrow[4] = {0.f, 0.f, 0.f, 0.f};

  for (int jt = jt0; jt < jt1; jt++) {
    __syncthreads();
    {
      const uint4* ksrc = (const uint4*)(kr + (bh * N_ + (size_t)jt * 64) * DH_);
#pragma unroll
      for (int p = 0; p < 4; p++) {
        int i = p * 256 + t;
        int row = i >> 4, c16 = i & 15;
        ((uint4*)sK)[row * 17 + c16] = ksrc[row * 16 + c16];
      }
#pragma unroll
      for (int p = 0; p < 4; p++) {
        int i = p * 256 + t;
        int row = i >> 3, c8 = i & 7;
        ((uint4*)sV)[row * 9 + c8] =
            *((const uint4*)(vT + (bh * DH_ + row) * N_ + (size_t)jt * 64) + c8);
      }
    }
    __syncthreads();

    f32x4 sf[4];
#pragma unroll
    for (int nt = 0; nt < 4; nt++) sf[nt] = zf;
#pragma unroll
    for (int s = 0; s < 4; s++) {
#pragma unroll
      for (int nt = 0; nt < 4; nt++) {
        bf16x8 b = *(const bf16x8*)(sK + (nt * 16 + l16) * KSTR + s * 32 + quad * 8);
        sf[nt] = mfma16(qfrag[s], b, sf[nt]);
      }
    }
    if (jt == qt) {
#pragma unroll
      for (int nt = 0; nt < 4; nt++) {
        int kg = jt * 64 + nt * 16 + l16;
#pragma unroll
        for (int r = 0; r < 4; r++) {
          int qg = qlo + quad * 4 + r;
          if (kg > qg) sf[nt][r] = -1e30f;
        }
      }
    }
    float alpha[4];
#pragma unroll
    for (int r = 0; r < 4; r++) {
      float tm = fmaxf(fmaxf(sf[0][r], sf[1][r]), fmaxf(sf[2][r], sf[3][r]));
      tm = fmaxf(tm, __shfl_xor(tm, 1));
      tm = fmaxf(tm, __shfl_xor(tm, 2));
      tm = fmaxf(tm, __shfl_xor(tm, 4));
      tm = fmaxf(tm, __shfl_xor(tm, 8));
      float mn = fmaxf(mrow[r], tm);
      alpha[r] = __expf(mrow[r] - mn);
      float rs = 0.f;
#pragma unroll
      for (int nt = 0; nt < 4; nt++) {
        float p = __expf(sf[nt][r] - mn);
        sf[nt][r] = p;
        rs += p;
      }
      rs += __shfl_xor(rs, 1);
      rs += __shfl_xor(rs, 2);
      rs += __shfl_xor(rs, 4);
      rs += __shfl_xor(rs, 8);
      lrow[r] = lrow[r] * alpha[r] + rs;
      mrow[r] = mn;
    }
#pragma unroll
    for (int i = 0; i < 8; i++) {
      o[i][0] *= alpha[0]; o[i][1] *= alpha[1];
      o[i][2] *= alpha[2]; o[i][3] *= alpha[3];
    }
    bf16* pw = sP[w];
#pragma unroll
    for (int nt = 0; nt < 4; nt++)
#pragma unroll
      for (int r = 0; r < 4; r++)
        pw[(quad * 4 + r) * VSTR + nt * 16 + l16] = (bf16)sf[nt][r];
    bf16x8 pa0 = *(const bf16x8*)(pw + l16 * VSTR + quad * 8);
    bf16x8 pa1 = *(const bf16x8*)(pw + l16 * VSTR + 32 + quad * 8);
#pragma unroll
    for (int vt = 0; vt < 8; vt++) {
      bf16x8 b0 = *(const bf16x8*)(sV + (vt * 16 + l16) * VSTR + quad * 8);
      bf16x8 b1 = *(const bf16x8*)(sV + (vt * 16 + l16) * VSTR + 32 + quad * 8);
      o[vt] = mfma16(pa0, b0, o[vt]);
      o[vt] = mfma16(pa1, b1, o[vt]);
    }
  }

  if (qt < 8) {
#pragma unroll
    for (int vt = 0; vt < 8; vt++)
#pragma unroll
      for (int r = 0; r < 4; r++) {
        int qg = qlo + quad * 4 + r;
        attn_out[(bh * N_ + qg) * DH_ + vt * 16 + l16] = o[vt][r] / lrow[r];
      }
  } else {
    int cid = ((int)bh * 24 + qt - 8) * 4 + c;
    if (l16 == 0) {
#pragma unroll
      for (int r = 0; r < 4; r++) {
        size_t si = ((size_t)cid * 64 + w * 16 + quad * 4 + r) * 2;
        pstat[si] = mrow[r];
        pstat[si + 1] = lrow[r];
      }
    }
#pragma unroll
    for (int vt = 0; vt < 8; vt++)
#pragma unroll
      for (int r = 0; r < 4; r++) {
        int lr = w * 16 + quad * 4 + r;
        pO[((size_t)cid * 64 + lr) * DH_ + vt * 16 + l16] = (bf16)o[vt][r];
      }
  }
}

// ------- combine partial chunks (qt>=8): up to 4 per q-row -------
__global__ __launch_bounds__(256) void k_combine(const bf16* __restrict__ pO,
                                                 const float* __restrict__ pstat,
                                                 float* __restrict__ attn_out) {
  int x = blockIdx.x;          // 384 = 16 bh * 24 qt
  int bh = x / 24, qi = x % 24;
  int qt = 8 + qi;
  int nch = (qt + 8) / 8;
  int t = threadIdx.x;
  int row = t >> 2, dseg = (t & 3) * 32;
  int cidb = (bh * 24 + qi) * 4;
  float ms[4], ls[4];
  float mg = -1e30f;
#pragma unroll 4
  for (int c = 0; c < nch; c++) {
    float2 st = *(const float2*)(pstat + ((size_t)(cidb + c) * 64 + row) * 2);
    ms[c] = st.x; ls[c] = st.y;
    mg = fmaxf(mg, st.x);
  }
  float L = 0.f, wc[4];
#pragma unroll 4
  for (int c = 0; c < nch; c++) { wc[c] = __expf(ms[c] - mg); L += ls[c] * wc[c]; }
  float inv = 1.f / L;
  float acc[32];
#pragma unroll
  for (int i = 0; i < 32; i++) acc[i] = 0.f;
#pragma unroll 4
  for (int c = 0; c < nch; c++) {
    const bf16x8* p = (const bf16x8*)(pO + ((size_t)(cidb + c) * 64 + row) * DH_ + dseg);
#pragma unroll
    for (int j = 0; j < 4; j++) {
      bf16x8 v = p[j];
#pragma unroll
      for (int e2 = 0; e2 < 8; e2++) acc[j * 8 + e2] += wc[c] * (float)v[e2];
    }
  }
  float* dst = attn_out + ((size_t)bh * N_ + qt * 64 + row) * DH_ + dseg;
#pragma unroll
  for (int i = 0; i < 32; i++) dst[i] = acc[i] * inv;
}

// ------- MFMA retrieval (q & k paths) + gate-combine + vnew -------
#define SMT_STRIDE 136
__global__ __launch_bounds__(256) void k_retrieve2(const bf16* __restrict__ qkv,
                                                   const bf16* __restrict__ mkvT,
                                                   const float* __restrict__ qden,
                                                   const float* __restrict__ kden,
                                                   const float* __restrict__ attn,
                                                   const float* __restrict__ hg,
                                                   bf16* __restrict__ comb,
                                                   bf16* __restrict__ vnew) {
  __shared__ __align__(16) bf16 smT[DH_ * SMT_STRIDE];
  int h = blockIdx.y, b = blockIdx.z;
  size_t bh = (size_t)b * H_ + h;
  int t = threadIdx.x;
  int w = t >> 6, lane = t & 63, quad = lane >> 4, l16 = lane & 15;
  int n0 = blockIdx.x * 64;

  {
    const uint4* src = (const uint4*)(mkvT + bh * DH_ * DH_);
    uint4* dst = (uint4*)smT;
#pragma unroll
    for (int it = 0; it < 8; it++) {
      int i = t + it * 256;
      int row = i >> 4, col = i & 15;
      dst[row * 17 + col] = src[i];
    }
  }

  int nrow = n0 + w * 16 + l16;
  const bf16* base = qkv + ((size_t)b * N_ + nrow) * NO_ + h * DH_;
  bf16x8 qa[4], ka[4];
#pragma unroll
  for (int s = 0; s < 4; s++) {
    int k0 = s * 32 + quad * 8;
    bf16x8 q8 = *(const bf16x8*)(base + k0);
    bf16x8 k8 = *(const bf16x8*)(base + D_ + k0);
    bf16x8 qo, ko;
#pragma unroll
    for (int e2 = 0; e2 < 8; e2++) {
      qo[e2] = (bf16)elu1((float)q8[e2]);
      ko[e2] = (bf16)elu1((float)k8[e2]);
    }
    qa[s] = qo; ka[s] = ko;
  }

  __syncthreads();
  f32x4 zf = {0.f, 0.f, 0.f, 0.f};
  f32x4 accq[8], acck[8];
#pragma unroll
  for (int vt = 0; vt < 8; vt++) { accq[vt] = zf; acck[vt] = zf; }
#pragma unroll
  for (int vt = 0; vt < 8; vt++) {
#pragma unroll
    for (int s = 0; s < 4; s++) {
      bf16x8 bfr = *(const bf16x8*)(smT + (vt * 16 + l16) * SMT_STRIDE + s * 32 + quad * 8);
      accq[vt] = mfma16(qa[s], bfr, accq[vt]);
      acck[vt] = mfma16(ka[s], bfr, acck[vt]);
    }
  }

  float g = 1.f / (1.f + __expf(-hg[h]));
#pragma unroll
  for (int r = 0; r < 4; r++) {
    int n = n0 + w * 16 + quad * 4 + r;
    size_t m = (size_t)b * N_ + n;
    float qd = fmaxf(qden[bh * N_ + n], 1e-10f);
    float kd = fmaxf(kden[bh * N_ + n], 1e-10f);
#pragma unroll
    for (int vt = 0; vt < 8; vt++) {
      int v = vt * 16 + l16;
      float mo = accq[vt][r] / qd;
      float ov = attn[(bh * N_ + n) * DH_ + v];
      comb[m * D_ + h * DH_ + v] = (bf16)(ov * g + mo * (1.f - g));
      float vv = (float)qkv[m * NO_ + 2 * D_ + h * DH_ + v];
      vnew[(bh * N_ + n) * DH_ + v] = (bf16)(vv - acck[vt][r] / kd);
    }
  }
}

// ---------------- init out_kv with mem_kv ----------------
__global__ void k_init_kv(const float* __restrict__ mem_kv, float* __restrict__ out_kv) {
  int i = blockIdx.x * 256 + threadIdx.x;
  if (i < B_ * H_ * DH_ * DH_) out_kv[i] = mem_kv[i];
}

// ---- new_kv: out_kv[bh] += kfT[bh] @ vnT[bh]^T, split-K over n ----
#define GSTR 40
__global__ __launch_bounds__(256) void k_newkv2(const bf16* __restrict__ kfT,
                                                const bf16* __restrict__ vnT,
                                                float* __restrict__ out_kv) {
  __shared__ __align__(16) bf16 sA[128 * GSTR];
  __shared__ __align__(16) bf16 sB[128 * GSTR];
  int t = threadIdx.x;
  int w = t >> 6, lane = t & 63, quad = lane >> 4, l16 = lane & 15;
  size_t bh = (size_t)blockIdx.z * H_ + blockIdx.y;
  const bf16* A  = kfT + bh * DH_ * N_;
  const bf16* Bm = vnT + bh * DH_ * N_;
  int wr = (w & 1) * 64, wc = (w >> 1) * 64;
  f32x4 zf = {0.f, 0.f, 0.f, 0.f};
  f32x4 acc[4][4];
#pragma unroll
  for (int a = 0; a < 4; a++)
#pragma unroll
    for (int c = 0; c < 4; c++) acc[a][c] = zf;
  int trow = t >> 2, tc = t & 3;
  int kend = (blockIdx.x + 1) * 128;
  for (int k0 = blockIdx.x * 128; k0 < kend; k0 += 32) {
    __syncthreads();
    ((uint4*)sA)[trow * 5 + tc]        = *((const uint4*)(A + (size_t)trow * N_ + k0) + tc);
    ((uint4*)sA)[(trow + 64) * 5 + tc] = *((const uint4*)(A + (size_t)(trow + 64) * N_ + k0) + tc);
    ((uint4*)sB)[trow * 5 + tc]        = *((const uint4*)(Bm + (size_t)trow * N_ + k0) + tc);
    ((uint4*)sB)[(trow + 64) * 5 + tc] = *((const uint4*)(Bm + (size_t)(trow + 64) * N_ + k0) + tc);
    __syncthreads();
    bf16x8 af[4], bfr[4];
#pragma unroll
    for (int mt = 0; mt < 4; mt++)
      af[mt] = *(const bf16x8*)(sA + (wr + mt * 16 + l16) * GSTR + quad * 8);
#pragma unroll
    for (int nt = 0; nt < 4; nt++)
      bfr[nt] = *(const bf16x8*)(sB + (wc + nt * 16 + l16) * GSTR + quad * 8);
#pragma unroll
    for (int mt = 0; mt < 4; mt++)
#pragma unroll
      for (int nt = 0; nt < 4; nt++)
        acc[mt][nt] = mfma16(af[mt], bfr[nt], acc[mt][nt]);
  }
  float* obh = out_kv + bh * DH_ * DH_;
#pragma unroll
  for (int mt = 0; mt < 4; mt++)
#pragma unroll
    for (int nt = 0; nt < 4; nt++) {
      int row = wr + mt * 16 + quad * 4;
      int col = wc + nt * 16 + l16;
#pragma unroll
      for (int r = 0; r < 4; r++)
        atomicAdd(obh + (size_t)(row + r) * DH_ + col, acc[mt][nt][r]);
    }
}

// ---- new_norm: out_norm[bh][k] = mem_norm + row-sum of kfT (coalesced) ----
__global__ __launch_bounds__(256) void k_newnorm2(const bf16* __restrict__ kfT,
                                                  const float* __restrict__ mem_norm,
                                                  float* __restrict__ out_norm) {
  int bh = blockIdx.x;
  int t = threadIdx.x;
  int k = t >> 1, half = t & 1;
  const bf16x8* row = (const bf16x8*)(kfT + ((size_t)bh * DH_ + k) * N_ + half * (N_ / 2));
  float s = 0.f;
#pragma unroll 4
  for (int i = 0; i < N_ / 16; i++) {
    bf16x8 v = row[i];
#pragma unroll
    for (int e = 0; e < 8; e++) s += (float)v[e];
  }
  s += __shfl_xor(s, 1);
  if (half == 0) out_norm[(size_t)bh * DH_ + k] = mem_norm[(size_t)bh * DH_ + k] + s;
}

extern "C" void kernel_launch(void* const* d_in, const int* in_sizes, int n_in,
                              void* d_out, int out_size, void* d_ws, size_t ws_size,
                              hipStream_t stream) {
  const float* x        = (const float*)d_in[0];
  const float* gamma    = (const float*)d_in[1];
  const float* w_qkv    = (const float*)d_in[2];
  const float* w_out    = (const float*)d_in[3];
  const float* hg       = (const float*)d_in[4];
  const float* mem_kv   = (const float*)d_in[5];
  const float* mem_norm = (const float*)d_in[6];
  float* out      = (float*)d_out;
  float* out_kv   = out + (size_t)B_ * N_ * D_;
  float* out_norm = out_kv + (size_t)B_ * H_ * DH_ * DH_;

  char* ws = (char*)d_ws;
  size_t off = 0;
  auto alloc = [&](size_t bytes) -> void* {
    void* p = ws + off;
    off += (bytes + 255) & ~(size_t)255;
    return p;
  };
  bf16*  xn   = (bf16*)alloc((size_t)B_ * N_ * D_ * 2);
  bf16*  wqb  = (bf16*)alloc((size_t)NO_ * D_ * 2);
  bf16*  wob  = (bf16*)alloc((size_t)D_ * D_ * 2);
  bf16*  qkvb = (bf16*)alloc((size_t)B_ * N_ * NO_ * 2);
  bf16*  qr   = (bf16*)alloc((size_t)B_ * H_ * N_ * DH_ * 2);
  bf16*  kr   = (bf16*)alloc((size_t)B_ * H_ * N_ * DH_ * 2);
  bf16*  vT   = (bf16*)alloc((size_t)B_ * H_ * DH_ * N_ * 2);
  bf16*  kf   = (bf16*)alloc((size_t)B_ * H_ * N_ * DH_ * 2);
  bf16*  vnew = (bf16*)alloc((size_t)B_ * H_ * N_ * DH_ * 2);
  float* qden = (float*)alloc((size_t)B_ * H_ * N_ * 4);
  float* kden = (float*)alloc((size_t)B_ * H_ * N_ * 4);
  float* attn = (float*)alloc((size_t)B_ * H_ * N_ * DH_ * 4);
  bf16*  mkvT = (bf16*)alloc((size_t)B_ * H_ * DH_ * DH_ * 2);
  size_t pO_bytes    = (size_t)1536 * 64 * DH_ * 2;
  size_t pstat_bytes = (size_t)1536 * 64 * 2 * 4;
  size_t comb_bytes  = (size_t)B_ * N_ * D_ * 2;
  size_t kfT_bytes   = (size_t)B_ * H_ * DH_ * N_ * 2;
  size_t union_bytes = pO_bytes + pstat_bytes;
  if (comb_bytes + 2 * kfT_bytes > union_bytes) union_bytes = comb_bytes + 2 * kfT_bytes;
  char* uni = (char*)alloc(union_bytes);
  bf16*  pO    = (bf16*)uni;
  float* pstat = (float*)(uni + pO_bytes);
  bf16*  comb  = (bf16*)uni;
  bf16*  kfT   = (bf16*)(uni + comb_bytes);
  bf16*  vnT   = (bf16*)(uni + comb_bytes + kfT_bytes);
  (void)in_sizes; (void)n_in; (void)out_size; (void)ws_size;

  k_rmsnorm<<<dim3(B_ * N_), 256, 0, stream>>>(x, gamma, xn);
  k_cvt4<<<(NO_ * D_ / 4 + 255) / 256, 256, 0, stream>>>((const float4*)w_qkv, (bf16x4*)wqb, NO_ * D_ / 4);
  k_cvt4<<<(D_ * D_ / 4 + 255) / 256, 256, 0, stream>>>((const float4*)w_out, (bf16x4*)wob, D_ * D_ / 4);
  k_mkvT<<<dim3(B_ * H_), 256, 0, stream>>>(mem_kv, mkvT);
  k_gemm_lds<bf16><<<dim3(NO_ / 128, B_ * N_ / 128), 256, 0, stream>>>(xn, wqb, qkvb, B_ * N_, NO_, D_);
  k_prep<<<dim3(N_, H_, B_), 128, 0, stream>>>(qkvb, mem_norm, qr, kr, vT, kf, qden, kden);
  k_attn2<<<dim3(1280), 256, 0, stream>>>(qr, kr, vT, attn, pO, pstat);
  k_combine<<<dim3(384), 256, 0, stream>>>(pO, pstat, attn);
  k_retrieve2<<<dim3(N_ / 64, H_, B_), 256, 0, stream>>>(qkvb, mkvT, qden, kden, attn, hg, comb, vnew);
  k_gemm_lds<float><<<dim3(D_ / 128, B_ * N_ / 128), 256, 0, stream>>>(comb, wob, out, B_ * N_, D_, D_);
  k_transp<<<dim3(N_ / 64, DH_ / 64, B_ * H_), 256, 0, stream>>>(kf, kfT, N_, DH_);
  k_transp<<<dim3(N_ / 64, DH_ / 64, B_ * H_), 256, 0, stream>>>(vnew, vnT, N_, DH_);
  k_init_kv<<<(B_ * H_ * DH_ * DH_ + 255) / 256, 256, 0, stream>>>(mem_kv, out_kv);
  k_newkv2<<<dim3(16, H_, B_), 256, 0, stream>>>(kfT, vnT, out_kv);
  k_newnorm2<<<dim3(B_ * H_), 256, 0, stream>>>(kfT, mem_norm, out_norm);
}

// Round 9
// 302.075 us; speedup vs baseline: 2.9099x; 1.0942x over previous
//
#include <hip/hip_runtime.h>
#include <hip/hip_bf16.h>

#define B_ 2
#define N_ 2048
#define H_ 8
#define DH_ 128
#define D_ 1024
#define NO_ 3072
#define SCALE_ 0.08838834764831845f

typedef __bf16 bf16;
typedef __bf16 bf16x4 __attribute__((ext_vector_type(4)));
typedef __bf16 bf16x8 __attribute__((ext_vector_type(8)));
typedef float f32x4 __attribute__((ext_vector_type(4)));

__device__ inline f32x4 mfma16(bf16x8 a, bf16x8 b, f32x4 c) {
  return __builtin_amdgcn_mfma_f32_16x16x32_bf16(a, b, c, 0, 0, 0);
}

__device__ inline float elu1(float x) { return x > 0.f ? x + 1.f : __expf(x); }

// async global->LDS 16B: lds dest = wave-uniform base + lane*16
__device__ inline void gl_lds16(const bf16* g, bf16* l) {
  __builtin_amdgcn_global_load_lds(
      (const __attribute__((address_space(1))) unsigned int*)g,
      (__attribute__((address_space(3))) unsigned int*)l, 16, 0, 0);
}

// ---------------- RMSNorm: x[4096][1024] -> xn bf16 ----------------
__global__ __launch_bounds__(256) void k_rmsnorm(const float* __restrict__ x,
                                                 const float* __restrict__ gamma,
                                                 bf16* __restrict__ xn) {
  int row = blockIdx.x;
  int t = threadIdx.x;
  const float4* xr = (const float4*)(x + (size_t)row * D_);
  float4 xv = xr[t];
  float ss = xv.x*xv.x + xv.y*xv.y + xv.z*xv.z + xv.w*xv.w;
#pragma unroll
  for (int m = 1; m < 64; m <<= 1) ss += __shfl_xor(ss, m);
  __shared__ float sred[4];
  if ((t & 63) == 0) sred[t >> 6] = ss;
  __syncthreads();
  float tot = sred[0] + sred[1] + sred[2] + sred[3];
  float scale = 32.0f / fmaxf(sqrtf(tot), 1e-12f);
  float4 gv = ((const float4*)gamma)[t];
  bf16x4 ov;
  ov[0] = (bf16)(xv.x * scale * gv.x);
  ov[1] = (bf16)(xv.y * scale * gv.y);
  ov[2] = (bf16)(xv.z * scale * gv.z);
  ov[3] = (bf16)(xv.w * scale * gv.w);
  *(bf16x4*)(xn + (size_t)row * D_ + t * 4) = ov;
}

// ---------------- fp32 -> bf16 convert ----------------
__global__ void k_cvt4(const float4* __restrict__ in, bf16x4* __restrict__ out, int n4) {
  int i = blockIdx.x * blockDim.x + threadIdx.x;
  if (i < n4) {
    float4 v = in[i];
    bf16x4 o;
    o[0] = (bf16)v.x; o[1] = (bf16)v.y; o[2] = (bf16)v.z; o[3] = (bf16)v.w;
    out[i] = o;
  }
}

// ---- mem_kv [bh][k][v] fp32 -> mkvT [bh][v][k] bf16 (global transpose) ----
__global__ __launch_bounds__(256) void k_mkvT(const float* __restrict__ mem_kv,
                                              bf16* __restrict__ mkvT) {
  int bh = blockIdx.x;
  int t = threadIdx.x;
  int v = t & 127, khalf = t >> 7;
  const float* src = mem_kv + (size_t)bh * DH_ * DH_;
  bf16* dst = mkvT + (size_t)bh * DH_ * DH_ + (size_t)v * DH_ + khalf * 64;
#pragma unroll
  for (int kk8 = 0; kk8 < 8; kk8++) {
    int k0 = khalf * 64 + kk8 * 8;
    bf16x8 o;
#pragma unroll
    for (int e = 0; e < 8; e++) o[e] = (bf16)src[(size_t)(k0 + e) * DH_ + v];
    *(bf16x8*)(dst + kk8 * 8) = o;
  }
}

// --- C[M][N] = A[M][K] @ B[N][K]^T, m97-style global_load_lds staging ---
template <typename OT>
__global__ __launch_bounds__(256) void k_gemm_lds(const bf16* __restrict__ A,
                                                  const bf16* __restrict__ B,
                                                  OT* __restrict__ C,
                                                  int M, int Nn, int K) {
  __shared__ __align__(16) bf16 sA[128 * 32];
  __shared__ __align__(16) bf16 sB[128 * 32];
  int t = threadIdx.x;
  int w = t >> 6, lane = t & 63, quad = lane >> 4, l16 = lane & 15;
  int m0 = blockIdx.y * 128, n0 = blockIdx.x * 128;
  int wr = (w & 1) * 64, wc = (w >> 1) * 64;
  f32x4 zf = {0.f, 0.f, 0.f, 0.f};
  f32x4 acc[4][4];
#pragma unroll
  for (int a = 0; a < 4; a++)
#pragma unroll
    for (int c = 0; c < 4; c++) acc[a][c] = zf;
  int srow = w * 16 + (lane >> 2);
  int scol = (lane & 3) * 8;
  const bf16* gA = A + (size_t)(m0 + srow) * K + scol;
  const bf16* gB = B + (size_t)(n0 + srow) * K + scol;
  bf16* lA0 = sA + (size_t)w * 16 * 32;
  bf16* lA1 = sA + (size_t)(64 + w * 16) * 32;
  bf16* lB0 = sB + (size_t)w * 16 * 32;
  bf16* lB1 = sB + (size_t)(64 + w * 16) * 32;
  for (int k0 = 0; k0 < K; k0 += 32) {
    __syncthreads();
    gl_lds16(gA + k0, lA0);
    gl_lds16(gA + (size_t)64 * K + k0, lA1);
    gl_lds16(gB + k0, lB0);
    gl_lds16(gB + (size_t)64 * K + k0, lB1);
    __syncthreads();
    bf16x8 af[4], bfr[4];
#pragma unroll
    for (int mt = 0; mt < 4; mt++)
      af[mt] = *(const bf16x8*)(sA + (wr + mt * 16 + l16) * 32 + quad * 8);
#pragma unroll
    for (int nt = 0; nt < 4; nt++)
      bfr[nt] = *(const bf16x8*)(sB + (wc + nt * 16 + l16) * 32 + quad * 8);
#pragma unroll
    for (int mt = 0; mt < 4; mt++)
#pragma unroll
      for (int nt = 0; nt < 4; nt++)
        acc[mt][nt] = mfma16(af[mt], bfr[nt], acc[mt][nt]);
  }
#pragma unroll
  for (int mt = 0; mt < 4; mt++)
#pragma unroll
    for (int nt = 0; nt < 4; nt++) {
      int row = m0 + wr + mt * 16 + quad * 4;
      int col = n0 + wc + nt * 16 + l16;
      OT* cp = C + (size_t)row * Nn + col;
#pragma unroll
      for (int r = 0; r < 4; r++) cp[(size_t)r * Nn] = (OT)acc[mt][nt][r];
    }
}

// --- prep2: 64 tokens x 1 head per block. RoPE(q,k) -> qr,kr (n-major);
//     kf,v -> kfT,vT (d-major via LDS transpose); qden/kden reductions. ---
__global__ __launch_bounds__(256) void k_prep2(const bf16* __restrict__ qkv,
                                               const float* __restrict__ mem_norm,
                                               bf16* __restrict__ qr, bf16* __restrict__ kr,
                                               bf16* __restrict__ vT, bf16* __restrict__ kfT,
                                               float* __restrict__ qden, float* __restrict__ kden) {
  __shared__ __align__(16) bf16 sQ[64 * 136], sK[64 * 136], sV[64 * 136];
  __shared__ float smn[128];
  int n0 = blockIdx.x * 64, h = blockIdx.y, b = blockIdx.z;
  size_t bh = (size_t)b * H_ + h;
  int t = threadIdx.x;
#pragma unroll
  for (int p = 0; p < 4; p++) {
    int i = p * 256 + t;            // 1024 uint4 per plane
    int row = i >> 4, c16 = i & 15;
    size_t base = ((size_t)b * N_ + n0 + row) * NO_ + (size_t)h * DH_;
    ((uint4*)sQ)[row * 17 + c16] = *((const uint4*)(qkv + base) + c16);
    ((uint4*)sK)[row * 17 + c16] = *((const uint4*)(qkv + base + D_) + c16);
    ((uint4*)sV)[row * 17 + c16] = *((const uint4*)(qkv + base + 2 * D_) + c16);
  }
  if (t < 128) smn[t] = mem_norm[bh * DH_ + t];
  __syncthreads();
  int row = t >> 1, h2 = t & 1, d0 = h2 * 64;
  int n = n0 + row;
  float sq = 0.f, sk = 0.f;
  const float cexp = 13.287712379549449f / 128.0f;  // log2(10000)/128
#pragma unroll 2
  for (int c = 0; c < 8; c++) {
    bf16x8 q8 = *(const bf16x8*)(sQ + row * 136 + d0 + c * 8);
    bf16x8 k8 = *(const bf16x8*)(sK + row * 136 + d0 + c * 8);
    bf16x8 qo, ko, kf8;
#pragma unroll
    for (int e = 0; e < 8; e += 2) {
      int d = d0 + c * 8 + e;
      float invf = exp2f(-(float)d * cexp);
      float ang = (float)n * invf;
      float sn, cs;
      __sincosf(ang, &sn, &cs);
      float qx = (float)q8[e] * SCALE_, qy = (float)q8[e + 1] * SCALE_;
      qo[e]     = (bf16)(qx * cs - qy * sn);
      qo[e + 1] = (bf16)(qy * cs + qx * sn);
      float kx = (float)k8[e], ky = (float)k8[e + 1];
      ko[e]     = (bf16)(kx * cs - ky * sn);
      ko[e + 1] = (bf16)(ky * cs + kx * sn);
      float f0 = elu1(kx), f1 = elu1(ky);
      kf8[e] = (bf16)f0; kf8[e + 1] = (bf16)f1;
      sk += f0 * smn[d] + f1 * smn[d + 1];
      sq += elu1((float)q8[e]) * smn[d] + elu1((float)q8[e + 1]) * smn[d + 1];
    }
    *(bf16x8*)(qr + (bh * N_ + n) * DH_ + d0 + c * 8) = qo;
    *(bf16x8*)(kr + (bh * N_ + n) * DH_ + d0 + c * 8) = ko;
    *(bf16x8*)(sK + row * 136 + d0 + c * 8) = kf8;  // in place; region owned by this thread
  }
  sq += __shfl_xor(sq, 1);
  sk += __shfl_xor(sk, 1);
  if (h2 == 0) { qden[bh * N_ + n] = sq; kden[bh * N_ + n] = sk; }
  __syncthreads();
  // transpose out: kfT, vT rows d (128), cols n (64)
  int d = t >> 1, part = t & 1;
#pragma unroll
  for (int v8 = 0; v8 < 4; v8++) {
    bf16x8 okf, ov;
#pragma unroll
    for (int e = 0; e < 8; e++) {
      int nn = part * 32 + v8 * 8 + e;
      okf[e] = sK[nn * 136 + d];
      ov[e]  = sV[nn * 136 + d];
    }
    size_t o = (bh * DH_ + d) * N_ + n0 + part * 32 + v8 * 8;
    *(bf16x8*)(kfT + o) = okf;
    *(bf16x8*)(vT + o)  = ov;
  }
}

// ------- flash attention, K-chunked (flash-decoding style) -------
#define KSTR 136
#define VSTR 72
__global__ __launch_bounds__(256) void k_attn2(const bf16* __restrict__ qr,
                                               const bf16* __restrict__ kr,
                                               const bf16* __restrict__ vT,
                                               bf16* __restrict__ attn_out,
                                               bf16* __restrict__ pO,
                                               float* __restrict__ pstat) {
  __shared__ __align__(16) bf16 sK[64 * KSTR];
  __shared__ __align__(16) bf16 sV[128 * VSTR];
  __shared__ __align__(16) bf16 sP[4][16 * VSTR];
  int x = blockIdx.x;
  size_t bh = x / 80;
  int e = x % 80;
  int qt, c;
  if (e < 32)      { qt = 31 - (e >> 2); c = e & 3; }
  else if (e < 56) { int u = e - 32; qt = 23 - u / 3; c = u % 3; }
  else if (e < 72) { int u = e - 56; qt = 15 - (u >> 1); c = u & 1; }
  else             { qt = 7 - (e - 72); c = 0; }
  int jt0 = c * 8;
  int jt1 = min(jt0 + 8, qt + 1);

  int t = threadIdx.x;
  int w = t >> 6, lane = t & 63, quad = lane >> 4, l16 = lane & 15;
  int qlo = qt * 64 + w * 16;

  bf16x8 qfrag[4];
  const bf16* qrow = qr + (bh * N_ + qlo + l16) * DH_;
#pragma unroll
  for (int s = 0; s < 4; s++) qfrag[s] = *(const bf16x8*)(qrow + s * 32 + quad * 8);

  f32x4 zf = {0.f, 0.f, 0.f, 0.f};
  f32x4 o[8];
#pragma unroll
  for (int i = 0; i < 8; i++) o[i] = zf;
  float mrow[4] = {-1e30f, -1e30f, -1e30f, -1e30f};
  float lrow[4] = {0.f, 0.f, 0.f, 0.f};

  for (int jt = jt0; jt < jt1; jt++) {
    __syncthreads();
    {
      const uint4* ksrc = (const uint4*)(kr + (bh * N_ + (size_t)jt * 64) * DH_);
#pragma unroll
      for (int p = 0; p < 4; p++) {
        int i = p * 256 + t;
        int row = i >> 4, c16 = i & 15;
        ((uint4*)sK)[row * 17 + c16] = ksrc[row * 16 + c16];
      }
#pragma unroll
      for (int p = 0; p < 4; p++) {
        int i = p * 256 + t;
        int row = i >> 3, c8 = i & 7;
        ((uint4*)sV)[row * 9 + c8] =
            *((const uint4*)(vT + (bh * DH_ + row) * N_ + (size_t)jt * 64) + c8);
      }
    }
    __syncthreads();

    f32x4 sf[4];
#pragma unroll
    for (int nt = 0; nt < 4; nt++) sf[nt] = zf;
#pragma unroll
    for (int s = 0; s < 4; s++) {
#pragma unroll
      for (int nt = 0; nt < 4; nt++) {
        bf16x8 b = *(const bf16x8*)(sK + (nt * 16 + l16) * KSTR + s * 32 + quad * 8);
        sf[nt] = mfma16(qfrag[s], b, sf[nt]);
      }
    }
    if (jt == qt) {
#pragma unroll
      for (int nt = 0; nt < 4; nt++) {
        int kg = jt * 64 + nt * 16 + l16;
#pragma unroll
        for (int r = 0; r < 4; r++) {
          int qg = qlo + quad * 4 + r;
          if (kg > qg) sf[nt][r] = -1e30f;
        }
      }
    }
    float alpha[4];
#pragma unroll
    for (int r = 0; r < 4; r++) {
      float tm = fmaxf(fmaxf(sf[0][r], sf[1][r]), fmaxf(sf[2][r], sf[3][r]));
      tm = fmaxf(tm, __shfl_xor(tm, 1));
      tm = fmaxf(tm, __shfl_xor(tm, 2));
      tm = fmaxf(tm, __shfl_xor(tm, 4));
      tm = fmaxf(tm, __shfl_xor(tm, 8));
      float mn = fmaxf(mrow[r], tm);
      alpha[r] = __expf(mrow[r] - mn);
      float rs = 0.f;
#pragma unroll
      for (int nt = 0; nt < 4; nt++) {
        float p = __expf(sf[nt][r] - mn);
        sf[nt][r] = p;
        rs += p;
      }
      rs += __shfl_xor(rs, 1);
      rs += __shfl_xor(rs, 2);
      rs += __shfl_xor(rs, 4);
      rs += __shfl_xor(rs, 8);
      lrow[r] = lrow[r] * alpha[r] + rs;
      mrow[r] = mn;
    }
#pragma unroll
    for (int i = 0; i < 8; i++) {
      o[i][0] *= alpha[0]; o[i][1] *= alpha[1];
      o[i][2] *= alpha[2]; o[i][3] *= alpha[3];
    }
    bf16* pw = sP[w];
#pragma unroll
    for (int nt = 0; nt < 4; nt++)
#pragma unroll
      for (int r = 0; r < 4; r++)
        pw[(quad * 4 + r) * VSTR + nt * 16 + l16] = (bf16)sf[nt][r];
    bf16x8 pa0 = *(const bf16x8*)(pw + l16 * VSTR + quad * 8);
    bf16x8 pa1 = *(const bf16x8*)(pw + l16 * VSTR + 32 + quad * 8);
#pragma unroll
    for (int vt = 0; vt < 8; vt++) {
      bf16x8 b0 = *(const bf16x8*)(sV + (vt * 16 + l16) * VSTR + quad * 8);
      bf16x8 b1 = *(const bf16x8*)(sV + (vt * 16 + l16) * VSTR + 32 + quad * 8);
      o[vt] = mfma16(pa0, b0, o[vt]);
      o[vt] = mfma16(pa1, b1, o[vt]);
    }
  }

  if (qt < 8) {
#pragma unroll
    for (int vt = 0; vt < 8; vt++)
#pragma unroll
      for (int r = 0; r < 4; r++) {
        int qg = qlo + quad * 4 + r;
        attn_out[(bh * N_ + qg) * DH_ + vt * 16 + l16] = (bf16)(o[vt][r] / lrow[r]);
      }
  } else {
    int cid = ((int)bh * 24 + qt - 8) * 4 + c;
    if (l16 == 0) {
#pragma unroll
      for (int r = 0; r < 4; r++) {
        size_t si = ((size_t)cid * 64 + w * 16 + quad * 4 + r) * 2;
        pstat[si] = mrow[r];
        pstat[si + 1] = lrow[r];
      }
    }
#pragma unroll
    for (int vt = 0; vt < 8; vt++)
#pragma unroll
      for (int r = 0; r < 4; r++) {
        int lr = w * 16 + quad * 4 + r;
        pO[((size_t)cid * 64 + lr) * DH_ + vt * 16 + l16] = (bf16)o[vt][r];
      }
  }
}

// ------- combine partial chunks (qt>=8): up to 4 per q-row -------
__global__ __launch_bounds__(256) void k_combine(const bf16* __restrict__ pO,
                                                 const float* __restrict__ pstat,
                                                 bf16* __restrict__ attn_out) {
  int x = blockIdx.x;          // 384 = 16 bh * 24 qt
  int bh = x / 24, qi = x % 24;
  int qt = 8 + qi;
  int nch = (qt + 8) / 8;
  int t = threadIdx.x;
  int row = t >> 2, dseg = (t & 3) * 32;
  int cidb = (bh * 24 + qi) * 4;
  float ms[4], ls[4];
  float mg = -1e30f;
#pragma unroll 4
  for (int c = 0; c < nch; c++) {
    float2 st = *(const float2*)(pstat + ((size_t)(cidb + c) * 64 + row) * 2);
    ms[c] = st.x; ls[c] = st.y;
    mg = fmaxf(mg, st.x);
  }
  float L = 0.f, wc[4];
#pragma unroll 4
  for (int c = 0; c < nch; c++) { wc[c] = __expf(ms[c] - mg); L += ls[c] * wc[c]; }
  float inv = 1.f / L;
  float acc[32];
#pragma unroll
  for (int i = 0; i < 32; i++) acc[i] = 0.f;
#pragma unroll 4
  for (int c = 0; c < nch; c++) {
    const bf16x8* p = (const bf16x8*)(pO + ((size_t)(cidb + c) * 64 + row) * DH_ + dseg);
#pragma unroll
    for (int j = 0; j < 4; j++) {
      bf16x8 v = p[j];
#pragma unroll
      for (int e2 = 0; e2 < 8; e2++) acc[j * 8 + e2] += wc[c] * (float)v[e2];
    }
  }
  bf16* dst = attn_out + ((size_t)bh * N_ + qt * 64 + row) * DH_ + dseg;
#pragma unroll
  for (int j = 0; j < 4; j++) {
    bf16x8 ov;
#pragma unroll
    for (int e2 = 0; e2 < 8; e2++) ov[e2] = (bf16)(acc[j * 8 + e2] * inv);
    *(bf16x8*)(dst + j * 8) = ov;
  }
}

// ------- MFMA retrieval + gate-combine + vnew (emits vnT d-major) -------
#define SMT_STRIDE 136
#define VNSTR 138
__global__ __launch_bounds__(256) void k_retrieve2(const bf16* __restrict__ qkv,
                                                   const bf16* __restrict__ mkvT,
                                                   const float* __restrict__ qden,
                                                   const float* __restrict__ kden,
                                                   const bf16* __restrict__ attn,
                                                   const float* __restrict__ hg,
                                                   bf16* __restrict__ comb,
                                                   bf16* __restrict__ vnT) {
  __shared__ __align__(16) bf16 smT[DH_ * SMT_STRIDE];
  __shared__ bf16 sVn[64 * VNSTR];
  int h = blockIdx.y, b = blockIdx.z;
  size_t bh = (size_t)b * H_ + h;
  int t = threadIdx.x;
  int w = t >> 6, lane = t & 63, quad = lane >> 4, l16 = lane & 15;
  int n0 = blockIdx.x * 64;

  {
    const uint4* src = (const uint4*)(mkvT + bh * DH_ * DH_);
    uint4* dst = (uint4*)smT;
#pragma unroll
    for (int it = 0; it < 8; it++) {
      int i = t + it * 256;
      int row = i >> 4, col = i & 15;
      dst[row * 17 + col] = src[i];
    }
  }

  int nrow = n0 + w * 16 + l16;
  const bf16* base = qkv + ((size_t)b * N_ + nrow) * NO_ + h * DH_;
  bf16x8 qa[4], ka[4];
#pragma unroll
  for (int s = 0; s < 4; s++) {
    int k0 = s * 32 + quad * 8;
    bf16x8 q8 = *(const bf16x8*)(base + k0);
    bf16x8 k8 = *(const bf16x8*)(base + D_ + k0);
    bf16x8 qo, ko;
#pragma unroll
    for (int e2 = 0; e2 < 8; e2++) {
      qo[e2] = (bf16)elu1((float)q8[e2]);
      ko[e2] = (bf16)elu1((float)k8[e2]);
    }
    qa[s] = qo; ka[s] = ko;
  }

  __syncthreads();
  f32x4 zf = {0.f, 0.f, 0.f, 0.f};
  f32x4 accq[8], acck[8];
#pragma unroll
  for (int vt = 0; vt < 8; vt++) { accq[vt] = zf; acck[vt] = zf; }
#pragma unroll
  for (int vt = 0; vt < 8; vt++) {
#pragma unroll
    for (int s = 0; s < 4; s++) {
      bf16x8 bfr = *(const bf16x8*)(smT + (vt * 16 + l16) * SMT_STRIDE + s * 32 + quad * 8);
      accq[vt] = mfma16(qa[s], bfr, accq[vt]);
      acck[vt] = mfma16(ka[s], bfr, acck[vt]);
    }
  }

  float g = 1.f / (1.f + __expf(-hg[h]));
#pragma unroll
  for (int r = 0; r < 4; r++) {
    int nl = w * 16 + quad * 4 + r;
    int n = n0 + nl;
    size_t m = (size_t)b * N_ + n;
    float qd = fmaxf(qden[bh * N_ + n], 1e-10f);
    float kd = fmaxf(kden[bh * N_ + n], 1e-10f);
#pragma unroll
    for (int vt = 0; vt < 8; vt++) {
      int v = vt * 16 + l16;
      float mo = accq[vt][r] / qd;
      float ov = (float)attn[(bh * N_ + n) * DH_ + v];
      comb[m * D_ + h * DH_ + v] = (bf16)(ov * g + mo * (1.f - g));
      float vv = (float)qkv[m * NO_ + 2 * D_ + h * DH_ + v];
      sVn[nl * VNSTR + v] = (bf16)(vv - acck[vt][r] / kd);
    }
  }
  __syncthreads();
  // transpose out vnT: rows v (128), cols n (64)
  int d = t >> 1, part = t & 1;
#pragma unroll
  for (int v8 = 0; v8 < 4; v8++) {
    bf16x8 ov;
#pragma unroll
    for (int e2 = 0; e2 < 8; e2++) ov[e2] = sVn[(part * 32 + v8 * 8 + e2) * VNSTR + d];
    *(bf16x8*)(vnT + (bh * DH_ + d) * N_ + n0 + part * 32 + v8 * 8) = ov;
  }
}

// ---------------- init out_kv with mem_kv ----------------
__global__ void k_init_kv(const float* __restrict__ mem_kv, float* __restrict__ out_kv) {
  int i = blockIdx.x * 256 + threadIdx.x;
  if (i < B_ * H_ * DH_ * DH_) out_kv[i] = mem_kv[i];
}

// ---- new_kv: out_kv[bh] += kfT[bh] @ vnT[bh]^T, split-K over n ----
#define GSTR 40
__global__ __launch_bounds__(256) void k_newkv2(const bf16* __restrict__ kfT,
                                                const bf16* __restrict__ vnT,
                                                float* __restrict__ out_kv) {
  __shared__ __align__(16) bf16 sA[128 * GSTR];
  __shared__ __align__(16) bf16 sB[128 * GSTR];
  int t = threadIdx.x;
  int w = t >> 6, lane = t & 63, quad = lane >> 4, l16 = lane & 15;
  size_t bh = (size_t)blockIdx.z * H_ + blockIdx.y;
  const bf16* A  = kfT + bh * DH_ * N_;
  const bf16* Bm = vnT + bh * DH_ * N_;
  int wr = (w & 1) * 64, wc = (w >> 1) * 64;
  f32x4 zf = {0.f, 0.f, 0.f, 0.f};
  f32x4 acc[4][4];
#pragma unroll
  for (int a = 0; a < 4; a++)
#pragma unroll
    for (int c = 0; c < 4; c++) acc[a][c] = zf;
  int trow = t >> 2, tc = t & 3;
  int kend = (blockIdx.x + 1) * 128;
  for (int k0 = blockIdx.x * 128; k0 < kend; k0 += 32) {
    __syncthreads();
    ((uint4*)sA)[trow * 5 + tc]        = *((const uint4*)(A + (size_t)trow * N_ + k0) + tc);
    ((uint4*)sA)[(trow + 64) * 5 + tc] = *((const uint4*)(A + (size_t)(trow + 64) * N_ + k0) + tc);
    ((uint4*)sB)[trow * 5 + tc]        = *((const uint4*)(Bm + (size_t)trow * N_ + k0) + tc);
    ((uint4*)sB)[(trow + 64) * 5 + tc] = *((const uint4*)(Bm + (size_t)(trow + 64) * N_ + k0) + tc);
    __syncthreads();
    bf16x8 af[4], bfr[4];
#pragma unroll
    for (int mt = 0; mt < 4; mt++)
      af[mt] = *(const bf16x8*)(sA + (wr + mt * 16 + l16) * GSTR + quad * 8);
#pragma unroll
    for (int nt = 0; nt < 4; nt++)
      bfr[nt] = *(const bf16x8*)(sB + (wc + nt * 16 + l16) * GSTR + quad * 8);
#pragma unroll
    for (int mt = 0; mt < 4; mt++)
#pragma unroll
      for (int nt = 0; nt < 4; nt++)
        acc[mt][nt] = mfma16(af[mt], bfr[nt], acc[mt][nt]);
  }
  float* obh = out_kv + bh * DH_ * DH_;
#pragma unroll
  for (int mt = 0; mt < 4; mt++)
#pragma unroll
    for (int nt = 0; nt < 4; nt++) {
      int row = wr + mt * 16 + quad * 4;
      int col = wc + nt * 16 + l16;
#pragma unroll
      for (int r = 0; r < 4; r++)
        atomicAdd(obh + (size_t)(row + r) * DH_ + col, acc[mt][nt][r]);
    }
}

// ---- new_norm: out_norm[bh][k] = mem_norm + row-sum of kfT (coalesced) ----
__global__ __launch_bounds__(256) void k_newnorm2(const bf16* __restrict__ kfT,
                                                  const float* __restrict__ mem_norm,
                                                  float* __restrict__ out_norm) {
  int bh = blockIdx.x;
  int t = threadIdx.x;
  int k = t >> 1, half = t & 1;
  const bf16x8* row = (const bf16x8*)(kfT + ((size_t)bh * DH_ + k) * N_ + half * (N_ / 2));
  float s = 0.f;
#pragma unroll 4
  for (int i = 0; i < N_ / 16; i++) {
    bf16x8 v = row[i];
#pragma unroll
    for (int e = 0; e < 8; e++) s += (float)v[e];
  }
  s += __shfl_xor(s, 1);
  if (half == 0) out_norm[(size_t)bh * DH_ + k] = mem_norm[(size_t)bh * DH_ + k] + s;
}

extern "C" void kernel_launch(void* const* d_in, const int* in_sizes, int n_in,
                              void* d_out, int out_size, void* d_ws, size_t ws_size,
                              hipStream_t stream) {
  const float* x        = (const float*)d_in[0];
  const float* gamma    = (const float*)d_in[1];
  const float* w_qkv    = (const float*)d_in[2];
  const float* w_out    = (const float*)d_in[3];
  const float* hg       = (const float*)d_in[4];
  const float* mem_kv   = (const float*)d_in[5];
  const float* mem_norm = (const float*)d_in[6];
  float* out      = (float*)d_out;
  float* out_kv   = out + (size_t)B_ * N_ * D_;
  float* out_norm = out_kv + (size_t)B_ * H_ * DH_ * DH_;

  char* ws = (char*)d_ws;
  size_t off = 0;
  auto alloc = [&](size_t bytes) -> void* {
    void* p = ws + off;
    off += (bytes + 255) & ~(size_t)255;
    return p;
  };
  bf16*  xn   = (bf16*)alloc((size_t)B_ * N_ * D_ * 2);
  bf16*  wqb  = (bf16*)alloc((size_t)NO_ * D_ * 2);
  bf16*  wob  = (bf16*)alloc((size_t)D_ * D_ * 2);
  bf16*  qkvb = (bf16*)alloc((size_t)B_ * N_ * NO_ * 2);
  bf16*  qr   = (bf16*)alloc((size_t)B_ * H_ * N_ * DH_ * 2);
  bf16*  kr   = (bf16*)alloc((size_t)B_ * H_ * N_ * DH_ * 2);
  bf16*  vT   = (bf16*)alloc((size_t)B_ * H_ * DH_ * N_ * 2);
  bf16*  kfT  = (bf16*)alloc((size_t)B_ * H_ * DH_ * N_ * 2);  // written early (prep2)
  float* qden = (float*)alloc((size_t)B_ * H_ * N_ * 4);
  float* kden = (float*)alloc((size_t)B_ * H_ * N_ * 4);
  bf16*  attnb= (bf16*)alloc((size_t)B_ * H_ * N_ * DH_ * 2);
  bf16*  mkvT = (bf16*)alloc((size_t)B_ * H_ * DH_ * DH_ * 2);
  // Union: pO/pstat (dead after k_combine) alias comb/vnT (born in k_retrieve2)
  size_t pO_bytes    = (size_t)1536 * 64 * DH_ * 2;
  size_t pstat_bytes = (size_t)1536 * 64 * 2 * 4;
  size_t comb_bytes  = (size_t)B_ * N_ * D_ * 2;
  size_t vnT_bytes   = (size_t)B_ * H_ * DH_ * N_ * 2;
  size_t union_bytes = pO_bytes + pstat_bytes;
  if (comb_bytes + vnT_bytes > union_bytes) union_bytes = comb_bytes + vnT_bytes;
  char* uni = (char*)alloc(union_bytes);
  bf16*  pO    = (bf16*)uni;
  float* pstat = (float*)(uni + pO_bytes);
  bf16*  comb  = (bf16*)uni;
  bf16*  vnT   = (bf16*)(uni + comb_bytes);
  (void)in_sizes; (void)n_in; (void)out_size; (void)ws_size;

  k_rmsnorm<<<dim3(B_ * N_), 256, 0, stream>>>(x, gamma, xn);
  k_cvt4<<<(NO_ * D_ / 4 + 255) / 256, 256, 0, stream>>>((const float4*)w_qkv, (bf16x4*)wqb, NO_ * D_ / 4);
  k_cvt4<<<(D_ * D_ / 4 + 255) / 256, 256, 0, stream>>>((const float4*)w_out, (bf16x4*)wob, D_ * D_ / 4);
  k_mkvT<<<dim3(B_ * H_), 256, 0, stream>>>(mem_kv, mkvT);
  k_gemm_lds<bf16><<<dim3(NO_ / 128, B_ * N_ / 128), 256, 0, stream>>>(xn, wqb, qkvb, B_ * N_, NO_, D_);
  k_prep2<<<dim3(N_ / 64, H_, B_), 256, 0, stream>>>(qkvb, mem_norm, qr, kr, vT, kfT, qden, kden);
  k_attn2<<<dim3(1280), 256, 0, stream>>>(qr, kr, vT, attnb, pO, pstat);
  k_combine<<<dim3(384), 256, 0, stream>>>(pO, pstat, attnb);
  k_retrieve2<<<dim3(N_ / 64, H_, B_), 256, 0, stream>>>(qkvb, mkvT, qden, kden, attnb, hg, comb, vnT);
  k_gemm_lds<float><<<dim3(D_ / 128, B_ * N_ / 128), 256, 0, stream>>>(comb, wob, out, B_ * N_, D_, D_);
  k_init_kv<<<(B_ * H_ * DH_ * DH_ + 255) / 256, 256, 0, stream>>>(mem_kv, out_kv);
  k_newkv2<<<dim3(16, H_, B_), 256, 0, stream>>>(kfT, vnT, out_kv);
  k_newnorm2<<<dim3(B_ * H_), 256, 0, stream>>>(kfT, mem_norm, out_norm);
}